// Round 8
// baseline (1536.629 us; speedup 1.0000x reference)
//
#include <hip/hip_runtime.h>
#include <stdint.h>

#define B_ 16
#define S_ 30
#define T_ 10
#define H_ 400
#define V_ 20000
#define L_ 200
#define G_ 3
#define SB 480          // S*B rows
#define KP 416          // padded K (13*32)
#define MP 512          // padded M rows (8*64)
#define NT_VOC 313      // ceil(20000/64)
#define NP_G 1216       // padded 3H rows (19*64)
#define NP_EMB 20096    // padded V rows (314*64)
#define TV (T_*V_)      // 200000

#define GG_T 152        // 19*8 hh tiles per t
#define GIA_UNITS (T_*GG_T)         // 1520

// attention v3: one block per (which,b,row-group)
#define ATT_ROWS 6
#define ATT_NRB 5                   // 30/6
#define ATT3_BLKS (2*B_*ATT_NRB)    // 160
// vocab with XCD-chunked swizzle: 8 chunks x 40 nb x 8 mb
#define VOC_PAD 2560
// finalize role: 4-way split rows (short poles)
#define FZ_SPLIT 4
#define FZ_SEG (V_/FZ_SPLIT)        // 5000
#define FZ_BLKS (SB*FZ_SPLIT)       // 1920
#define GG_PAD 160                  // GG_T padded to keep vocab offset %8==0
#define MEGAC_BLKS (FZ_BLKS + ATT3_BLKS + GG_PAD + VOC_PAD)   // 4800 (vocab off 2240 %8==0)

#define PRE_UNITS (ATT3_BLKS + GIA_UNITS)

// setup1 role counts
#define TT_TILES 1456   // 16 * 7 * 13 transpose tiles
#define INIT_BLKS 832   // MP*KP/256
#define XA8_BLKS 936    // 9*MP*KP/(256*8)
#define PS8_BLKS 247    // NP_G*KP/(256*8)
#define EC8_BLKS 4082   // NP_EMB*KP/(256*8)
#define SETUP1_UNITS (2*TT_TILES + INIT_BLKS + XA8_BLKS + 2*PS8_BLKS + EC8_BLKS)

typedef unsigned short ushort_t;
typedef __attribute__((ext_vector_type(8))) short frag8;       // 8 bf16
typedef __attribute__((ext_vector_type(8))) unsigned short us8;
typedef __attribute__((ext_vector_type(4))) float f32x4;

__device__ __forceinline__ float b2f(ushort_t u){ return __uint_as_float(((unsigned)u)<<16); }
__device__ __forceinline__ ushort_t f2b(float f){
  unsigned u = __float_as_uint(f);
  unsigned r = u + 0x7fffu + ((u>>16)&1u);   // RNE
  return (ushort_t)(r>>16);
}

// ================= setup bodies =================

__device__ __forceinline__ void padsplit8_body(const float* __restrict__ src,
    ushort_t* __restrict__ hi, ushort_t* __restrict__ lo, int u8){
  int base = u8*8;
  if (base >= NP_G*KP) return;
  int r = base / KP, c = base - r*KP;
  us8 h, l;
  if (r < 3*H_ && c+8 <= H_){
    float4 a = *(const float4*)(src + (size_t)r*H_ + c);
    float4 b = *(const float4*)(src + (size_t)r*H_ + c + 4);
    float v[8] = {a.x,a.y,a.z,a.w,b.x,b.y,b.z,b.w};
    #pragma unroll
    for (int i=0;i<8;i++){ h[i]=f2b(v[i]); l[i]=f2b(v[i]-b2f(h[i])); }
  } else {
    #pragma unroll
    for (int i=0;i<8;i++){ h[i]=0; l[i]=0; }
  }
  *(us8*)(hi+base) = h; *(us8*)(lo+base) = l;
}

__device__ __forceinline__ void embcvt8_body(const float* __restrict__ emb,
    ushort_t* __restrict__ dst, long long u8){
  long long base = u8*8;
  if (base >= (long long)NP_EMB*KP) return;
  int r = (int)(base / KP), c = (int)(base - (long long)r*KP);
  us8 h;
  if (r < V_ && c+8 <= H_){
    float4 a = *(const float4*)(emb + (size_t)r*H_ + c);
    float4 b = *(const float4*)(emb + (size_t)r*H_ + c + 4);
    float v[8] = {a.x,a.y,a.z,a.w,b.x,b.y,b.z,b.w};
    #pragma unroll
    for (int i=0;i<8;i++) h[i]=f2b(v[i]);
  } else {
    #pragma unroll
    for (int i=0;i<8;i++) h[i]=0;
  }
  *(us8*)(dst+base) = h;
}

__device__ __forceinline__ void xallcvt8_body(const int* __restrict__ targets,
    const float* __restrict__ emb, float* __restrict__ xf_all,
    ushort_t* __restrict__ xa_hi, ushort_t* __restrict__ xa_lo, int u8){
  long long base = (long long)u8*8;
  if (base >= (long long)(T_-1)*MP*KP) return;
  int t = (int)(base / ((long long)MP*KP)) + 1;
  int rem = (int)(base - (long long)(t-1)*MP*KP);
  int r = rem / KP, c = rem - r*KP;
  size_t off = (size_t)t*MP*KP + rem;
  us8 h, l;
  if (r < SB && c+8 <= H_){
    int s = r>>4, b = r&15;
    int tg = targets[(b*S_ + s)*T_ + (t-1)];
    float4 a = *(const float4*)(emb + (size_t)tg*H_ + c);
    float4 bb= *(const float4*)(emb + (size_t)tg*H_ + c + 4);
    float v[8] = {a.x,a.y,a.z,a.w,bb.x,bb.y,bb.z,bb.w};
    float* xfp = xf_all + (size_t)t*SB*H_ + (size_t)r*H_ + c;
    *(float4*)xfp = a; *(float4*)(xfp+4) = bb;
    #pragma unroll
    for (int i=0;i<8;i++){ h[i]=f2b(v[i]); l[i]=f2b(v[i]-b2f(h[i])); }
  } else {
    #pragma unroll
    for (int i=0;i<8;i++){ h[i]=0; l[i]=0; }
  }
  *(us8*)(xa_hi+off) = h; *(us8*)(xa_lo+off) = l;
}

__device__ __forceinline__ void transpose_body(const float* __restrict__ src,
    float* __restrict__ dst, int rel, int tid, float (*tile)[33]){
  int b  = rel / 91;           // 7*13 tiles per b
  int rem = rel - b*91;
  int l0 = (rem % 7)*32, k0 = (rem / 7)*32;
  int tx = tid & 31, ty = tid >> 5;   // 32 x 8
  const float* s = src + (size_t)b*L_*H_;
  float*       d = dst + (size_t)b*H_*L_;
  #pragma unroll
  for (int i=ty; i<32; i+=8){
    int l = l0+i, k = k0+tx;
    tile[i][tx] = (l<L_ && k<H_) ? s[(size_t)l*H_ + k] : 0.f;
  }
  __syncthreads();
  #pragma unroll
  for (int i=ty; i<32; i+=8){
    int k = k0+i, l = l0+tx;
    if (k<H_ && l<L_) d[(size_t)k*L_ + l] = tile[tx][i];
  }
  __syncthreads();
}

__device__ __forceinline__ void init2_body(const float* __restrict__ slot_att,
    const float* __restrict__ slot_emb,
    float* __restrict__ xf_all, ushort_t* __restrict__ xa_hi, ushort_t* __restrict__ xa_lo,
    ushort_t* __restrict__ hbfA, ushort_t* __restrict__ hbf2A,
    ushort_t* __restrict__ hbfB, ushort_t* __restrict__ hbf2B,
    float* __restrict__ hfA, int idx){
  if (idx >= MP*KP) return;
  int r = idx/KP, c = idx - r*KP;
  ushort_t xh = 0, xl = 0;
  if (r < SB && c < H_){
    int s = r >> 4;
    float xv = slot_emb[s*H_ + c];
    xf_all[(size_t)r*H_ + c] = xv;
    xh = f2b(xv); xl = f2b(xv - b2f(xh));
    hfA[(size_t)r*H_ + c] = slot_att[s*H_ + c];
  }
  xa_hi[idx] = xh; xa_lo[idx] = xl;
  hbfA[idx] = 0; hbf2A[idx] = 0;
  hbfB[idx] = 0; hbf2B[idx] = 0;
}

__global__ __launch_bounds__(256) void setup1_kernel(
    const float* __restrict__ sys_H, const float* __restrict__ user_H,
    float* __restrict__ seqT_s, float* __restrict__ seqT_u,
    const float* __restrict__ slot_att, const float* __restrict__ slot_emb,
    float* __restrict__ xf_all, ushort_t* __restrict__ xa_hi, ushort_t* __restrict__ xa_lo,
    ushort_t* __restrict__ hbfA, ushort_t* __restrict__ hbf2A,
    ushort_t* __restrict__ hbfB, ushort_t* __restrict__ hbf2B,
    float* __restrict__ hfA,
    const int* __restrict__ targets, const float* __restrict__ emb,
    const float* __restrict__ W_ih, ushort_t* __restrict__ Wih_hi, ushort_t* __restrict__ Wih_lo,
    const float* __restrict__ W_hh, ushort_t* __restrict__ Whh_hi, ushort_t* __restrict__ Whh_lo,
    ushort_t* __restrict__ embp){
  __shared__ float tile[32][33];
  int bid = blockIdx.x, tid = threadIdx.x;
  int u = bid;
  if (u < TT_TILES){ transpose_body(sys_H, seqT_s, u, tid, tile); return; }
  u -= TT_TILES;
  if (u < TT_TILES){ transpose_body(user_H, seqT_u, u, tid, tile); return; }
  u -= TT_TILES;
  if (u < INIT_BLKS){
    init2_body(slot_att, slot_emb, xf_all, xa_hi, xa_lo, hbfA, hbf2A, hbfB, hbf2B, hfA,
               u*256 + tid);
    return;
  }
  u -= INIT_BLKS;
  if (u < XA8_BLKS){ xallcvt8_body(targets, emb, xf_all, xa_hi, xa_lo, u*256 + tid); return; }
  u -= XA8_BLKS;
  if (u < PS8_BLKS){ padsplit8_body(W_ih, Wih_hi, Wih_lo, u*256 + tid); return; }
  u -= PS8_BLKS;
  if (u < PS8_BLKS){ padsplit8_body(W_hh, Whh_hi, Whh_lo, u*256 + tid); return; }
  u -= PS8_BLKS;
  embcvt8_body(emb, embp, (long long)u*256 + tid);
}

// ================= attention v3 (unroll-8 load ILP; add order per element unchanged) =================
__device__ void attend3_body(
    int u,
    const float* __restrict__ seqS, const float* __restrict__ seqTS, const float* __restrict__ muskS,
    const float* __restrict__ seqU, const float* __restrict__ seqTU, const float* __restrict__ muskU,
    const float* __restrict__ cond,
    float* __restrict__ ctxS, float* __restrict__ probS,
    float* __restrict__ ctxU, float* __restrict__ probU,
    float (*cond_l)[H_], float (*S_l)[208], float* smax, float* ssum){
  int which = (u >= B_*ATT_NRB) ? 1 : 0;
  int v = which ? u - B_*ATT_NRB : u;
  int b = v / ATT_NRB, rb = v - b*ATT_NRB;
  const float* seq  = which ? seqU  : seqS;
  const float* seqT = which ? seqTU : seqTS;
  const float* musk = which ? muskU : muskS;
  float* ctx  = which ? ctxU  : ctxS;
  float* prob = which ? probU : probS;
  int tid = threadIdx.x;
  int s0 = rb*ATT_ROWS;
  for (int idx=tid; idx<ATT_ROWS*H_; idx+=256){
    int i = idx/H_, k = idx - i*H_;
    cond_l[i][k] = cond[(size_t)((s0+i)*16 + b)*H_ + k];
  }
  __syncthreads();
  if (tid < L_){
    const float* sp = seqT + (size_t)b*H_*L_ + tid;
    float acc[ATT_ROWS];
    #pragma unroll
    for (int i=0;i<ATT_ROWS;i++) acc[i]=0.f;
    for (int k=0;k<H_;k+=8){
      float w[8];
      #pragma unroll
      for (int j=0;j<8;j++) w[j] = sp[(size_t)(k+j)*L_];
      #pragma unroll
      for (int i=0;i<ATT_ROWS;i++){
        float4 c0 = *(const float4*)&cond_l[i][k];
        float4 c1 = *(const float4*)&cond_l[i][k+4];
        acc[i] += c0.x*w[0]; acc[i] += c0.y*w[1]; acc[i] += c0.z*w[2]; acc[i] += c0.w*w[3];
        acc[i] += c1.x*w[4]; acc[i] += c1.y*w[5]; acc[i] += c1.z*w[6]; acc[i] += c1.w*w[7];
      }
    }
    float mk = musk[b*L_ + tid];
    #pragma unroll
    for (int i=0;i<ATT_ROWS;i++) S_l[i][tid] = acc[i] + mk;
  }
  __syncthreads();
  if (tid < ATT_ROWS*16){
    int i = tid >> 4, sub = tid & 15;
    float m = -3.0e38f;
    for (int l=sub; l<L_; l+=16) m = fmaxf(m, S_l[i][l]);
    #pragma unroll
    for (int d=8; d>=1; d>>=1) m = fmaxf(m, __shfl_xor(m, d));
    float sm = 0.f;
    for (int l=sub; l<L_; l+=16) sm += __expf(S_l[i][l] - m);
    #pragma unroll
    for (int d=8; d>=1; d>>=1) sm += __shfl_xor(sm, d);
    if (sub==0){ smax[i] = m; ssum[i] = sm; }
  }
  __syncthreads();
  for (int idx=tid; idx<ATT_ROWS*L_; idx+=256){
    int i = idx/L_, l = idx - i*L_;
    float p = __expf(S_l[i][l] - smax[i]) / ssum[i];
    S_l[i][l] = p;
    prob[(size_t)((s0+i)*16 + b)*L_ + l] = p;
  }
  __syncthreads();
  for (int k=tid; k<H_; k+=256){
    const float* sp2 = seq + (size_t)b*L_*H_ + k;
    float acc[ATT_ROWS];
    #pragma unroll
    for (int i=0;i<ATT_ROWS;i++) acc[i]=0.f;
    for (int l=0;l<L_;l+=8){
      float w[8];
      #pragma unroll
      for (int j=0;j<8;j++) w[j] = sp2[(size_t)(l+j)*H_];
      #pragma unroll
      for (int i=0;i<ATT_ROWS;i++){
        float4 p0 = *(const float4*)&S_l[i][l];
        float4 p1 = *(const float4*)&S_l[i][l+4];
        acc[i] += p0.x*w[0]; acc[i] += p0.y*w[1]; acc[i] += p0.z*w[2]; acc[i] += p0.w*w[3];
        acc[i] += p1.x*w[4]; acc[i] += p1.y*w[5]; acc[i] += p1.z*w[6]; acc[i] += p1.w*w[7];
      }
    }
    #pragma unroll
    for (int i=0;i<ATT_ROWS;i++)
      ctx[(size_t)((s0+i)*16 + b)*H_ + k] = acc[i];
  }
}

// ================= hi/lo GEMM tile =================
__device__ __forceinline__ void hl_gemm_tile(
    const ushort_t* __restrict__ A_hi, const ushort_t* __restrict__ A_lo,
    const ushort_t* __restrict__ B_hi, const ushort_t* __restrict__ B_lo,
    float* __restrict__ outg, int nb, int mb, int tid){
  int wave = tid>>6, lane = tid&63;
  int q = lane>>4, ln = lane&15;
  int m_base = mb*64 + wave*16;
  int n_base = nb*64;
  const ushort_t* Ah  = A_hi + (size_t)(m_base + ln)*KP;
  const ushort_t* Ah2 = A_lo + (size_t)(m_base + ln)*KP;
  f32x4 ah[4];
  #pragma unroll
  for (int nt=0;nt<4;nt++) ah[nt]=(f32x4){0,0,0,0};
  for (int kk=0; kk<KP; kk+=32){
    int ko = kk + q*8;
    frag8 ahv = *(const frag8*)(Ah  + ko);
    frag8 ah2 = *(const frag8*)(Ah2 + ko);
    #pragma unroll
    for (int nt=0;nt<4;nt++){
      size_t nrow = (size_t)(n_base + nt*16 + ln)*KP + ko;
      frag8 bhh = *(const frag8*)(B_hi + nrow);
      frag8 bhl = *(const frag8*)(B_lo + nrow);
      ah[nt] = __builtin_amdgcn_mfma_f32_16x16x32_bf16(ahv,bhh, ah[nt],0,0,0);
      ah[nt] = __builtin_amdgcn_mfma_f32_16x16x32_bf16(ahv,bhl, ah[nt],0,0,0);
      ah[nt] = __builtin_amdgcn_mfma_f32_16x16x32_bf16(ah2,bhh, ah[nt],0,0,0);
    }
  }
  int mrow = m_base + q*4;
  #pragma unroll
  for (int nt=0; nt<4; nt++){
    int n = n_base + nt*16 + ln;
    if (n >= 3*H_) continue;
    #pragma unroll
    for (int i=0;i<4;i++){
      int m = mrow + i;
      if (m < SB) outg[(size_t)m*(3*H_) + n] = ah[nt][i];
    }
  }
}

// ---------- pre: h0 attend (160) + gi_all GEMM (1520 tiles) ----------
__global__ __launch_bounds__(256) void pre_kernel(
    const float* __restrict__ seqS, const float* __restrict__ seqTS, const float* __restrict__ muskS,
    const float* __restrict__ seqU, const float* __restrict__ seqTU, const float* __restrict__ muskU,
    const float* __restrict__ cond,
    float* __restrict__ ctxS, float* __restrict__ probS,
    float* __restrict__ ctxU, float* __restrict__ probU,
    const ushort_t* __restrict__ xa_hi, const ushort_t* __restrict__ xa_lo,
    const ushort_t* __restrict__ Wih_hi, const ushort_t* __restrict__ Wih_lo,
    float* __restrict__ gi_all){
  __shared__ float cond_l[ATT_ROWS][H_];
  __shared__ float S_l[ATT_ROWS][208];
  __shared__ float smax[ATT_ROWS], ssum[ATT_ROWS];
  int u = blockIdx.x, tid = threadIdx.x;
  if (u < ATT3_BLKS){
    attend3_body(u, seqS, seqTS, muskS, seqU, seqTU, muskU, cond,
                 ctxS, probS, ctxU, probU, cond_l, S_l, smax, ssum);
    return;
  }
  u -= ATT3_BLKS;
  int t = u / GG_T, rem = u - t*GG_T;
  hl_gemm_tile(xa_hi + (size_t)t*MP*KP, xa_lo + (size_t)t*MP*KP,
               Wih_hi, Wih_lo, gi_all + (size_t)t*SB*(3*H_),
               rem % 19, rem / 19, tid);
}

// ---------- gg0v2: hh GEMM for t'=0 with on-the-fly A = bf16(cs+cu); also writes hf0 ----------
__global__ __launch_bounds__(256) void gg0v2_kernel(
    const float* __restrict__ cs, const float* __restrict__ cu,
    const ushort_t* __restrict__ Whh_hi, const ushort_t* __restrict__ Whh_lo,
    float* __restrict__ gh, float* __restrict__ hf0){
  int u = blockIdx.x, tid = threadIdx.x;
  int nb = u % 19, mb = u / 19;
  int wave = tid>>6, lane = tid&63;
  int q = lane>>4, ln = lane&15;
  int m_base = mb*64 + wave*16;
  int n_base = nb*64;
  int row = m_base + ln;
  f32x4 ah[4];
  #pragma unroll
  for (int nt=0;nt<4;nt++) ah[nt]=(f32x4){0,0,0,0};
  for (int kk=0; kk<KP; kk+=32){
    int ko = kk + q*8;
    frag8 ahv, ah2;
    if (row < SB && ko < H_){
      const float* c1 = cs + (size_t)row*H_ + ko;
      const float* c2 = cu + (size_t)row*H_ + ko;
      float4 a = *(const float4*)c1, b = *(const float4*)(c1+4);
      float4 e = *(const float4*)c2, f = *(const float4*)(c2+4);
      float v[8] = {a.x+e.x, a.y+e.y, a.z+e.z, a.w+e.w,
                    b.x+f.x, b.y+f.y, b.z+f.z, b.w+f.w};
      #pragma unroll
      for (int i=0;i<8;i++){
        ushort_t hb = f2b(v[i]);
        ahv[i] = (short)hb;
        ah2[i] = (short)f2b(v[i] - b2f(hb));
      }
      if (nb == 0){
        float* hp = hf0 + (size_t)row*H_ + ko;
        *(float4*)hp     = (float4){v[0],v[1],v[2],v[3]};
        *(float4*)(hp+4) = (float4){v[4],v[5],v[6],v[7]};
      }
    } else {
      #pragma unroll
      for (int i=0;i<8;i++){ ahv[i]=0; ah2[i]=0; }
    }
    #pragma unroll
    for (int nt=0;nt<4;nt++){
      size_t nrow = (size_t)(n_base + nt*16 + ln)*KP + ko;
      frag8 bhh = *(const frag8*)(Whh_hi + nrow);
      frag8 bhl = *(const frag8*)(Whh_lo + nrow);
      ah[nt] = __builtin_amdgcn_mfma_f32_16x16x32_bf16(ahv,bhh, ah[nt],0,0,0);
      ah[nt] = __builtin_amdgcn_mfma_f32_16x16x32_bf16(ahv,bhl, ah[nt],0,0,0);
      ah[nt] = __builtin_amdgcn_mfma_f32_16x16x32_bf16(ah2,bhh, ah[nt],0,0,0);
    }
  }
  int mrow = m_base + q*4;
  #pragma unroll
  for (int nt=0; nt<4; nt++){
    int n = n_base + nt*16 + ln;
    if (n >= 3*H_) continue;
    #pragma unroll
    for (int i=0;i<4;i++){
      int m = mrow + i;
      if (m < SB) gh[(size_t)m*(3*H_) + n] = ah[nt][i];
    }
  }
}

// ---------- GRU row ----------
__device__ __forceinline__ void gru_row(int r,
    const float* __restrict__ gia_t, const float* __restrict__ gh,
    const float* __restrict__ b_ih, const float* __restrict__ b_hh,
    const float* __restrict__ hold, float* __restrict__ hfw,
    ushort_t* __restrict__ hbfw, ushort_t* __restrict__ hbf2w, int tid){
  const float* gir = gia_t + (size_t)r*(3*H_);
  const float* ghr = gh    + (size_t)r*(3*H_);
  for (int j=tid; j<H_; j+=256){
    float i_r = gir[j]      + b_ih[j];
    float i_z = gir[H_+j]   + b_ih[H_+j];
    float i_n = gir[2*H_+j] + b_ih[2*H_+j];
    float h_r = ghr[j]      + b_hh[j];
    float h_z = ghr[H_+j]   + b_hh[H_+j];
    float h_n = ghr[2*H_+j] + b_hh[2*H_+j];
    float rg = 1.f/(1.f+__expf(-(i_r+h_r)));
    float zg = 1.f/(1.f+__expf(-(i_z+h_z)));
    float ng = tanhf(i_n + rg*h_n);
    float hv = (1.f-zg)*ng + zg*hold[(size_t)r*H_ + j];
    hfw[(size_t)r*H_ + j] = hv;
    ushort_t hb = f2b(hv);
    hbfw [r*KP + j] = hb;
    hbf2w[r*KP + j] = f2b(hv - b2f(hb));
  }
}

__global__ __launch_bounds__(256) void gru0_kernel(
    const float* __restrict__ gia_t, const float* __restrict__ gh,
    const float* __restrict__ b_ih, const float* __restrict__ b_hh,
    const float* __restrict__ hold, float* __restrict__ hfw,
    ushort_t* __restrict__ hbfw, ushort_t* __restrict__ hbf2w){
  gru_row(blockIdx.x, gia_t, gh, b_ih, b_hh, hold, hfw, hbfw, hbf2w, threadIdx.x);
}

// ---------- vocab GEMM tile ----------
__device__ __forceinline__ void vocab_tile(
    const ushort_t* __restrict__ A, const ushort_t* __restrict__ Bm,
    float* __restrict__ outp, float* __restrict__ pmax, float* __restrict__ psum,
    int nb, int mb, int tid){
  int wave = tid>>6, lane = tid&63;
  int q = lane>>4, ln = lane&15;
  int m_base = mb*64 + wave*16;
  int n_base = nb*64;
  const ushort_t* Arow = A + (size_t)(m_base + ln)*KP;
  f32x4 acc[4];
  #pragma unroll
  for (int nt=0;nt<4;nt++) acc[nt]=(f32x4){0,0,0,0};
  for (int kk=0; kk<KP; kk+=32){
    int ko = kk + q*8;
    frag8 a  = *(const frag8*)(Arow + ko);
    #pragma unroll
    for (int nt=0;nt<4;nt++){
      frag8 b = *(const frag8*)(Bm + (size_t)(n_base + nt*16 + ln)*KP + ko);
      acc[nt] = __builtin_amdgcn_mfma_f32_16x16x32_bf16(a,b,acc[nt],0,0,0);
    }
  }
  int mrow = m_base + q*4;
  #pragma unroll
  for (int nt=0; nt<4; nt++){
    int n = n_base + nt*16 + ln;
    if (n >= V_) continue;
    #pragma unroll
    for (int i=0;i<4;i++){
      int m = mrow + i;
      if (m < SB) outp[(size_t)m*TV + n] = acc[nt][i];
    }
  }
  #pragma unroll
  for (int i=0;i<4;i++){
    float mx = -3.0e38f;
    #pragma unroll
    for (int nt=0;nt<4;nt++){
      int n = n_base + nt*16 + ln;
      if (n < V_) mx = fmaxf(mx, acc[nt][i]);
    }
    #pragma unroll
    for (int d=8; d>=1; d>>=1) mx = fmaxf(mx, __shfl_xor(mx, d));
    float sm = 0.f;
    #pragma unroll
    for (int nt=0;nt<4;nt++){
      int n = n_base + nt*16 + ln;
      if (n < V_) sm += __expf(acc[nt][i] - mx);
    }
    #pragma unroll
    for (int d=8; d>=1; d>>=1) sm += __shfl_xor(sm, d);
    int m = mrow + i;
    if (ln == 0 && m < SB){
      pmax[(size_t)m*NT_VOC + nb] = mx;
      psum[(size_t)m*NT_VOC + nb] = sm;
    }
  }
}

// ---------- finalize: one (row, part) — scale pass + range-filtered scatter ----------
__device__ __forceinline__ void finalize_row_part(int r, int part,
    float* __restrict__ out_prev,
    const float* __restrict__ Marr, const float* __restrict__ scarr,
    const float* __restrict__ acarr, const float* __restrict__ bcarr,
    const float* __restrict__ ps, const float* __restrict__ pu,
    const int* __restrict__ story_sys, const int* __restrict__ story_user, int tid){
  int v0 = part*FZ_SEG, v1 = v0 + FZ_SEG;
  float M = Marr[r], sc = scarr[r];
  float* row = out_prev + (size_t)r*TV;
  for (int v=v0+tid; v<v1; v+=256) row[v] = __expf(row[v]-M)*sc;
  __syncthreads();    // drain scale-writes before atomics (same block owns this v-range)
  int b = r & 15;
  float a_ = acarr[r], b_ = bcarr[r];
  for (int i=tid; i<2*L_; i+=256){
    int which = (i >= L_) ? 1 : 0;
    int l = which ? i - L_ : i;
    int v = which ? story_user[b*L_+l] : story_sys[b*L_+l];
    if (v < v0 || v >= v1) continue;
    float val = which ? b_*pu[(size_t)r*L_+l] : a_*ps[(size_t)r*L_+l];
    atomicAdd(row + v, val);
  }
}

// ================= megaC v3: finalize(t-1) first (long poles), then attend, gg, vocab =================
__global__ __launch_bounds__(256) void megaC_kernel(
    const float* __restrict__ seqS, const float* __restrict__ seqTS, const float* __restrict__ muskS,
    const float* __restrict__ seqU, const float* __restrict__ seqTU, const float* __restrict__ muskU,
    const float* __restrict__ hf_r,
    const ushort_t* __restrict__ hbf_r, const ushort_t* __restrict__ hbf2_r,
    float* __restrict__ ctxS, float* __restrict__ probS,
    float* __restrict__ ctxU, float* __restrict__ probU,
    const ushort_t* __restrict__ embp, float* __restrict__ outp,
    float* __restrict__ pmax, float* __restrict__ psum,
    const ushort_t* __restrict__ Whh_hi, const ushort_t* __restrict__ Whh_lo,
    float* __restrict__ gh, int ngg,
    float* __restrict__ out_prev,
    const float* __restrict__ Marr, const float* __restrict__ scarr,
    const float* __restrict__ acarr, const float* __restrict__ bcarr,
    const float* __restrict__ ps_prev, const float* __restrict__ pu_prev,
    const int* __restrict__ story_sys, const int* __restrict__ story_user,
    int base_off){
  __shared__ float cond_l[ATT_ROWS][H_];
  __shared__ float S_l[ATT_ROWS][208];
  __shared__ float smax[ATT_ROWS], ssum[ATT_ROWS];
  int u = blockIdx.x + base_off, tid = threadIdx.x;
  if (u < FZ_BLKS){
    finalize_row_part(u>>2, u&3, out_prev, Marr, scarr, acarr, bcarr,
                      ps_prev, pu_prev, story_sys, story_user, tid);
    return;
  }
  u -= FZ_BLKS;
  if (u < ATT3_BLKS){
    attend3_body(u, seqS, seqTS, muskS, seqU, seqTU, muskU, hf_r,
                 ctxS, probS, ctxU, probU, cond_l, S_l, smax, ssum);
    return;
  }
  u -= ATT3_BLKS;
  if (u < GG_PAD){
    if (u < GG_T && ngg)
      hl_gemm_tile(hbf_r, hbf2_r, Whh_hi, Whh_lo, gh, u % 19, u / 19, tid);
    return;
  }
  u -= GG_PAD;
  // vocab: XCD-chunked swizzle (role offset 2240 and base_off 0/1920 are %8==0)
  int x = u & 7, j = u >> 3;
  int nb = x*40 + (j>>3), mb = j & 7;
  if (nb < NT_VOC)
    vocab_tile(hbf_r, embp, outp, pmax, psum, nb, mb, tid);
}

// ================= finalstats: gru(t+1) + per-row scalars + softmax stats =================
__device__ __forceinline__ float block_reduce(float v, float* red, int tid){
  red[tid]=v; __syncthreads();
  for (int s=128;s>0;s>>=1){ if(tid<s) red[tid]+=red[tid+s]; __syncthreads(); }
  float r = red[0]; __syncthreads();
  return r;
}

__global__ __launch_bounds__(256) void finalstats_kernel(
    const float* __restrict__ hf_r, const float* __restrict__ cs, const float* __restrict__ cu,
    const float* __restrict__ xf_t,
    const float* __restrict__ Wr_w, const float* __restrict__ Wr_b,
    const float* __restrict__ Wc_w, const float* __restrict__ Wc_b,
    const float* __restrict__ Wg_w, const float* __restrict__ Wg_b,
    const float* __restrict__ pmax, const float* __restrict__ psum,
    float* __restrict__ Marr, float* __restrict__ scarr,
    float* __restrict__ acarr, float* __restrict__ bcarr,
    float* __restrict__ gate_out, int do_gate,
    const float* __restrict__ gia_t1, const float* __restrict__ gh,
    const float* __restrict__ b_ih, const float* __restrict__ b_hh,
    float* __restrict__ hf_w, ushort_t* __restrict__ hbf_w, ushort_t* __restrict__ hbf2_w,
    int do_gru){
  __shared__ float red[256];
  int r = blockIdx.x, tid = threadIdx.x;
  if (do_gru)
    gru_row(r, gia_t1, gh, b_ih, b_hh, hf_r, hf_w, hbf_w, hbf2_w, tid);
  const float* h   = hf_r + (size_t)r*H_;
  const float* csr = cs + (size_t)r*H_;
  const float* cur = cu + (size_t)r*H_;
  const float* xr  = xf_t + (size_t)r*H_;
  float sr=0, ss=0, su=0, g0=0, g1=0, g2=0;
  for (int k=tid;k<4*H_;k+=256){
    float v = (k<H_)? h[k] : (k<2*H_)? csr[k-H_] : (k<3*H_)? cur[k-2*H_] : xr[k-3*H_];
    sr += Wr_w[k]*v;
  }
  for (int k=tid;k<3*H_;k+=256){
    float w = Wc_w[k];
    float vs = (k<H_)? h[k] : (k<2*H_)? csr[k-H_] : xr[k-2*H_];
    float vu = (k<H_)? h[k] : (k<2*H_)? cur[k-H_] : xr[k-2*H_];
    ss += w*vs; su += w*vu;
  }
  if (do_gate){
    for (int k=tid;k<2*H_;k+=256){
      float m = (k<H_)? csr[k] : cur[k-H_];
      g0 += Wg_w[k]*m;
      g1 += Wg_w[2*H_+k]*m;
      g2 += Wg_w[4*H_+k]*m;
    }
  }
  float SR = block_reduce(sr, red, tid);
  float SS = block_reduce(ss, red, tid);
  float SU = block_reduce(su, red, tid);
  if (do_gate){
    float G0=block_reduce(g0,red,tid);
    float G1=block_reduce(g1,red,tid);
    float G2=block_reduce(g2,red,tid);
    if (tid==0){
      gate_out[r*G_+0] = G0 + Wg_b[0];
      gate_out[r*G_+1] = G1 + Wg_b[1];
      gate_out[r*G_+2] = G2 + Wg_b[2];
    }
  }
  // softmax stats from online partials
  const float* pmr = pmax + (size_t)r*NT_VOC;
  const float* psr = psum + (size_t)r*NT_VOC;
  float lm = -3.0e38f;
  for (int nb=tid; nb<NT_VOC; nb+=256) lm = fmaxf(lm, pmr[nb]);
  red[tid]=lm; __syncthreads();
  for (int s=128;s>0;s>>=1){ if(tid<s) red[tid]=fmaxf(red[tid],red[tid+s]); __syncthreads(); }
  float M = red[0]; __syncthreads();
  float ls = 0.f;
  for (int nb=tid; nb<NT_VOC; nb+=256) ls += psr[nb]*__expf(pmr[nb]-M);
  float S = block_reduce(ls, red, tid);
  if (tid==0){
    float swv = 1.f/(1.f+__expf(-(SR + Wr_b[0])));
    float lcs = SS + Wc_b[0];
    float lcu = SU + Wc_b[0];
    float mx = fmaxf(lcs,lcu);
    float es = __expf(lcs-mx), eu = __expf(lcu-mx);
    float al = es/(es+eu);
    Marr[r]  = M;
    scarr[r] = swv / S;
    acarr[r] = (1.f-swv)*al;
    bcarr[r] = (1.f-swv)*(1.f-al);
  }
}

// ---------- tail finalize (t = T-1), 4-way split ----------
__global__ __launch_bounds__(256) void finalize_kernel(
    float* __restrict__ out_prev,
    const float* __restrict__ Marr, const float* __restrict__ scarr,
    const float* __restrict__ acarr, const float* __restrict__ bcarr,
    const float* __restrict__ ps, const float* __restrict__ pu,
    const int* __restrict__ story_sys, const int* __restrict__ story_user){
  int u = blockIdx.x;
  finalize_row_part(u>>2, u&3, out_prev, Marr, scarr, acarr, bcarr,
                    ps, pu, story_sys, story_user, threadIdx.x);
}

// ================= legacy basic-path kernels (small workspace fallback) =================

__global__ void padsplit_kernel(const float* __restrict__ src,
                                ushort_t* __restrict__ hi, ushort_t* __restrict__ lo){
  int idx = blockIdx.x*256 + threadIdx.x;
  if (idx >= NP_G*KP) return;
  int r = idx / KP, c = idx - r*KP;
  ushort_t h = 0, l = 0;
  if (r < 3*H_ && c < H_){
    float v = src[r*H_ + c];
    h = f2b(v);
    l = f2b(v - b2f(h));
  }
  hi[idx] = h; lo[idx] = l;
}

__global__ void initL_kernel(const float* __restrict__ slot_att, const float* __restrict__ slot_emb,
                            float* __restrict__ xf, ushort_t* __restrict__ xbf, ushort_t* __restrict__ xbf2,
                            ushort_t* __restrict__ hbf, ushort_t* __restrict__ hbf2,
                            float* __restrict__ hf){
  int idx = blockIdx.x*256 + threadIdx.x;
  if (idx >= MP*KP) return;
  int r = idx/KP, c = idx - r*KP;
  ushort_t xh = 0, xl = 0;
  if (r < SB && c < H_){
    int s = r >> 4;
    float xv = slot_emb[s*H_ + c];
    xf[r*H_ + c] = xv;
    xh = f2b(xv); xl = f2b(xv - b2f(xh));
    hf[r*H_ + c] = slot_att[s*H_ + c];
  }
  xbf[idx] = xh; xbf2[idx] = xl;
  hbf[idx] = 0;  hbf2[idx] = 0;
}

__global__ void addh_kernel(const float* __restrict__ cs, const float* __restrict__ cu,
                            float* __restrict__ hf, ushort_t* __restrict__ hbf, ushort_t* __restrict__ hbf2){
  int idx = blockIdx.x*256 + threadIdx.x;
  if (idx >= SB*H_) return;
  int r = idx/H_, c = idx - r*H_;
  float v = cs[idx] + cu[idx];
  hf[idx] = v;
  ushort_t hb = f2b(v);
  hbf [r*KP + c] = hb;
  hbf2[r*KP + c] = f2b(v - b2f(hb));
}

__global__ __launch_bounds__(256) void attendL_kernel(
    const float* __restrict__ seq, const float* __restrict__ musk,
    const float* __restrict__ cond, float* __restrict__ ctx, float* __restrict__ prob){
  __shared__ float hrow[H_];
  __shared__ float pl[L_];
  __shared__ float red[256];
  int r = blockIdx.x; int tid = threadIdx.x;
  int b = r & 15;
  for (int k=tid; k<H_; k+=256) hrow[k] = cond[(size_t)r*H_ + k];
  __syncthreads();
  float score = -3.0e38f;
  if (tid < L_){
    const float4* sp = (const float4*)(seq + ((size_t)b*L_ + tid)*H_);
    float acc = 0.f;
    for (int k=0; k<H_; k+=4){
      float4 v = sp[k>>2];
      acc += hrow[k]*v.x + hrow[k+1]*v.y + hrow[k+2]*v.z + hrow[k+3]*v.w;
    }
    score = acc + musk[b*L_ + tid];
  }
  red[tid] = score; __syncthreads();
  for (int s=128;s>0;s>>=1){ if(tid<s) red[tid]=fmaxf(red[tid],red[tid+s]); __syncthreads(); }
  float mv = red[0]; __syncthreads();
  float e = (tid<L_) ? __expf(score-mv) : 0.f;
  red[tid] = e; __syncthreads();
  for (int s=128;s>0;s>>=1){ if(tid<s) red[tid]+=red[tid+s]; __syncthreads(); }
  float sv = red[0]; __syncthreads();
  if (tid<L_){ float p = e/sv; pl[tid]=p; prob[(size_t)r*L_+tid]=p; }
  __syncthreads();
  for (int k=tid; k<H_; k+=256){
    float a = 0.f;
    const float* sp = seq + (size_t)b*L_*H_ + k;
    for (int l=0;l<L_;l++) a += pl[l]*sp[(size_t)l*H_];
    ctx[(size_t)r*H_ + k] = a;
  }
}

__global__ __launch_bounds__(256) void grugemmL_kernel(
    const ushort_t* __restrict__ xbf, const ushort_t* __restrict__ xbf2,
    const ushort_t* __restrict__ hbf, const ushort_t* __restrict__ hbf2,
    const ushort_t* __restrict__ Wih_hi, const ushort_t* __restrict__ Wih_lo,
    const ushort_t* __restrict__ Whh_hi, const ushort_t* __restrict__ Whh_lo,
    float* __restrict__ gi, float* __restrict__ gh){
  int tid = threadIdx.x;
  int wave = tid>>6, lane = tid&63;
  int q = lane>>4, ln = lane&15;
  int m_base = blockIdx.y*64 + wave*16;
  int n_base = blockIdx.x*64;
  const ushort_t* Ax  = xbf  + (size_t)(m_base + ln)*KP;
  const ushort_t* Ax2 = xbf2 + (size_t)(m_base + ln)*KP;
  const ushort_t* Ah  = hbf  + (size_t)(m_base + ln)*KP;
  const ushort_t* Ah2 = hbf2 + (size_t)(m_base + ln)*KP;
  f32x4 ai[4], ah[4];
  #pragma unroll
  for (int nt=0;nt<4;nt++){ ai[nt]=(f32x4){0,0,0,0}; ah[nt]=(f32x4){0,0,0,0}; }
  for (int kk=0; kk<KP; kk+=32){
    int ko = kk + q*8;
    frag8 ax  = *(const frag8*)(Ax  + ko);
    frag8 ax2 = *(const frag8*)(Ax2 + ko);
    frag8 ahv = *(const frag8*)(Ah  + ko);
    frag8 ah2 = *(const frag8*)(Ah2 + ko);
    #pragma unroll
    for (int nt=0;nt<4;nt++){
      size_t nrow = (size_t)(n_base + nt*16 + ln)*KP + ko;
      frag8 bih = *(const frag8*)(Wih_hi + nrow);
      frag8 bil = *(const frag8*)(Wih_lo + nrow);
      frag8 bhh = *(const frag8*)(Whh_hi + nrow);
      frag8 bhl = *(const frag8*)(Whh_lo + nrow);
      ai[nt] = __builtin_amdgcn_mfma_f32_16x16x32_bf16(ax, bih, ai[nt],0,0,0);
      ai[nt] = __builtin_amdgcn_mfma_f32_16x16x32_bf16(ax, bil, ai[nt],0,0,0);
      ai[nt] = __builtin_amdgcn_mfma_f32_16x16x32_bf16(ax2,bih, ai[nt],0,0,0);
      ah[nt] = __builtin_amdgcn_mfma_f32_16x16x32_bf16(ahv,bhh, ah[nt],0,0,0);
      ah[nt] = __builtin_amdgcn_mfma_f32_16x16x32_bf16(ahv,bhl, ah[nt],0,0,0);
      ah[nt] = __builtin_amdgcn_mfma_f32_16x16x32_bf16(ah2,bhh, ah[nt],0,0,0);
    }
  }
  int mrow = m_base + q*4;
  #pragma unroll
  for (int nt=0; nt<4; nt++){
    int n = n_base + nt*16 + ln;
    if (n >= 3*H_) continue;
    #pragma unroll
    for (int i=0;i<4;i++){
      int m = mrow + i;
      if (m < SB){
        gi[(size_t)m*(3*H_) + n] = ai[nt][i];
        gh[(size_t)m*(3*H_) + n] = ah[nt][i];
      }
    }
  }
}

__global__ void gruL_kernel(const float* __restrict__ gi, const float* __restrict__ gh,
    const float* __restrict__ b_ih, const float* __restrict__ b_hh,
    float* __restrict__ hf, ushort_t* __restrict__ hbf, ushort_t* __restrict__ hbf2){
  int idx = blockIdx.x*256 + threadIdx.x;
  if (idx >= SB*H_) return;
  int r = idx/H_, j = idx - r*H_;
  const float* gir = gi + (size_t)r*(3*H_);
  const float* ghr = gh + (size_t)r*(3*H_);
  float i_r = gir[j]      + b_ih[j];
  float i_z = gir[H_+j]   + b_ih[H_+j];
  float i_n = gir[2*H_+j] + b_ih[2*H_+j];
  float h_r = ghr[j]      + b_hh[j];
  float h_z = ghr[H_+j]   + b_hh[H_+j];
  float h_n = ghr[2*H_+j] + b_hh[2*H_+j];
  float rg = 1.f/(1.f+__expf(-(i_r+h_r)));
  float zg = 1.f/(1.f+__expf(-(i_z+h_z)));
  float ng = tanhf(i_n + rg*h_n);
  float hv = (1.f-zg)*ng + zg*hf[idx];
  hf[idx] = hv;
  ushort_t hb = f2b(hv);
  hbf [r*KP + j] = hb;
  hbf2[r*KP + j] = f2b(hv - b2f(hb));
}

__global__ __launch_bounds__(256) void smallL_kernel(
    const float* __restrict__ hf, const float* __restrict__ cs, const float* __restrict__ cu,
    const float* __restrict__ xf,
    const float* __restrict__ Wr_w, const float* __restrict__ Wr_b,
    const float* __restrict__ Wc_w, const float* __restrict__ Wc_b,
    const float* __restrict__ Wg_w, const float* __restrict__ Wg_b,
    float* __restrict__ sw_arr, float* __restrict__ ac_arr, float* __restrict__ bc_arr,
    float* __restrict__ gate_out, int do_gate){
  __shared__ float red[256];
  int r = blockIdx.x, tid = threadIdx.x;
  const float* h   = hf + (size_t)r*H_;
  const float* csr = cs + (size_t)r*H_;
  const float* cur = cu + (size_t)r*H_;
  const float* xr  = xf + (size_t)r*H_;
  float sr=0, ss=0, su=0, g0=0, g1=0, g2=0;
  for (int k=tid;k<4*H_;k+=256){
    float v = (k<H_)? h[k] : (k<2*H_)? csr[k-H_] : (k<3*H_)? cur[k-2*H_] : xr[k-3*H_];
    sr += Wr_w[k]*v;
  }
  for (int k=tid;k<3*H_;k+=256){
    float w = Wc_w[k];
    float vs = (k<H_)? h[k] : (k<2*H_)? csr[k-H_] : xr[k-2*H_];
    float vu = (k<H_)? h[k] : (k<2*H_)? cur[k-H_] : xr[k-2*H_];
    ss += w*vs; su += w*vu;
  }
  if (do_gate){
    for (int k=tid;k<2*H_;k+=256){
      float m = (k<H_)? csr[k] : cur[k-H_];
      g0 += Wg_w[k]*m;
      g1 += Wg_w[2*H_+k]*m;
      g2 += Wg_w[4*H_+k]*m;
    }
  }
  float SR = block_reduce(sr, red, tid);
  float SS = block_reduce(ss, red, tid);
  float SU = block_reduce(su, red, tid);
  float G0=0,G1=0,G2=0;
  if (do_gate){ G0=block_reduce(g0,red,tid); G1=block_reduce(g1,red,tid); G2=block_reduce(g2,red,tid); }
  if (tid==0){
    float swv = 1.f/(1.f+__expf(-(SR + Wr_b[0])));
    float lcs = SS + Wc_b[0];
    float lcu = SU + Wc_b[0];
    float mx = fmaxf(lcs,lcu);
    float es = __expf(lcs-mx), eu = __expf(lcu-mx);
    float al = es/(es+eu);
    sw_arr[r]=swv; ac_arr[r]=(1.f-swv)*al; bc_arr[r]=(1.f-swv)*(1.f-al);
    if (do_gate){
      gate_out[r*G_+0] = G0 + Wg_b[0];
      gate_out[r*G_+1] = G1 + Wg_b[1];
      gate_out[r*G_+2] = G2 + Wg_b[2];
    }
  }
}

__device__ __forceinline__ frag8 load_cvt8(const float* p){
  float4 a = *(const float4*)p;
  float4 b = *(const float4*)(p+4);
  frag8 r;
  r[0]=(short)f2b(a.x); r[1]=(short)f2b(a.y); r[2]=(short)f2b(a.z); r[3]=(short)f2b(a.w);
  r[4]=(short)f2b(b.x); r[5]=(short)f2b(b.y); r[6]=(short)f2b(b.z); r[7]=(short)f2b(b.w);
  return r;
}

__global__ __launch_bounds__(256) void vocabL_kernel(
    const ushort_t* __restrict__ A, const float* __restrict__ emb,
    float* __restrict__ outp){
  int tid = threadIdx.x;
  int wave = tid>>6, lane = tid&63;
  int q = lane>>4, ln = lane&15;
  int m_base = blockIdx.y*64 + wave*16;
  int n_base = blockIdx.x*64;
  const ushort_t* Arow = A + (size_t)(m_base + ln)*KP;
  int n0 = min(n_base +  0 + ln, V_-1);
  int n1 = min(n_base + 16 + ln, V_-1);
  int n2 = min(n_base + 32 + ln, V_-1);
  int n3 = min(n_base + 48 + ln, V_-1);
  const float* B0 = emb + (size_t)n0*H_;
  const float* B1 = emb + (size_t)n1*H_;
  const float* B2 = emb + (size_t)n2*H_;
  const float* B3 = emb + (size_t)n3*H_;
  f32x4 acc0={0,0,0,0}, acc1={0,0,0,0}, acc2={0,0,0,0}, acc3={0,0,0,0};
  for (int kk=0; kk<KP; kk+=32){
    int ko = kk + q*8;
    int safe = (ko < H_) ? ko : 0;
    frag8 a  = *(const frag8*)(Arow + ko);
    frag8 b0 = load_cvt8(B0 + safe);
    frag8 b1 = load_cvt8(B1 + safe);
    frag8 b2 = load_cvt8(B2 + safe);
    frag8 b3 = load_cvt8(B3 + safe);
    acc0 = __builtin_amdgcn_mfma_f32_16x16x32_bf16(a,b0,acc0,0,0,0);
    acc1 = __builtin_amdgcn_mfma_f32_16x16x32_bf16(a,b1,acc1,0,0,0);
    acc2 = __builtin_amdgcn_mfma_f32_16x16x32_bf16(a,b2,acc2,0,0,0);
    acc3 = __builtin_amdgcn_mfma_f32_16x16x32_bf16(a,b3,acc3,0,0,0);
  }
  int mrow = m_base + q*4;
  #pragma unroll
  for (int nt=0; nt<4; nt++){
    f32x4 acc = (nt==0)?acc0:(nt==1)?acc1:(nt==2)?acc2:acc3;
    int n = n_base + nt*16 + ln;
    if (n >= V_) continue;
    #pragma unroll
    for (int i=0;i<4;i++){
      int m = mrow + i;
      if (m < SB) outp[(size_t)m*TV + n] = acc[i];
    }
  }
}

__global__ __launch_bounds__(256) void softmax_scatterL_kernel(
    const float* __restrict__ sw_arr, const float* __restrict__ ac, const float* __restrict__ bc,
    const float* __restrict__ p_s, const float* __restrict__ p_u,
    const int* __restrict__ story_sys, const int* __restrict__ story_user,
    float* __restrict__ outp){
  __shared__ float red[256];
  int r = blockIdx.x, tid = threadIdx.x;
  float* row = outp + (size_t)r*TV;
  float m = -3.0e38f;
  for (int v=tid; v<V_; v+=256) m = fmaxf(m, row[v]);
  red[tid]=m; __syncthreads();
  for (int s=128;s>0;s>>=1){ if(tid<s) red[tid]=fmaxf(red[tid],red[tid+s]); __syncthreads(); }
  float M = red[0]; __syncthreads();
  float sum = 0.f;
  for (int v=tid; v<V_; v+=256) sum += __expf(row[v] - M);
  red[tid]=sum; __syncthreads();
  for (int s=128;s>0;s>>=1){ if(tid<s) red[tid]+=red[tid+s]; __syncthreads(); }
  float S = red[0]; __syncthreads();
  float scale = sw_arr[r]/S;
  for (int v=tid; v<V_; v+=256) row[v] = __expf(row[v] - M)*scale;
  __syncthreads();
  int b = r & 15;
  float a_ = ac[r], b_ = bc[r];
  for (int i=tid; i<2*L_; i+=256){
    int which = (i >= L_) ? 1 : 0;
    int l = which ? i - L_ : i;
    int v = which ? story_user[b*L_+l] : story_sys[b*L_+l];
    float val = which ? b_*p_u[(size_t)r*L_+l] : a_*p_s[(size_t)r*L_+l];
    atomicAdd(row + v, val);
  }
}

__global__ void nextxL_kernel(const int* __restrict__ targets, const float* __restrict__ emb,
    float* __restrict__ xf, ushort_t* __restrict__ xbf, ushort_t* __restrict__ xbf2, int t){
  int idx = blockIdx.x*256 + threadIdx.x;
  if (idx >= SB*H_) return;
  int r = idx/H_, k = idx - r*H_;
  int s = r>>4, b = r&15;
  int tg = targets[(b*S_ + s)*T_ + t];
  float v = emb[(size_t)tg*H_ + k];
  xf[(size_t)r*H_ + k] = v;
  ushort_t hb = f2b(v);
  xbf [r*KP + k] = hb;
  xbf2[r*KP + k] = f2b(v - b2f(hb));
}

// ================= host =================
extern "C" void kernel_launch(void* const* d_in, const int* in_sizes, int n_in,
                              void* d_out, int out_size, void* d_ws, size_t ws_size,
                              hipStream_t stream){
  const float* sys_H    = (const float*)d_in[0];
  const float* user_H   = (const float*)d_in[1];
  const float* sys_musk = (const float*)d_in[2];
  const float* user_musk= (const float*)d_in[3];
  const float* emb      = (const float*)d_in[4];
  const float* W_ih     = (const float*)d_in[5];
  const float* W_hh     = (const float*)d_in[6];
  const float* b_ih     = (const float*)d_in[7];
  const float* b_hh     = (const float*)d_in[8];
  const float* Wg_w     = (const float*)d_in[9];
  const float* Wg_b     = (const float*)d_in[10];
  const float* Wr_w     = (const float*)d_in[11];
  const float* Wr_b     = (const float*)d_in[12];
  const float* Wc_w     = (const float*)d_in[13];
  const float* Wc_b     = (const float*)d_in[14];
  const float* slot_att = (const float*)d_in[15];
  const float* slot_emb = (const float*)d_in[16];
  const int* story_sys  = (const int*)d_in[17];
  const int* story_user = (const int*)d_in[18];
  const int* targets    = (const int*)d_in[19];
  float* out = (float*)d_out;                      // OUTPUT IS FLOAT32
  float* gate_out = out + (size_t)SB*TV;

  char* base = (char*)d_ws;
  size_t off = 0;
  auto take = [&](size_t bytes)->char*{
    char* p = base + off; off += (bytes + 255) & ~(size_t)255; return p;
  };
  // --- shared (legacy + primary) ---
  ushort_t* Wih_hi = (ushort_t*)take((size_t)NP_G*KP*2);
  ushort_t* Wih_lo = (ushort_t*)take((size_t)NP_G*KP*2);
  ushort_t* Whh_hi = (ushort_t*)take((size_t)NP_G*KP*2);
  ushort_t* Whh_lo = (ushort_t*)take((size_t)NP_G*KP*2);
  ushort_t* hbf0  = (ushort_t*)take((size_t)MP*KP*2);
  ushort_t* hbf20 = (ushort_t*)take((size_t)MP*KP*2);
  float* hf0   = (float*)take((size_t)SB*H_*4);
  float* ctx_s = (float*)take((size_t)SB*H_*4);
  float* ctx_u = (float*)take((size_t)SB*H_*4);
  float* p_s   = (float*)take((size_t)SB*L_*4);
  float* p_u   = (float*)take((size_t)SB*L_*4);
  float* gh    = (float*)take((size_t)SB*3*H_*4);
  // --- legacy-only ---
  float* gi_l  = (float*)take((size_t)SB*3*H_*4);
  float* xf_l  = (float*)take((size_t)SB*H_*4);
  ushort_t* xbf_l  = (ushort_t*)take((size_t)MP*KP*2);
  ushort_t* xbf2_l = (ushort_t*)take((size_t)MP*KP*2);
  float* sw_arr = (float*)take(SB*4);
  float* ac_arr = (float*)take(SB*4);
  float* bc_arr = (float*)take(SB*4);
  size_t off_legacy = off;
  // --- primary-only ---
  ushort_t* hbf1  = (ushort_t*)take((size_t)MP*KP*2);
  ushort_t* hbf21 = (ushort_t*)take((size_t)MP*KP*2);
  float* hf1   = (float*)take((size_t)SB*H_*4);
  float* pmaxw = (float*)take((size_t)MP*NT_VOC*4);
  float* psumw = (float*)take((size_t)MP*NT_VOC*4);
  float* gi_all= (float*)take((size_t)T_*SB*3*H_*4);
  float* xf_all= (float*)take((size_t)T_*SB*H_*4);
  ushort_t* xa_hi = (ushort_t*)take((size_t)T_*MP*KP*2);
  ushort_t* xa_lo = (ushort_t*)take((size_t)T_*MP*KP*2);
  ushort_t* embp  = (ushort_t*)take((size_t)NP_EMB*KP*2);
  float* seqT_s = (float*)take((size_t)B_*H_*L_*4);
  float* seqT_u = (float*)take((size_t)B_*H_*L_*4);
  // double-buffered prob + per-row stat arrays (by t parity)
  float* psb[2] = { (float*)take((size_t)SB*L_*4), (float*)take((size_t)SB*L_*4) };
  float* pub[2] = { (float*)take((size_t)SB*L_*4), (float*)take((size_t)SB*L_*4) };
  float* Mar[2] = { (float*)take(SB*4), (float*)take(SB*4) };
  float* scar[2]= { (float*)take(SB*4), (float*)take(SB*4) };
  float* acar[2]= { (float*)take(SB*4), (float*)take(SB*4) };
  float* bcar[2]= { (float*)take(SB*4), (float*)take(SB*4) };
  size_t off_full = off;

  if (off_full <= ws_size){
    // ============ primary path: 25 dispatches ============
    setup1_kernel<<<SETUP1_UNITS,256,0,stream>>>(
        sys_H, user_H, seqT_s, seqT_u, slot_att, slot_emb,
        xf_all, xa_hi, xa_lo, hbf0, hbf20, hbf1, hbf21, hf0,
        targets, emb, W_ih, Wih_hi, Wih_lo, W_hh, Whh_hi, Whh_lo, embp);
    pre_kernel<<<PRE_UNITS,256,0,stream>>>(
        sys_H, seqT_s, sys_musk, user_H, seqT_u, user_musk,
        hf0, ctx_s, psb[1], ctx_u, pub[1],
        xa_hi, xa_lo, Wih_hi, Wih_lo, gi_all);
    // gg0v2: gh = bf16hl(ctx_s+ctx_u) @ Whh  (also writes hf0 = ctx_s+ctx_u)
    gg0v2_kernel<<<GG_T,256,0,stream>>>(ctx_s, ctx_u, Whh_hi, Whh_lo, gh, hf0);
    // gru(0): h(0) -> buf1
    gru0_kernel<<<SB,256,0,stream>>>(gi_all, gh, b_ih, b_hh, hf0, hf1, hbf1, hbf21);

    float* hfb[2]      = { hf0, hf1 };
    ushort_t* hbfb[2]  = { hbf0, hbf1 };
    ushort_t* hbf2b[2] = { hbf20, hbf21 };
    for (int t=0; t<T_; t++){
      int cur = (t+1)&1;     // h(t) lives here
      int nxt = t&1;         // gru(t+1) writes here
      int ngg = (t < T_-1) ? 1 : 0;
      int base_off = (t > 0) ? 0 : FZ_BLKS;   // skip finalize role entirely at t=0
      int grid = MEGAC_BLKS - base_off;
      int pc = t&1;                   // attend(t) prob parity
      int pp = (t-1)&1;               // finalize(t-1) parity
      float* outp = out + (size_t)t*V_;
      float* outprev = out + (size_t)(t>0 ? t-1 : 0)*V_;
      megaC_kernel<<<grid,256,0,stream>>>(
          sys_H, seqT_s, sys_musk, user_H, seqT_u, user_musk,
          hfb[cur], hbfb[cur], hbf2b[cur],
          ctx_s, psb[pc], ctx_u, pub[pc],
          embp, outp, pmaxw, psumw,
          Whh_hi, Whh_lo, gh, ngg,
          outprev, Mar[pp], scar[pp], acar[pp], bcar[pp],
          psb[pp], pub[pp], story_sys, story_user, base_off);
      finalstats_kernel<<<SB,256,0,stream>>>(
          hfb[cur], ctx_s, ctx_u, xf_all + (size_t)t*SB*H_,
          Wr_w, Wr_b, Wc_w, Wc_b, Wg_w, Wg_b,
          pmaxw, psumw,
          Mar[t&1], scar[t&1], acar[t&1], bcar[t&1],
          gate_out, (t==0)?1:0,
          gi_all + (size_t)(t<T_-1 ? t+1 : 0)*SB*3*H_, gh, b_ih, b_hh,
          hfb[nxt], hbfb[nxt], hbf2b[nxt], (t<T_-1)?1:0);
    }
    // tail finalize for t = T-1 (parity (T-1)&1 = 1)
    finalize_kernel<<<FZ_BLKS,256,0,stream>>>(
        out + (size_t)(T_-1)*V_, Mar[1], scar[1], acar[1], bcar[1],
        psb[1], pub[1], story_sys, story_user);
    return;
  }

  if (off_legacy <= ws_size){
    // ============ legacy basic path ============
    padsplit_kernel<<<(NP_G*KP+255)/256,256,0,stream>>>(W_ih, Wih_hi, Wih_lo);
    padsplit_kernel<<<(NP_G*KP+255)/256,256,0,stream>>>(W_hh, Whh_hi, Whh_lo);
    initL_kernel<<<(MP*KP+255)/256,256,0,stream>>>(slot_att, slot_emb, xf_l, xbf_l, xbf2_l,
                                                   hbf0, hbf20, hf0);
    attendL_kernel<<<SB,256,0,stream>>>(sys_H, sys_musk, hf0, ctx_s, p_s);
    attendL_kernel<<<SB,256,0,stream>>>(user_H, user_musk, hf0, ctx_u, p_u);
    addh_kernel<<<(SB*H_+255)/256,256,0,stream>>>(ctx_s, ctx_u, hf0, hbf0, hbf20);
    for (int t=0; t<T_; t++){
      grugemmL_kernel<<<dim3(NP_G/64, MP/64),256,0,stream>>>(xbf_l, xbf2_l, hbf0, hbf20,
          Wih_hi, Wih_lo, Whh_hi, Whh_lo, gi_l, gh);
      gruL_kernel<<<(SB*H_+255)/256,256,0,stream>>>(gi_l, gh, b_ih, b_hh, hf0, hbf0, hbf20);
      attendL_kernel<<<SB,256,0,stream>>>(sys_H, sys_musk, hf0, ctx_s, p_s);
      attendL_kernel<<<SB,256,0,stream>>>(user_H, user_musk, hf0, ctx_u, p_u);
      smallL_kernel<<<SB,256,0,stream>>>(hf0, ctx_s, ctx_u, xf_l, Wr_w, Wr_b, Wc_w, Wc_b,
                                         Wg_w, Wg_b, sw_arr, ac_arr, bc_arr, gate_out, (t==0)?1:0);
      float* outp = out + (size_t)t*V_;
      vocabL_kernel<<<dim3(NT_VOC, MP/64),256,0,stream>>>(hbf0, emb, outp);
      softmax_scatterL_kernel<<<SB,256,0,stream>>>(sw_arr, ac_arr, bc_arr, p_s, p_u,
                                                   story_sys, story_user, outp);
      if (t < T_-1)
        nextxL_kernel<<<(SB*H_+255)/256,256,0,stream>>>(targets, emb, xf_l, xbf_l, xbf2_l, t);
    }
  }
}

// Round 9
// 1467.395 us; speedup vs baseline: 1.0472x; 1.0472x over previous
//
#include <hip/hip_runtime.h>
#include <stdint.h>

#define B_ 16
#define S_ 30
#define T_ 10
#define H_ 400
#define V_ 20000
#define L_ 200
#define G_ 3
#define SB 480          // S*B rows
#define KP 416          // padded K (13*32)
#define MP 512          // padded M rows (8*64)
#define NT_VOC 313      // ceil(20000/64)
#define NP_G 1216       // padded 3H rows (19*64)
#define NP_EMB 20096    // padded V rows (314*64)
#define TV (T_*V_)      // 200000

#define GG_T 152        // 19*8 hh tiles per t
#define GIA_UNITS (T_*GG_T)         // 1520

// attention v3: one block per (which,b,row-group)
#define ATT_ROWS 6
#define ATT_NRB 5                   // 30/6
#define ATT3_BLKS (2*B_*ATT_NRB)    // 160
// vocab with XCD-chunked swizzle: 8 chunks x 40 nb x 8 mb
#define VOC_PAD 2560
// finalize role: 2-way split rows (R7-verified config)
#define FZ_SPLIT 2
#define FZ_SEG (V_/FZ_SPLIT)        // 10000
#define FZ_BLKS (SB*FZ_SPLIT)       // 960 (%8==0)
#define GG_PAD 160                  // GG_T padded to keep vocab offset %8==0
#define MEGAC_BLKS (FZ_BLKS + ATT3_BLKS + GG_PAD + VOC_PAD)   // 3840

#define PRE_UNITS (ATT3_BLKS + GIA_UNITS)

// setup1 role counts
#define TT_TILES 1456   // 16 * 7 * 13 transpose tiles
#define INIT_BLKS 832   // MP*KP/256
#define XA8_BLKS 936    // 9*MP*KP/(256*8)
#define PS8_BLKS 247    // NP_G*KP/(256*8)
#define EC8_BLKS 4082   // NP_EMB*KP/(256*8)
#define SETUP1_UNITS (2*TT_TILES + INIT_BLKS + XA8_BLKS + 2*PS8_BLKS + EC8_BLKS)

typedef unsigned short ushort_t;
typedef __attribute__((ext_vector_type(8))) short frag8;       // 8 bf16
typedef __attribute__((ext_vector_type(8))) unsigned short us8;
typedef __attribute__((ext_vector_type(4))) float f32x4;

__device__ __forceinline__ float b2f(ushort_t u){ return __uint_as_float(((unsigned)u)<<16); }
__device__ __forceinline__ ushort_t f2b(float f){
  unsigned u = __float_as_uint(f);
  unsigned r = u + 0x7fffu + ((u>>16)&1u);   // RNE
  return (ushort_t)(r>>16);
}

// ================= setup bodies =================

__device__ __forceinline__ void padsplit8_body(const float* __restrict__ src,
    ushort_t* __restrict__ hi, ushort_t* __restrict__ lo, int u8){
  int base = u8*8;
  if (base >= NP_G*KP) return;
  int r = base / KP, c = base - r*KP;
  us8 h, l;
  if (r < 3*H_ && c+8 <= H_){
    float4 a = *(const float4*)(src + (size_t)r*H_ + c);
    float4 b = *(const float4*)(src + (size_t)r*H_ + c + 4);
    float v[8] = {a.x,a.y,a.z,a.w,b.x,b.y,b.z,b.w};
    #pragma unroll
    for (int i=0;i<8;i++){ h[i]=f2b(v[i]); l[i]=f2b(v[i]-b2f(h[i])); }
  } else {
    #pragma unroll
    for (int i=0;i<8;i++){ h[i]=0; l[i]=0; }
  }
  *(us8*)(hi+base) = h; *(us8*)(lo+base) = l;
}

__device__ __forceinline__ void embcvt8_body(const float* __restrict__ emb,
    ushort_t* __restrict__ dst, long long u8){
  long long base = u8*8;
  if (base >= (long long)NP_EMB*KP) return;
  int r = (int)(base / KP), c = (int)(base - (long long)r*KP);
  us8 h;
  if (r < V_ && c+8 <= H_){
    float4 a = *(const float4*)(emb + (size_t)r*H_ + c);
    float4 b = *(const float4*)(emb + (size_t)r*H_ + c + 4);
    float v[8] = {a.x,a.y,a.z,a.w,b.x,b.y,b.z,b.w};
    #pragma unroll
    for (int i=0;i<8;i++) h[i]=f2b(v[i]);
  } else {
    #pragma unroll
    for (int i=0;i<8;i++) h[i]=0;
  }
  *(us8*)(dst+base) = h;
}

__device__ __forceinline__ void xallcvt8_body(const int* __restrict__ targets,
    const float* __restrict__ emb, float* __restrict__ xf_all,
    ushort_t* __restrict__ xa_hi, ushort_t* __restrict__ xa_lo, int u8){
  long long base = (long long)u8*8;
  if (base >= (long long)(T_-1)*MP*KP) return;
  int t = (int)(base / ((long long)MP*KP)) + 1;
  int rem = (int)(base - (long long)(t-1)*MP*KP);
  int r = rem / KP, c = rem - r*KP;
  size_t off = (size_t)t*MP*KP + rem;
  us8 h, l;
  if (r < SB && c+8 <= H_){
    int s = r>>4, b = r&15;
    int tg = targets[(b*S_ + s)*T_ + (t-1)];
    float4 a = *(const float4*)(emb + (size_t)tg*H_ + c);
    float4 bb= *(const float4*)(emb + (size_t)tg*H_ + c + 4);
    float v[8] = {a.x,a.y,a.z,a.w,bb.x,bb.y,bb.z,bb.w};
    float* xfp = xf_all + (size_t)t*SB*H_ + (size_t)r*H_ + c;
    *(float4*)xfp = a; *(float4*)(xfp+4) = bb;
    #pragma unroll
    for (int i=0;i<8;i++){ h[i]=f2b(v[i]); l[i]=f2b(v[i]-b2f(h[i])); }
  } else {
    #pragma unroll
    for (int i=0;i<8;i++){ h[i]=0; l[i]=0; }
  }
  *(us8*)(xa_hi+off) = h; *(us8*)(xa_lo+off) = l;
}

__device__ __forceinline__ void transpose_body(const float* __restrict__ src,
    float* __restrict__ dst, int rel, int tid, float (*tile)[33]){
  int b  = rel / 91;           // 7*13 tiles per b
  int rem = rel - b*91;
  int l0 = (rem % 7)*32, k0 = (rem / 7)*32;
  int tx = tid & 31, ty = tid >> 5;   // 32 x 8
  const float* s = src + (size_t)b*L_*H_;
  float*       d = dst + (size_t)b*H_*L_;
  #pragma unroll
  for (int i=ty; i<32; i+=8){
    int l = l0+i, k = k0+tx;
    tile[i][tx] = (l<L_ && k<H_) ? s[(size_t)l*H_ + k] : 0.f;
  }
  __syncthreads();
  #pragma unroll
  for (int i=ty; i<32; i+=8){
    int k = k0+i, l = l0+tx;
    if (k<H_ && l<L_) d[(size_t)k*L_ + l] = tile[tx][i];
  }
  __syncthreads();
}

__device__ __forceinline__ void init2_body(const float* __restrict__ slot_att,
    const float* __restrict__ slot_emb,
    float* __restrict__ xf_all, ushort_t* __restrict__ xa_hi, ushort_t* __restrict__ xa_lo,
    ushort_t* __restrict__ hbfA, ushort_t* __restrict__ hbf2A,
    ushort_t* __restrict__ hbfB, ushort_t* __restrict__ hbf2B,
    float* __restrict__ hfA, int idx){
  if (idx >= MP*KP) return;
  int r = idx/KP, c = idx - r*KP;
  ushort_t xh = 0, xl = 0;
  if (r < SB && c < H_){
    int s = r >> 4;
    float xv = slot_emb[s*H_ + c];
    xf_all[(size_t)r*H_ + c] = xv;
    xh = f2b(xv); xl = f2b(xv - b2f(xh));
    hfA[(size_t)r*H_ + c] = slot_att[s*H_ + c];
  }
  xa_hi[idx] = xh; xa_lo[idx] = xl;
  hbfA[idx] = 0; hbf2A[idx] = 0;
  hbfB[idx] = 0; hbf2B[idx] = 0;
}

__global__ __launch_bounds__(256) void setup1_kernel(
    const float* __restrict__ sys_H, const float* __restrict__ user_H,
    float* __restrict__ seqT_s, float* __restrict__ seqT_u,
    const float* __restrict__ slot_att, const float* __restrict__ slot_emb,
    float* __restrict__ xf_all, ushort_t* __restrict__ xa_hi, ushort_t* __restrict__ xa_lo,
    ushort_t* __restrict__ hbfA, ushort_t* __restrict__ hbf2A,
    ushort_t* __restrict__ hbfB, ushort_t* __restrict__ hbf2B,
    float* __restrict__ hfA,
    const int* __restrict__ targets, const float* __restrict__ emb,
    const float* __restrict__ W_ih, ushort_t* __restrict__ Wih_hi, ushort_t* __restrict__ Wih_lo,
    const float* __restrict__ W_hh, ushort_t* __restrict__ Whh_hi, ushort_t* __restrict__ Whh_lo,
    ushort_t* __restrict__ embp){
  __shared__ float tile[32][33];
  int bid = blockIdx.x, tid = threadIdx.x;
  int u = bid;
  if (u < TT_TILES){ transpose_body(sys_H, seqT_s, u, tid, tile); return; }
  u -= TT_TILES;
  if (u < TT_TILES){ transpose_body(user_H, seqT_u, u, tid, tile); return; }
  u -= TT_TILES;
  if (u < INIT_BLKS){
    init2_body(slot_att, slot_emb, xf_all, xa_hi, xa_lo, hbfA, hbf2A, hbfB, hbf2B, hfA,
               u*256 + tid);
    return;
  }
  u -= INIT_BLKS;
  if (u < XA8_BLKS){ xallcvt8_body(targets, emb, xf_all, xa_hi, xa_lo, u*256 + tid); return; }
  u -= XA8_BLKS;
  if (u < PS8_BLKS){ padsplit8_body(W_ih, Wih_hi, Wih_lo, u*256 + tid); return; }
  u -= PS8_BLKS;
  if (u < PS8_BLKS){ padsplit8_body(W_hh, Whh_hi, Whh_lo, u*256 + tid); return; }
  u -= PS8_BLKS;
  embcvt8_body(emb, embp, (long long)u*256 + tid);
}

// ================= attention v3 (R7-verified unroll-4) =================
__device__ void attend3_body(
    int u,
    const float* __restrict__ seqS, const float* __restrict__ seqTS, const float* __restrict__ muskS,
    const float* __restrict__ seqU, const float* __restrict__ seqTU, const float* __restrict__ muskU,
    const float* __restrict__ cond,
    float* __restrict__ ctxS, float* __restrict__ probS,
    float* __restrict__ ctxU, float* __restrict__ probU,
    float (*cond_l)[H_], float (*S_l)[208], float* smax, float* ssum){
  int which = (u >= B_*ATT_NRB) ? 1 : 0;
  int v = which ? u - B_*ATT_NRB : u;
  int b = v / ATT_NRB, rb = v - b*ATT_NRB;
  const float* seq  = which ? seqU  : seqS;
  const float* seqT = which ? seqTU : seqTS;
  const float* musk = which ? muskU : muskS;
  float* ctx  = which ? ctxU  : ctxS;
  float* prob = which ? probU : probS;
  int tid = threadIdx.x;
  int s0 = rb*ATT_ROWS;
  for (int idx=tid; idx<ATT_ROWS*H_; idx+=256){
    int i = idx/H_, k = idx - i*H_;
    cond_l[i][k] = cond[(size_t)((s0+i)*16 + b)*H_ + k];
  }
  __syncthreads();
  if (tid < L_){
    const float* sp = seqT + (size_t)b*H_*L_ + tid;
    float acc[ATT_ROWS];
    #pragma unroll
    for (int i=0;i<ATT_ROWS;i++) acc[i]=0.f;
    for (int k=0;k<H_;k+=4){
      float v0 = sp[(size_t)(k  )*L_];
      float v1 = sp[(size_t)(k+1)*L_];
      float v2 = sp[(size_t)(k+2)*L_];
      float v3 = sp[(size_t)(k+3)*L_];
      #pragma unroll
      for (int i=0;i<ATT_ROWS;i++){
        float4 c = *(const float4*)&cond_l[i][k];
        acc[i] += c.x*v0; acc[i] += c.y*v1; acc[i] += c.z*v2; acc[i] += c.w*v3;
      }
    }
    float mk = musk[b*L_ + tid];
    #pragma unroll
    for (int i=0;i<ATT_ROWS;i++) S_l[i][tid] = acc[i] + mk;
  }
  __syncthreads();
  if (tid < ATT_ROWS*16){
    int i = tid >> 4, sub = tid & 15;
    float m = -3.0e38f;
    for (int l=sub; l<L_; l+=16) m = fmaxf(m, S_l[i][l]);
    #pragma unroll
    for (int d=8; d>=1; d>>=1) m = fmaxf(m, __shfl_xor(m, d));
    float sm = 0.f;
    for (int l=sub; l<L_; l+=16) sm += __expf(S_l[i][l] - m);
    #pragma unroll
    for (int d=8; d>=1; d>>=1) sm += __shfl_xor(sm, d);
    if (sub==0){ smax[i] = m; ssum[i] = sm; }
  }
  __syncthreads();
  for (int idx=tid; idx<ATT_ROWS*L_; idx+=256){
    int i = idx/L_, l = idx - i*L_;
    float p = __expf(S_l[i][l] - smax[i]) / ssum[i];
    S_l[i][l] = p;
    prob[(size_t)((s0+i)*16 + b)*L_ + l] = p;
  }
  __syncthreads();
  for (int k=tid; k<H_; k+=256){
    const float* sp2 = seq + (size_t)b*L_*H_ + k;
    float acc[ATT_ROWS];
    #pragma unroll
    for (int i=0;i<ATT_ROWS;i++) acc[i]=0.f;
    for (int l=0;l<L_;l+=4){
      float v0 = sp2[(size_t)(l  )*H_];
      float v1 = sp2[(size_t)(l+1)*H_];
      float v2 = sp2[(size_t)(l+2)*H_];
      float v3 = sp2[(size_t)(l+3)*H_];
      #pragma unroll
      for (int i=0;i<ATT_ROWS;i++){
        float4 pp = *(const float4*)&S_l[i][l];
        acc[i] += pp.x*v0; acc[i] += pp.y*v1; acc[i] += pp.z*v2; acc[i] += pp.w*v3;
      }
    }
    #pragma unroll
    for (int i=0;i<ATT_ROWS;i++)
      ctx[(size_t)((s0+i)*16 + b)*H_ + k] = acc[i];
  }
}

// ================= hi/lo GEMM tile =================
__device__ __forceinline__ void hl_gemm_tile(
    const ushort_t* __restrict__ A_hi, const ushort_t* __restrict__ A_lo,
    const ushort_t* __restrict__ B_hi, const ushort_t* __restrict__ B_lo,
    float* __restrict__ outg, int nb, int mb, int tid){
  int wave = tid>>6, lane = tid&63;
  int q = lane>>4, ln = lane&15;
  int m_base = mb*64 + wave*16;
  int n_base = nb*64;
  const ushort_t* Ah  = A_hi + (size_t)(m_base + ln)*KP;
  const ushort_t* Ah2 = A_lo + (size_t)(m_base + ln)*KP;
  f32x4 ah[4];
  #pragma unroll
  for (int nt=0;nt<4;nt++) ah[nt]=(f32x4){0,0,0,0};
  for (int kk=0; kk<KP; kk+=32){
    int ko = kk + q*8;
    frag8 ahv = *(const frag8*)(Ah  + ko);
    frag8 ah2 = *(const frag8*)(Ah2 + ko);
    #pragma unroll
    for (int nt=0;nt<4;nt++){
      size_t nrow = (size_t)(n_base + nt*16 + ln)*KP + ko;
      frag8 bhh = *(const frag8*)(B_hi + nrow);
      frag8 bhl = *(const frag8*)(B_lo + nrow);
      ah[nt] = __builtin_amdgcn_mfma_f32_16x16x32_bf16(ahv,bhh, ah[nt],0,0,0);
      ah[nt] = __builtin_amdgcn_mfma_f32_16x16x32_bf16(ahv,bhl, ah[nt],0,0,0);
      ah[nt] = __builtin_amdgcn_mfma_f32_16x16x32_bf16(ah2,bhh, ah[nt],0,0,0);
    }
  }
  int mrow = m_base + q*4;
  #pragma unroll
  for (int nt=0; nt<4; nt++){
    int n = n_base + nt*16 + ln;
    if (n >= 3*H_) continue;
    #pragma unroll
    for (int i=0;i<4;i++){
      int m = mrow + i;
      if (m < SB) outg[(size_t)m*(3*H_) + n] = ah[nt][i];
    }
  }
}

// ---------- pre: h0 attend (160) + gi_all GEMM (1520 tiles) ----------
__global__ __launch_bounds__(256) void pre_kernel(
    const float* __restrict__ seqS, const float* __restrict__ seqTS, const float* __restrict__ muskS,
    const float* __restrict__ seqU, const float* __restrict__ seqTU, const float* __restrict__ muskU,
    const float* __restrict__ cond,
    float* __restrict__ ctxS, float* __restrict__ probS,
    float* __restrict__ ctxU, float* __restrict__ probU,
    const ushort_t* __restrict__ xa_hi, const ushort_t* __restrict__ xa_lo,
    const ushort_t* __restrict__ Wih_hi, const ushort_t* __restrict__ Wih_lo,
    float* __restrict__ gi_all){
  __shared__ float cond_l[ATT_ROWS][H_];
  __shared__ float S_l[ATT_ROWS][208];
  __shared__ float smax[ATT_ROWS], ssum[ATT_ROWS];
  int u = blockIdx.x, tid = threadIdx.x;
  if (u < ATT3_BLKS){
    attend3_body(u, seqS, seqTS, muskS, seqU, seqTU, muskU, cond,
                 ctxS, probS, ctxU, probU, cond_l, S_l, smax, ssum);
    return;
  }
  u -= ATT3_BLKS;
  int t = u / GG_T, rem = u - t*GG_T;
  hl_gemm_tile(xa_hi + (size_t)t*MP*KP, xa_lo + (size_t)t*MP*KP,
               Wih_hi, Wih_lo, gi_all + (size_t)t*SB*(3*H_),
               rem % 19, rem / 19, tid);
}

// ---------- gg0v2: hh GEMM for t'=0 with on-the-fly A = bf16(cs+cu); also writes hf0 ----------
__global__ __launch_bounds__(256) void gg0v2_kernel(
    const float* __restrict__ cs, const float* __restrict__ cu,
    const ushort_t* __restrict__ Whh_hi, const ushort_t* __restrict__ Whh_lo,
    float* __restrict__ gh, float* __restrict__ hf0){
  int u = blockIdx.x, tid = threadIdx.x;
  int nb = u % 19, mb = u / 19;
  int wave = tid>>6, lane = tid&63;
  int q = lane>>4, ln = lane&15;
  int m_base = mb*64 + wave*16;
  int n_base = nb*64;
  int row = m_base + ln;
  f32x4 ah[4];
  #pragma unroll
  for (int nt=0;nt<4;nt++) ah[nt]=(f32x4){0,0,0,0};
  for (int kk=0; kk<KP; kk+=32){
    int ko = kk + q*8;
    frag8 ahv, ah2;
    if (row < SB && ko < H_){
      const float* c1 = cs + (size_t)row*H_ + ko;
      const float* c2 = cu + (size_t)row*H_ + ko;
      float4 a = *(const float4*)c1, b = *(const float4*)(c1+4);
      float4 e = *(const float4*)c2, f = *(const float4*)(c2+4);
      float v[8] = {a.x+e.x, a.y+e.y, a.z+e.z, a.w+e.w,
                    b.x+f.x, b.y+f.y, b.z+f.z, b.w+f.w};
      #pragma unroll
      for (int i=0;i<8;i++){
        ushort_t hb = f2b(v[i]);
        ahv[i] = (short)hb;
        ah2[i] = (short)f2b(v[i] - b2f(hb));
      }
      if (nb == 0){
        float* hp = hf0 + (size_t)row*H_ + ko;
        *(float4*)hp     = (float4){v[0],v[1],v[2],v[3]};
        *(float4*)(hp+4) = (float4){v[4],v[5],v[6],v[7]};
      }
    } else {
      #pragma unroll
      for (int i=0;i<8;i++){ ahv[i]=0; ah2[i]=0; }
    }
    #pragma unroll
    for (int nt=0;nt<4;nt++){
      size_t nrow = (size_t)(n_base + nt*16 + ln)*KP + ko;
      frag8 bhh = *(const frag8*)(Whh_hi + nrow);
      frag8 bhl = *(const frag8*)(Whh_lo + nrow);
      ah[nt] = __builtin_amdgcn_mfma_f32_16x16x32_bf16(ahv,bhh, ah[nt],0,0,0);
      ah[nt] = __builtin_amdgcn_mfma_f32_16x16x32_bf16(ahv,bhl, ah[nt],0,0,0);
      ah[nt] = __builtin_amdgcn_mfma_f32_16x16x32_bf16(ah2,bhh, ah[nt],0,0,0);
    }
  }
  int mrow = m_base + q*4;
  #pragma unroll
  for (int nt=0; nt<4; nt++){
    int n = n_base + nt*16 + ln;
    if (n >= 3*H_) continue;
    #pragma unroll
    for (int i=0;i<4;i++){
      int m = mrow + i;
      if (m < SB) gh[(size_t)m*(3*H_) + n] = ah[nt][i];
    }
  }
}

// ---------- GRU row ----------
__device__ __forceinline__ void gru_row(int r,
    const float* __restrict__ gia_t, const float* __restrict__ gh,
    const float* __restrict__ b_ih, const float* __restrict__ b_hh,
    const float* __restrict__ hold, float* __restrict__ hfw,
    ushort_t* __restrict__ hbfw, ushort_t* __restrict__ hbf2w, int tid){
  const float* gir = gia_t + (size_t)r*(3*H_);
  const float* ghr = gh    + (size_t)r*(3*H_);
  for (int j=tid; j<H_; j+=256){
    float i_r = gir[j]      + b_ih[j];
    float i_z = gir[H_+j]   + b_ih[H_+j];
    float i_n = gir[2*H_+j] + b_ih[2*H_+j];
    float h_r = ghr[j]      + b_hh[j];
    float h_z = ghr[H_+j]   + b_hh[H_+j];
    float h_n = ghr[2*H_+j] + b_hh[2*H_+j];
    float rg = 1.f/(1.f+__expf(-(i_r+h_r)));
    float zg = 1.f/(1.f+__expf(-(i_z+h_z)));
    float ng = tanhf(i_n + rg*h_n);
    float hv = (1.f-zg)*ng + zg*hold[(size_t)r*H_ + j];
    hfw[(size_t)r*H_ + j] = hv;
    ushort_t hb = f2b(hv);
    hbfw [r*KP + j] = hb;
    hbf2w[r*KP + j] = f2b(hv - b2f(hb));
  }
}

__global__ __launch_bounds__(256) void gru0_kernel(
    const float* __restrict__ gia_t, const float* __restrict__ gh,
    const float* __restrict__ b_ih, const float* __restrict__ b_hh,
    const float* __restrict__ hold, float* __restrict__ hfw,
    ushort_t* __restrict__ hbfw, ushort_t* __restrict__ hbf2w){
  gru_row(blockIdx.x, gia_t, gh, b_ih, b_hh, hold, hfw, hbfw, hbf2w, threadIdx.x);
}

// ---------- vocab GEMM tile ----------
__device__ __forceinline__ void vocab_tile(
    const ushort_t* __restrict__ A, const ushort_t* __restrict__ Bm,
    float* __restrict__ outp, float* __restrict__ pmax, float* __restrict__ psum,
    int nb, int mb, int tid){
  int wave = tid>>6, lane = tid&63;
  int q = lane>>4, ln = lane&15;
  int m_base = mb*64 + wave*16;
  int n_base = nb*64;
  const ushort_t* Arow = A + (size_t)(m_base + ln)*KP;
  f32x4 acc[4];
  #pragma unroll
  for (int nt=0;nt<4;nt++) acc[nt]=(f32x4){0,0,0,0};
  for (int kk=0; kk<KP; kk+=32){
    int ko = kk + q*8;
    frag8 a  = *(const frag8*)(Arow + ko);
    #pragma unroll
    for (int nt=0;nt<4;nt++){
      frag8 b = *(const frag8*)(Bm + (size_t)(n_base + nt*16 + ln)*KP + ko);
      acc[nt] = __builtin_amdgcn_mfma_f32_16x16x32_bf16(a,b,acc[nt],0,0,0);
    }
  }
  int mrow = m_base + q*4;
  #pragma unroll
  for (int nt=0; nt<4; nt++){
    int n = n_base + nt*16 + ln;
    if (n >= V_) continue;
    #pragma unroll
    for (int i=0;i<4;i++){
      int m = mrow + i;
      if (m < SB) outp[(size_t)m*TV + n] = acc[nt][i];
    }
  }
  #pragma unroll
  for (int i=0;i<4;i++){
    float mx = -3.0e38f;
    #pragma unroll
    for (int nt=0;nt<4;nt++){
      int n = n_base + nt*16 + ln;
      if (n < V_) mx = fmaxf(mx, acc[nt][i]);
    }
    #pragma unroll
    for (int d=8; d>=1; d>>=1) mx = fmaxf(mx, __shfl_xor(mx, d));
    float sm = 0.f;
    #pragma unroll
    for (int nt=0;nt<4;nt++){
      int n = n_base + nt*16 + ln;
      if (n < V_) sm += __expf(acc[nt][i] - mx);
    }
    #pragma unroll
    for (int d=8; d>=1; d>>=1) sm += __shfl_xor(sm, d);
    int m = mrow + i;
    if (ln == 0 && m < SB){
      pmax[(size_t)m*NT_VOC + nb] = mx;
      psum[(size_t)m*NT_VOC + nb] = sm;
    }
  }
}

// ---------- finalize: one (row, part) — scale pass + range-filtered scatter ----------
__device__ __forceinline__ void finalize_row_part(int r, int part,
    float* __restrict__ out_prev,
    const float* __restrict__ Marr, const float* __restrict__ scarr,
    const float* __restrict__ acarr, const float* __restrict__ bcarr,
    const float* __restrict__ ps, const float* __restrict__ pu,
    const int* __restrict__ story_sys, const int* __restrict__ story_user, int tid){
  int v0 = part*FZ_SEG, v1 = v0 + FZ_SEG;
  float M = Marr[r], sc = scarr[r];
  float* row = out_prev + (size_t)r*TV;
  for (int v=v0+tid; v<v1; v+=256) row[v] = __expf(row[v]-M)*sc;
  __syncthreads();    // drain scale-writes before atomics (same block owns this v-range)
  int b = r & 15;
  float a_ = acarr[r], b_ = bcarr[r];
  for (int i=tid; i<2*L_; i+=256){
    int which = (i >= L_) ? 1 : 0;
    int l = which ? i - L_ : i;
    int v = which ? story_user[b*L_+l] : story_sys[b*L_+l];
    if (v < v0 || v >= v1) continue;
    float val = which ? b_*pu[(size_t)r*L_+l] : a_*ps[(size_t)r*L_+l];
    atomicAdd(row + v, val);
  }
}

// ================= megaC: finalize(t-1) first (long poles), then attend, gg, vocab =================
__global__ __launch_bounds__(256) void megaC_kernel(
    const float* __restrict__ seqS, const float* __restrict__ seqTS, const float* __restrict__ muskS,
    const float* __restrict__ seqU, const float* __restrict__ seqTU, const float* __restrict__ muskU,
    const float* __restrict__ hf_r,
    const ushort_t* __restrict__ hbf_r, const ushort_t* __restrict__ hbf2_r,
    float* __restrict__ ctxS, float* __restrict__ probS,
    float* __restrict__ ctxU, float* __restrict__ probU,
    const ushort_t* __restrict__ embp, float* __restrict__ outp,
    float* __restrict__ pmax, float* __restrict__ psum,
    const ushort_t* __restrict__ Whh_hi, const ushort_t* __restrict__ Whh_lo,
    float* __restrict__ gh, int ngg,
    float* __restrict__ out_prev,
    const float* __restrict__ Marr, const float* __restrict__ scarr,
    const float* __restrict__ acarr, const float* __restrict__ bcarr,
    const float* __restrict__ ps_prev, const float* __restrict__ pu_prev,
    const int* __restrict__ story_sys, const int* __restrict__ story_user,
    int base_off){
  __shared__ float cond_l[ATT_ROWS][H_];
  __shared__ float S_l[ATT_ROWS][208];
  __shared__ float smax[ATT_ROWS], ssum[ATT_ROWS];
  int u = blockIdx.x + base_off, tid = threadIdx.x;
  if (u < FZ_BLKS){
    finalize_row_part(u>>1, u&1, out_prev, Marr, scarr, acarr, bcarr,
                      ps_prev, pu_prev, story_sys, story_user, tid);
    return;
  }
  u -= FZ_BLKS;
  if (u < ATT3_BLKS){
    attend3_body(u, seqS, seqTS, muskS, seqU, seqTU, muskU, hf_r,
                 ctxS, probS, ctxU, probU, cond_l, S_l, smax, ssum);
    return;
  }
  u -= ATT3_BLKS;
  if (u < GG_PAD){
    if (u < GG_T && ngg)
      hl_gemm_tile(hbf_r, hbf2_r, Whh_hi, Whh_lo, gh, u % 19, u / 19, tid);
    return;
  }
  u -= GG_PAD;
  // vocab: XCD-chunked swizzle (role offset 1280 and base_off 0/960 are %8==0)
  int x = u & 7, j = u >> 3;
  int nb = x*40 + (j>>3), mb = j & 7;
  if (nb < NT_VOC)
    vocab_tile(hbf_r, embp, outp, pmax, psum, nb, mb, tid);
}

// ================= finalstats: gru(t+1) + per-row scalars + softmax stats =================
__device__ __forceinline__ float block_reduce(float v, float* red, int tid){
  red[tid]=v; __syncthreads();
  for (int s=128;s>0;s>>=1){ if(tid<s) red[tid]+=red[tid+s]; __syncthreads(); }
  float r = red[0]; __syncthreads();
  return r;
}

__global__ __launch_bounds__(256) void finalstats_kernel(
    const float* __restrict__ hf_r, const float* __restrict__ cs, const float* __restrict__ cu,
    const float* __restrict__ xf_t,
    const float* __restrict__ Wr_w, const float* __restrict__ Wr_b,
    const float* __restrict__ Wc_w, const float* __restrict__ Wc_b,
    const float* __restrict__ Wg_w, const float* __restrict__ Wg_b,
    const float* __restrict__ pmax, const float* __restrict__ psum,
    float* __restrict__ Marr, float* __restrict__ scarr,
    float* __restrict__ acarr, float* __restrict__ bcarr,
    float* __restrict__ gate_out, int do_gate,
    const float* __restrict__ gia_t1, const float* __restrict__ gh,
    const float* __restrict__ b_ih, const float* __restrict__ b_hh,
    float* __restrict__ hf_w, ushort_t* __restrict__ hbf_w, ushort_t* __restrict__ hbf2_w,
    int do_gru){
  __shared__ float red[256];
  int r = blockIdx.x, tid = threadIdx.x;
  if (do_gru)
    gru_row(r, gia_t1, gh, b_ih, b_hh, hf_r, hf_w, hbf_w, hbf2_w, tid);
  const float* h   = hf_r + (size_t)r*H_;
  const float* csr = cs + (size_t)r*H_;
  const float* cur = cu + (size_t)r*H_;
  const float* xr  = xf_t + (size_t)r*H_;
  float sr=0, ss=0, su=0, g0=0, g1=0, g2=0;
  for (int k=tid;k<4*H_;k+=256){
    float v = (k<H_)? h[k] : (k<2*H_)? csr[k-H_] : (k<3*H_)? cur[k-2*H_] : xr[k-3*H_];
    sr += Wr_w[k]*v;
  }
  for (int k=tid;k<3*H_;k+=256){
    float w = Wc_w[k];
    float vs = (k<H_)? h[k] : (k<2*H_)? csr[k-H_] : xr[k-2*H_];
    float vu = (k<H_)? h[k] : (k<2*H_)? cur[k-H_] : xr[k-2*H_];
    ss += w*vs; su += w*vu;
  }
  if (do_gate){
    for (int k=tid;k<2*H_;k+=256){
      float m = (k<H_)? csr[k] : cur[k-H_];
      g0 += Wg_w[k]*m;
      g1 += Wg_w[2*H_+k]*m;
      g2 += Wg_w[4*H_+k]*m;
    }
  }
  float SR = block_reduce(sr, red, tid);
  float SS = block_reduce(ss, red, tid);
  float SU = block_reduce(su, red, tid);
  if (do_gate){
    float G0=block_reduce(g0,red,tid);
    float G1=block_reduce(g1,red,tid);
    float G2=block_reduce(g2,red,tid);
    if (tid==0){
      gate_out[r*G_+0] = G0 + Wg_b[0];
      gate_out[r*G_+1] = G1 + Wg_b[1];
      gate_out[r*G_+2] = G2 + Wg_b[2];
    }
  }
  // softmax stats from online partials
  const float* pmr = pmax + (size_t)r*NT_VOC;
  const float* psr = psum + (size_t)r*NT_VOC;
  float lm = -3.0e38f;
  for (int nb=tid; nb<NT_VOC; nb+=256) lm = fmaxf(lm, pmr[nb]);
  red[tid]=lm; __syncthreads();
  for (int s=128;s>0;s>>=1){ if(tid<s) red[tid]=fmaxf(red[tid],red[tid+s]); __syncthreads(); }
  float M = red[0]; __syncthreads();
  float ls = 0.f;
  for (int nb=tid; nb<NT_VOC; nb+=256) ls += psr[nb]*__expf(pmr[nb]-M);
  float S = block_reduce(ls, red, tid);
  if (tid==0){
    float swv = 1.f/(1.f+__expf(-(SR + Wr_b[0])));
    float lcs = SS + Wc_b[0];
    float lcu = SU + Wc_b[0];
    float mx = fmaxf(lcs,lcu);
    float es = __expf(lcs-mx), eu = __expf(lcu-mx);
    float al = es/(es+eu);
    Marr[r]  = M;
    scarr[r] = swv / S;
    acarr[r] = (1.f-swv)*al;
    bcarr[r] = (1.f-swv)*(1.f-al);
  }
}

// ---------- tail finalize (t = T-1), 2-way split ----------
__global__ __launch_bounds__(256) void finalize_kernel(
    float* __restrict__ out_prev,
    const float* __restrict__ Marr, const float* __restrict__ scarr,
    const float* __restrict__ acarr, const float* __restrict__ bcarr,
    const float* __restrict__ ps, const float* __restrict__ pu,
    const int* __restrict__ story_sys, const int* __restrict__ story_user){
  int u = blockIdx.x;
  finalize_row_part(u>>1, u&1, out_prev, Marr, scarr, acarr, bcarr,
                    ps, pu, story_sys, story_user, threadIdx.x);
}

// ================= legacy basic-path kernels (small workspace fallback) =================

__global__ void padsplit_kernel(const float* __restrict__ src,
                                ushort_t* __restrict__ hi, ushort_t* __restrict__ lo){
  int idx = blockIdx.x*256 + threadIdx.x;
  if (idx >= NP_G*KP) return;
  int r = idx / KP, c = idx - r*KP;
  ushort_t h = 0, l = 0;
  if (r < 3*H_ && c < H_){
    float v = src[r*H_ + c];
    h = f2b(v);
    l = f2b(v - b2f(h));
  }
  hi[idx] = h; lo[idx] = l;
}

__global__ void initL_kernel(const float* __restrict__ slot_att, const float* __restrict__ slot_emb,
                            float* __restrict__ xf, ushort_t* __restrict__ xbf, ushort_t* __restrict__ xbf2,
                            ushort_t* __restrict__ hbf, ushort_t* __restrict__ hbf2,
                            float* __restrict__ hf){
  int idx = blockIdx.x*256 + threadIdx.x;
  if (idx >= MP*KP) return;
  int r = idx/KP, c = idx - r*KP;
  ushort_t xh = 0, xl = 0;
  if (r < SB && c < H_){
    int s = r >> 4;
    float xv = slot_emb[s*H_ + c];
    xf[r*H_ + c] = xv;
    xh = f2b(xv); xl = f2b(xv - b2f(xh));
    hf[r*H_ + c] = slot_att[s*H_ + c];
  }
  xbf[idx] = xh; xbf2[idx] = xl;
  hbf[idx] = 0;  hbf2[idx] = 0;
}

__global__ void addh_kernel(const float* __restrict__ cs, const float* __restrict__ cu,
                            float* __restrict__ hf, ushort_t* __restrict__ hbf, ushort_t* __restrict__ hbf2){
  int idx = blockIdx.x*256 + threadIdx.x;
  if (idx >= SB*H_) return;
  int r = idx/H_, c = idx - r*H_;
  float v = cs[idx] + cu[idx];
  hf[idx] = v;
  ushort_t hb = f2b(v);
  hbf [r*KP + c] = hb;
  hbf2[r*KP + c] = f2b(v - b2f(hb));
}

__global__ __launch_bounds__(256) void attendL_kernel(
    const float* __restrict__ seq, const float* __restrict__ musk,
    const float* __restrict__ cond, float* __restrict__ ctx, float* __restrict__ prob){
  __shared__ float hrow[H_];
  __shared__ float pl[L_];
  __shared__ float red[256];
  int r = blockIdx.x; int tid = threadIdx.x;
  int b = r & 15;
  for (int k=tid; k<H_; k+=256) hrow[k] = cond[(size_t)r*H_ + k];
  __syncthreads();
  float score = -3.0e38f;
  if (tid < L_){
    const float4* sp = (const float4*)(seq + ((size_t)b*L_ + tid)*H_);
    float acc = 0.f;
    for (int k=0; k<H_; k+=4){
      float4 v = sp[k>>2];
      acc += hrow[k]*v.x + hrow[k+1]*v.y + hrow[k+2]*v.z + hrow[k+3]*v.w;
    }
    score = acc + musk[b*L_ + tid];
  }
  red[tid] = score; __syncthreads();
  for (int s=128;s>0;s>>=1){ if(tid<s) red[tid]=fmaxf(red[tid],red[tid+s]); __syncthreads(); }
  float mv = red[0]; __syncthreads();
  float e = (tid<L_) ? __expf(score-mv) : 0.f;
  red[tid] = e; __syncthreads();
  for (int s=128;s>0;s>>=1){ if(tid<s) red[tid]+=red[tid+s]; __syncthreads(); }
  float sv = red[0]; __syncthreads();
  if (tid<L_){ float p = e/sv; pl[tid]=p; prob[(size_t)r*L_+tid]=p; }
  __syncthreads();
  for (int k=tid; k<H_; k+=256){
    float a = 0.f;
    const float* sp = seq + (size_t)b*L_*H_ + k;
    for (int l=0;l<L_;l++) a += pl[l]*sp[(size_t)l*H_];
    ctx[(size_t)r*H_ + k] = a;
  }
}

__global__ __launch_bounds__(256) void grugemmL_kernel(
    const ushort_t* __restrict__ xbf, const ushort_t* __restrict__ xbf2,
    const ushort_t* __restrict__ hbf, const ushort_t* __restrict__ hbf2,
    const ushort_t* __restrict__ Wih_hi, const ushort_t* __restrict__ Wih_lo,
    const ushort_t* __restrict__ Whh_hi, const ushort_t* __restrict__ Whh_lo,
    float* __restrict__ gi, float* __restrict__ gh){
  int tid = threadIdx.x;
  int wave = tid>>6, lane = tid&63;
  int q = lane>>4, ln = lane&15;
  int m_base = blockIdx.y*64 + wave*16;
  int n_base = blockIdx.x*64;
  const ushort_t* Ax  = xbf  + (size_t)(m_base + ln)*KP;
  const ushort_t* Ax2 = xbf2 + (size_t)(m_base + ln)*KP;
  const ushort_t* Ah  = hbf  + (size_t)(m_base + ln)*KP;
  const ushort_t* Ah2 = hbf2 + (size_t)(m_base + ln)*KP;
  f32x4 ai[4], ah[4];
  #pragma unroll
  for (int nt=0;nt<4;nt++){ ai[nt]=(f32x4){0,0,0,0}; ah[nt]=(f32x4){0,0,0,0}; }
  for (int kk=0; kk<KP; kk+=32){
    int ko = kk + q*8;
    frag8 ax  = *(const frag8*)(Ax  + ko);
    frag8 ax2 = *(const frag8*)(Ax2 + ko);
    frag8 ahv = *(const frag8*)(Ah  + ko);
    frag8 ah2 = *(const frag8*)(Ah2 + ko);
    #pragma unroll
    for (int nt=0;nt<4;nt++){
      size_t nrow = (size_t)(n_base + nt*16 + ln)*KP + ko;
      frag8 bih = *(const frag8*)(Wih_hi + nrow);
      frag8 bil = *(const frag8*)(Wih_lo + nrow);
      frag8 bhh = *(const frag8*)(Whh_hi + nrow);
      frag8 bhl = *(const frag8*)(Whh_lo + nrow);
      ai[nt] = __builtin_amdgcn_mfma_f32_16x16x32_bf16(ax, bih, ai[nt],0,0,0);
      ai[nt] = __builtin_amdgcn_mfma_f32_16x16x32_bf16(ax, bil, ai[nt],0,0,0);
      ai[nt] = __builtin_amdgcn_mfma_f32_16x16x32_bf16(ax2,bih, ai[nt],0,0,0);
      ah[nt] = __builtin_amdgcn_mfma_f32_16x16x32_bf16(ahv,bhh, ah[nt],0,0,0);
      ah[nt] = __builtin_amdgcn_mfma_f32_16x16x32_bf16(ahv,bhl, ah[nt],0,0,0);
      ah[nt] = __builtin_amdgcn_mfma_f32_16x16x32_bf16(ah2,bhh, ah[nt],0,0,0);
    }
  }
  int mrow = m_base + q*4;
  #pragma unroll
  for (int nt=0; nt<4; nt++){
    int n = n_base + nt*16 + ln;
    if (n >= 3*H_) continue;
    #pragma unroll
    for (int i=0;i<4;i++){
      int m = mrow + i;
      if (m < SB){
        gi[(size_t)m*(3*H_) + n] = ai[nt][i];
        gh[(size_t)m*(3*H_) + n] = ah[nt][i];
      }
    }
  }
}

__global__ void gruL_kernel(const float* __restrict__ gi, const float* __restrict__ gh,
    const float* __restrict__ b_ih, const float* __restrict__ b_hh,
    float* __restrict__ hf, ushort_t* __restrict__ hbf, ushort_t* __restrict__ hbf2){
  int idx = blockIdx.x*256 + threadIdx.x;
  if (idx >= SB*H_) return;
  int r = idx/H_, j = idx - r*H_;
  const float* gir = gi + (size_t)r*(3*H_);
  const float* ghr = gh + (size_t)r*(3*H_);
  float i_r = gir[j]      + b_ih[j];
  float i_z = gir[H_+j]   + b_ih[H_+j];
  float i_n = gir[2*H_+j] + b_ih[2*H_+j];
  float h_r = ghr[j]      + b_hh[j];
  float h_z = ghr[H_+j]   + b_hh[H_+j];
  float h_n = ghr[2*H_+j] + b_hh[2*H_+j];
  float rg = 1.f/(1.f+__expf(-(i_r+h_r)));
  float zg = 1.f/(1.f+__expf(-(i_z+h_z)));
  float ng = tanhf(i_n + rg*h_n);
  float hv = (1.f-zg)*ng + zg*hf[idx];
  hf[idx] = hv;
  ushort_t hb = f2b(hv);
  hbf [r*KP + j] = hb;
  hbf2[r*KP + j] = f2b(hv - b2f(hb));
}

__global__ __launch_bounds__(256) void smallL_kernel(
    const float* __restrict__ hf, const float* __restrict__ cs, const float* __restrict__ cu,
    const float* __restrict__ xf,
    const float* __restrict__ Wr_w, const float* __restrict__ Wr_b,
    const float* __restrict__ Wc_w, const float* __restrict__ Wc_b,
    const float* __restrict__ Wg_w, const float* __restrict__ Wg_b,
    float* __restrict__ sw_arr, float* __restrict__ ac_arr, float* __restrict__ bc_arr,
    float* __restrict__ gate_out, int do_gate){
  __shared__ float red[256];
  int r = blockIdx.x, tid = threadIdx.x;
  const float* h   = hf + (size_t)r*H_;
  const float* csr = cs + (size_t)r*H_;
  const float* cur = cu + (size_t)r*H_;
  const float* xr  = xf + (size_t)r*H_;
  float sr=0, ss=0, su=0, g0=0, g1=0, g2=0;
  for (int k=tid;k<4*H_;k+=256){
    float v = (k<H_)? h[k] : (k<2*H_)? csr[k-H_] : (k<3*H_)? cur[k-2*H_] : xr[k-3*H_];
    sr += Wr_w[k]*v;
  }
  for (int k=tid;k<3*H_;k+=256){
    float w = Wc_w[k];
    float vs = (k<H_)? h[k] : (k<2*H_)? csr[k-H_] : xr[k-2*H_];
    float vu = (k<H_)? h[k] : (k<2*H_)? cur[k-H_] : xr[k-2*H_];
    ss += w*vs; su += w*vu;
  }
  if (do_gate){
    for (int k=tid;k<2*H_;k+=256){
      float m = (k<H_)? csr[k] : cur[k-H_];
      g0 += Wg_w[k]*m;
      g1 += Wg_w[2*H_+k]*m;
      g2 += Wg_w[4*H_+k]*m;
    }
  }
  float SR = block_reduce(sr, red, tid);
  float SS = block_reduce(ss, red, tid);
  float SU = block_reduce(su, red, tid);
  float G0=0,G1=0,G2=0;
  if (do_gate){ G0=block_reduce(g0,red,tid); G1=block_reduce(g1,red,tid); G2=block_reduce(g2,red,tid); }
  if (tid==0){
    float swv = 1.f/(1.f+__expf(-(SR + Wr_b[0])));
    float lcs = SS + Wc_b[0];
    float lcu = SU + Wc_b[0];
    float mx = fmaxf(lcs,lcu);
    float es = __expf(lcs-mx), eu = __expf(lcu-mx);
    float al = es/(es+eu);
    sw_arr[r]=swv; ac_arr[r]=(1.f-swv)*al; bc_arr[r]=(1.f-swv)*(1.f-al);
    if (do_gate){
      gate_out[r*G_+0] = G0 + Wg_b[0];
      gate_out[r*G_+1] = G1 + Wg_b[1];
      gate_out[r*G_+2] = G2 + Wg_b[2];
    }
  }
}

__device__ __forceinline__ frag8 load_cvt8(const float* p){
  float4 a = *(const float4*)p;
  float4 b = *(const float4*)(p+4);
  frag8 r;
  r[0]=(short)f2b(a.x); r[1]=(short)f2b(a.y); r[2]=(short)f2b(a.z); r[3]=(short)f2b(a.w);
  r[4]=(short)f2b(b.x); r[5]=(short)f2b(b.y); r[6]=(short)f2b(b.z); r[7]=(short)f2b(b.w);
  return r;
}

__global__ __launch_bounds__(256) void vocabL_kernel(
    const ushort_t* __restrict__ A, const float* __restrict__ emb,
    float* __restrict__ outp){
  int tid = threadIdx.x;
  int wave = tid>>6, lane = tid&63;
  int q = lane>>4, ln = lane&15;
  int m_base = blockIdx.y*64 + wave*16;
  int n_base = blockIdx.x*64;
  const ushort_t* Arow = A + (size_t)(m_base + ln)*KP;
  int n0 = min(n_base +  0 + ln, V_-1);
  int n1 = min(n_base + 16 + ln, V_-1);
  int n2 = min(n_base + 32 + ln, V_-1);
  int n3 = min(n_base + 48 + ln, V_-1);
  const float* B0 = emb + (size_t)n0*H_;
  const float* B1 = emb + (size_t)n1*H_;
  const float* B2 = emb + (size_t)n2*H_;
  const float* B3 = emb + (size_t)n3*H_;
  f32x4 acc0={0,0,0,0}, acc1={0,0,0,0}, acc2={0,0,0,0}, acc3={0,0,0,0};
  for (int kk=0; kk<KP; kk+=32){
    int ko = kk + q*8;
    int safe = (ko < H_) ? ko : 0;
    frag8 a  = *(const frag8*)(Arow + ko);
    frag8 b0 = load_cvt8(B0 + safe);
    frag8 b1 = load_cvt8(B1 + safe);
    frag8 b2 = load_cvt8(B2 + safe);
    frag8 b3 = load_cvt8(B3 + safe);
    acc0 = __builtin_amdgcn_mfma_f32_16x16x32_bf16(a,b0,acc0,0,0,0);
    acc1 = __builtin_amdgcn_mfma_f32_16x16x32_bf16(a,b1,acc1,0,0,0);
    acc2 = __builtin_amdgcn_mfma_f32_16x16x32_bf16(a,b2,acc2,0,0,0);
    acc3 = __builtin_amdgcn_mfma_f32_16x16x32_bf16(a,b3,acc3,0,0,0);
  }
  int mrow = m_base + q*4;
  #pragma unroll
  for (int nt=0; nt<4; nt++){
    f32x4 acc = (nt==0)?acc0:(nt==1)?acc1:(nt==2)?acc2:acc3;
    int n = n_base + nt*16 + ln;
    if (n >= V_) continue;
    #pragma unroll
    for (int i=0;i<4;i++){
      int m = mrow + i;
      if (m < SB) outp[(size_t)m*TV + n] = acc[i];
    }
  }
}

__global__ __launch_bounds__(256) void softmax_scatterL_kernel(
    const float* __restrict__ sw_arr, const float* __restrict__ ac, const float* __restrict__ bc,
    const float* __restrict__ p_s, const float* __restrict__ p_u,
    const int* __restrict__ story_sys, const int* __restrict__ story_user,
    float* __restrict__ outp){
  __shared__ float red[256];
  int r = blockIdx.x, tid = threadIdx.x;
  float* row = outp + (size_t)r*TV;
  float m = -3.0e38f;
  for (int v=tid; v<V_; v+=256) m = fmaxf(m, row[v]);
  red[tid]=m; __syncthreads();
  for (int s=128;s>0;s>>=1){ if(tid<s) red[tid]=fmaxf(red[tid],red[tid+s]); __syncthreads(); }
  float M = red[0]; __syncthreads();
  float sum = 0.f;
  for (int v=tid; v<V_; v+=256) sum += __expf(row[v] - M);
  red[tid]=sum; __syncthreads();
  for (int s=128;s>0;s>>=1){ if(tid<s) red[tid]+=red[tid+s]; __syncthreads(); }
  float S = red[0]; __syncthreads();
  float scale = sw_arr[r]/S;
  for (int v=tid; v<V_; v+=256) row[v] = __expf(row[v] - M)*scale;
  __syncthreads();
  int b = r & 15;
  float a_ = ac[r], b_ = bc[r];
  for (int i=tid; i<2*L_; i+=256){
    int which = (i >= L_) ? 1 : 0;
    int l = which ? i - L_ : i;
    int v = which ? story_user[b*L_+l] : story_sys[b*L_+l];
    float val = which ? b_*p_u[(size_t)r*L_+l] : a_*p_s[(size_t)r*L_+l];
    atomicAdd(row + v, val);
  }
}

__global__ void nextxL_kernel(const int* __restrict__ targets, const float* __restrict__ emb,
    float* __restrict__ xf, ushort_t* __restrict__ xbf, ushort_t* __restrict__ xbf2, int t){
  int idx = blockIdx.x*256 + threadIdx.x;
  if (idx >= SB*H_) return;
  int r = idx/H_, k = idx - r*H_;
  int s = r>>4, b = r&15;
  int tg = targets[(b*S_ + s)*T_ + t];
  float v = emb[(size_t)tg*H_ + k];
  xf[(size_t)r*H_ + k] = v;
  ushort_t hb = f2b(v);
  xbf [r*KP + k] = hb;
  xbf2[r*KP + k] = f2b(v - b2f(hb));
}

// ================= host =================
extern "C" void kernel_launch(void* const* d_in, const int* in_sizes, int n_in,
                              void* d_out, int out_size, void* d_ws, size_t ws_size,
                              hipStream_t stream){
  const float* sys_H    = (const float*)d_in[0];
  const float* user_H   = (const float*)d_in[1];
  const float* sys_musk = (const float*)d_in[2];
  const float* user_musk= (const float*)d_in[3];
  const float* emb      = (const float*)d_in[4];
  const float* W_ih     = (const float*)d_in[5];
  const float* W_hh     = (const float*)d_in[6];
  const float* b_ih     = (const float*)d_in[7];
  const float* b_hh     = (const float*)d_in[8];
  const float* Wg_w     = (const float*)d_in[9];
  const float* Wg_b     = (const float*)d_in[10];
  const float* Wr_w     = (const float*)d_in[11];
  const float* Wr_b     = (const float*)d_in[12];
  const float* Wc_w     = (const float*)d_in[13];
  const float* Wc_b     = (const float*)d_in[14];
  const float* slot_att = (const float*)d_in[15];
  const float* slot_emb = (const float*)d_in[16];
  const int* story_sys  = (const int*)d_in[17];
  const int* story_user = (const int*)d_in[18];
  const int* targets    = (const int*)d_in[19];
  float* out = (float*)d_out;                      // OUTPUT IS FLOAT32
  float* gate_out = out + (size_t)SB*TV;

  char* base = (char*)d_ws;
  size_t off = 0;
  auto take = [&](size_t bytes)->char*{
    char* p = base + off; off += (bytes + 255) & ~(size_t)255; return p;
  };
  // --- shared (legacy + primary) ---
  ushort_t* Wih_hi = (ushort_t*)take((size_t)NP_G*KP*2);
  ushort_t* Wih_lo = (ushort_t*)take((size_t)NP_G*KP*2);
  ushort_t* Whh_hi = (ushort_t*)take((size_t)NP_G*KP*2);
  ushort_t* Whh_lo = (ushort_t*)take((size_t)NP_G*KP*2);
  ushort_t* hbf0  = (ushort_t*)take((size_t)MP*KP*2);
  ushort_t* hbf20 = (ushort_t*)take((size_t)MP*KP*2);
  float* hf0   = (float*)take((size_t)SB*H_*4);
  float* ctx_s = (float*)take((size_t)SB*H_*4);
  float* ctx_u = (float*)take((size_t)SB*H_*4);
  float* p_s   = (float*)take((size_t)SB*L_*4);
  float* p_u   = (float*)take((size_t)SB*L_*4);
  float* gh    = (float*)take((size_t)SB*3*H_*4);
  // --- legacy-only ---
  float* gi_l  = (float*)take((size_t)SB*3*H_*4);
  float* xf_l  = (float*)take((size_t)SB*H_*4);
  ushort_t* xbf_l  = (ushort_t*)take((size_t)MP*KP*2);
  ushort_t* xbf2_l = (ushort_t*)take((size_t)MP*KP*2);
  float* sw_arr = (float*)take(SB*4);
  float* ac_arr = (float*)take(SB*4);
  float* bc_arr = (float*)take(SB*4);
  size_t off_legacy = off;
  // --- primary-only ---
  ushort_t* hbf1  = (ushort_t*)take((size_t)MP*KP*2);
  ushort_t* hbf21 = (ushort_t*)take((size_t)MP*KP*2);
  float* hf1   = (float*)take((size_t)SB*H_*4);
  float* pmaxw = (float*)take((size_t)MP*NT_VOC*4);
  float* psumw = (float*)take((size_t)MP*NT_VOC*4);
  float* gi_all= (float*)take((size_t)T_*SB*3*H_*4);
  float* xf_all= (float*)take((size_t)T_*SB*H_*4);
  ushort_t* xa_hi = (ushort_t*)take((size_t)T_*MP*KP*2);
  ushort_t* xa_lo = (ushort_t*)take((size_t)T_*MP*KP*2);
  ushort_t* embp  = (ushort_t*)take((size_t)NP_EMB*KP*2);
  float* seqT_s = (float*)take((size_t)B_*H_*L_*4);
  float* seqT_u = (float*)take((size_t)B_*H_*L_*4);
  // double-buffered prob + per-row stat arrays (by t parity)
  float* psb[2] = { (float*)take((size_t)SB*L_*4), (float*)take((size_t)SB*L_*4) };
  float* pub[2] = { (float*)take((size_t)SB*L_*4), (float*)take((size_t)SB*L_*4) };
  float* Mar[2] = { (float*)take(SB*4), (float*)take(SB*4) };
  float* scar[2]= { (float*)take(SB*4), (float*)take(SB*4) };
  float* acar[2]= { (float*)take(SB*4), (float*)take(SB*4) };
  float* bcar[2]= { (float*)take(SB*4), (float*)take(SB*4) };
  size_t off_full = off;

  if (off_full <= ws_size){
    // ============ primary path: 25 dispatches ============
    setup1_kernel<<<SETUP1_UNITS,256,0,stream>>>(
        sys_H, user_H, seqT_s, seqT_u, slot_att, slot_emb,
        xf_all, xa_hi, xa_lo, hbf0, hbf20, hbf1, hbf21, hf0,
        targets, emb, W_ih, Wih_hi, Wih_lo, W_hh, Whh_hi, Whh_lo, embp);
    pre_kernel<<<PRE_UNITS,256,0,stream>>>(
        sys_H, seqT_s, sys_musk, user_H, seqT_u, user_musk,
        hf0, ctx_s, psb[1], ctx_u, pub[1],
        xa_hi, xa_lo, Wih_hi, Wih_lo, gi_all);
    // gg0v2: gh = bf16hl(ctx_s+ctx_u) @ Whh  (also writes hf0 = ctx_s+ctx_u)
    gg0v2_kernel<<<GG_T,256,0,stream>>>(ctx_s, ctx_u, Whh_hi, Whh_lo, gh, hf0);
    // gru(0): h(0) -> buf1
    gru0_kernel<<<SB,256,0,stream>>>(gi_all, gh, b_ih, b_hh, hf0, hf1, hbf1, hbf21);

    float* hfb[2]      = { hf0, hf1 };
    ushort_t* hbfb[2]  = { hbf0, hbf1 };
    ushort_t* hbf2b[2] = { hbf20, hbf21 };
    for (int t=0; t<T_; t++){
      int cur = (t+1)&1;     // h(t) lives here
      int nxt = t&1;         // gru(t+1) writes here
      int ngg = (t < T_-1) ? 1 : 0;
      int base_off = (t > 0) ? 0 : FZ_BLKS;   // skip finalize role entirely at t=0 (960 %8==0)
      int grid = MEGAC_BLKS - base_off;
      int pc = t&1;                   // attend(t) prob parity
      int pp = (t-1)&1;               // finalize(t-1) parity
      float* outp = out + (size_t)t*V_;
      float* outprev = out + (size_t)(t>0 ? t-1 : 0)*V_;
      megaC_kernel<<<grid,256,0,stream>>>(
          sys_H, seqT_s, sys_musk, user_H, seqT_u, user_musk,
          hfb[cur], hbfb[cur], hbf2b[cur],
          ctx_s, psb[pc], ctx_u, pub[pc],
          embp, outp, pmaxw, psumw,
          Whh_hi, Whh_lo, gh, ngg,
          outprev, Mar[pp], scar[pp], acar[pp], bcar[pp],
          psb[pp], pub[pp], story_sys, story_user, base_off);
      finalstats_kernel<<<SB,256,0,stream>>>(
          hfb[cur], ctx_s, ctx_u, xf_all + (size_t)t*SB*H_,
          Wr_w, Wr_b, Wc_w, Wc_b, Wg_w, Wg_b,
          pmaxw, psumw,
          Mar[t&1], scar[t&1], acar[t&1], bcar[t&1],
          gate_out, (t==0)?1:0,
          gi_all + (size_t)(t<T_-1 ? t+1 : 0)*SB*3*H_, gh, b_ih, b_hh,
          hfb[nxt], hbfb[nxt], hbf2b[nxt], (t<T_-1)?1:0);
    }
    // tail finalize for t = T-1 (parity (T-1)&1 = 1)
    finalize_kernel<<<FZ_BLKS,256,0,stream>>>(
        out + (size_t)(T_-1)*V_, Mar[1], scar[1], acar[1], bcar[1],
        psb[1], pub[1], story_sys, story_user);
    return;
  }

  if (off_legacy <= ws_size){
    // ============ legacy basic path ============
    padsplit_kernel<<<(NP_G*KP+255)/256,256,0,stream>>>(W_ih, Wih_hi, Wih_lo);
    padsplit_kernel<<<(NP_G*KP+255)/256,256,0,stream>>>(W_hh, Whh_hi, Whh_lo);
    initL_kernel<<<(MP*KP+255)/256,256,0,stream>>>(slot_att, slot_emb, xf_l, xbf_l, xbf2_l,
                                                   hbf0, hbf20, hf0);
    attendL_kernel<<<SB,256,0,stream>>>(sys_H, sys_musk, hf0, ctx_s, p_s);
    attendL_kernel<<<SB,256,0,stream>>>(user_H, user_musk, hf0, ctx_u, p_u);
    addh_kernel<<<(SB*H_+255)/256,256,0,stream>>>(ctx_s, ctx_u, hf0, hbf0, hbf20);
    for (int t=0; t<T_; t++){
      grugemmL_kernel<<<dim3(NP_G/64, MP/64),256,0,stream>>>(xbf_l, xbf2_l, hbf0, hbf20,
          Wih_hi, Wih_lo, Whh_hi, Whh_lo, gi_l, gh);
      gruL_kernel<<<(SB*H_+255)/256,256,0,stream>>>(gi_l, gh, b_ih, b_hh, hf0, hbf0, hbf20);
      attendL_kernel<<<SB,256,0,stream>>>(sys_H, sys_musk, hf0, ctx_s, p_s);
      attendL_kernel<<<SB,256,0,stream>>>(user_H, user_musk, hf0, ctx_u, p_u);
      smallL_kernel<<<SB,256,0,stream>>>(hf0, ctx_s, ctx_u, xf_l, Wr_w, Wr_b, Wc_w, Wc_b,
                                         Wg_w, Wg_b, sw_arr, ac_arr, bc_arr, gate_out, (t==0)?1:0);
      float* outp = out + (size_t)t*V_;
      vocabL_kernel<<<dim3(NT_VOC, MP/64),256,0,stream>>>(hbf0, emb, outp);
      softmax_scatterL_kernel<<<SB,256,0,stream>>>(sw_arr, ac_arr, bc_arr, p_s, p_u,
                                                   story_sys, story_user, outp);
      if (t < T_-1)
        nextxL_kernel<<<(SB*H_+255)/256,256,0,stream>>>(targets, emb, xf_l, xbf_l, xbf2_l, t);
    }
  }
}

// Round 10
// 1412.840 us; speedup vs baseline: 1.0876x; 1.0386x over previous
//
#include <hip/hip_runtime.h>
#include <stdint.h>

#define B_ 16
#define S_ 30
#define T_ 10
#define H_ 400
#define V_ 20000
#define L_ 200
#define G_ 3
#define SB 480          // S*B rows
#define KP 416          // padded K (13*32)
#define MP 512          // padded M rows (8*64)
#define NT_VOC 313      // ceil(20000/64)
#define NP_G 1216       // padded 3H rows (19*64)
#define NP_EMB 20096    // padded V rows (314*64)
#define TV (T_*V_)      // 200000

#define GG_T 152        // 19*8 hh tiles per t
#define GIA_UNITS (T_*GG_T)         // 1520

// attention v3: one block per (which,b,row-group)
#define ATT_ROWS 6
#define ATT_NRB 5                   // 30/6
#define ATT3_BLKS (2*B_*ATT_NRB)    // 160
// vocab with XCD-chunked swizzle: 8 chunks x 40 nb x 8 mb
#define VOC_PAD 2560
// finalize role: 2-way split rows (R7-verified config)
#define FZ_SPLIT 2
#define FZ_SEG (V_/FZ_SPLIT)        // 10000
#define FZ_BLKS (SB*FZ_SPLIT)       // 960 (%8==0)
#define GG_PAD 160                  // GG_T padded to keep vocab offset %8==0
#define MEGAC_BLKS (FZ_BLKS + ATT3_BLKS + GG_PAD + VOC_PAD)   // 3840

#define PRE_UNITS (ATT3_BLKS + GIA_UNITS)

// setup1 role counts
#define TT_TILES 1456   // 16 * 7 * 13 transpose tiles
#define INIT_BLKS 832   // MP*KP/256
#define XA8_BLKS 936    // 9*MP*KP/(256*8)
#define PS8_BLKS 247    // NP_G*KP/(256*8)
#define EC8_BLKS 4082   // NP_EMB*KP/(256*8)
#define SETUP1_UNITS (2*TT_TILES + INIT_BLKS + XA8_BLKS + 2*PS8_BLKS + EC8_BLKS)

typedef unsigned short ushort_t;
typedef __attribute__((ext_vector_type(8))) short frag8;       // 8 bf16
typedef __attribute__((ext_vector_type(8))) unsigned short us8;
typedef __attribute__((ext_vector_type(4))) float f32x4;

__device__ __forceinline__ float b2f(ushort_t u){ return __uint_as_float(((unsigned)u)<<16); }
__device__ __forceinline__ ushort_t f2b(float f){
  unsigned u = __float_as_uint(f);
  unsigned r = u + 0x7fffu + ((u>>16)&1u);   // RNE
  return (ushort_t)(r>>16);
}

// ================= setup bodies =================

__device__ __forceinline__ void padsplit8_body(const float* __restrict__ src,
    ushort_t* __restrict__ hi, ushort_t* __restrict__ lo, int u8){
  int base = u8*8;
  if (base >= NP_G*KP) return;
  int r = base / KP, c = base - r*KP;
  us8 h, l;
  if (r < 3*H_ && c+8 <= H_){
    float4 a = *(const float4*)(src + (size_t)r*H_ + c);
    float4 b = *(const float4*)(src + (size_t)r*H_ + c + 4);
    float v[8] = {a.x,a.y,a.z,a.w,b.x,b.y,b.z,b.w};
    #pragma unroll
    for (int i=0;i<8;i++){ h[i]=f2b(v[i]); l[i]=f2b(v[i]-b2f(h[i])); }
  } else {
    #pragma unroll
    for (int i=0;i<8;i++){ h[i]=0; l[i]=0; }
  }
  *(us8*)(hi+base) = h; *(us8*)(lo+base) = l;
}

__device__ __forceinline__ void embcvt8_body(const float* __restrict__ emb,
    ushort_t* __restrict__ dst, long long u8){
  long long base = u8*8;
  if (base >= (long long)NP_EMB*KP) return;
  int r = (int)(base / KP), c = (int)(base - (long long)r*KP);
  us8 h;
  if (r < V_ && c+8 <= H_){
    float4 a = *(const float4*)(emb + (size_t)r*H_ + c);
    float4 b = *(const float4*)(emb + (size_t)r*H_ + c + 4);
    float v[8] = {a.x,a.y,a.z,a.w,b.x,b.y,b.z,b.w};
    #pragma unroll
    for (int i=0;i<8;i++) h[i]=f2b(v[i]);
  } else {
    #pragma unroll
    for (int i=0;i<8;i++) h[i]=0;
  }
  *(us8*)(dst+base) = h;
}

__device__ __forceinline__ void xallcvt8_body(const int* __restrict__ targets,
    const float* __restrict__ emb, float* __restrict__ xf_all,
    ushort_t* __restrict__ xa_hi, ushort_t* __restrict__ xa_lo, int u8){
  long long base = (long long)u8*8;
  if (base >= (long long)(T_-1)*MP*KP) return;
  int t = (int)(base / ((long long)MP*KP)) + 1;
  int rem = (int)(base - (long long)(t-1)*MP*KP);
  int r = rem / KP, c = rem - r*KP;
  size_t off = (size_t)t*MP*KP + rem;
  us8 h, l;
  if (r < SB && c+8 <= H_){
    int s = r>>4, b = r&15;
    int tg = targets[(b*S_ + s)*T_ + (t-1)];
    float4 a = *(const float4*)(emb + (size_t)tg*H_ + c);
    float4 bb= *(const float4*)(emb + (size_t)tg*H_ + c + 4);
    float v[8] = {a.x,a.y,a.z,a.w,bb.x,bb.y,bb.z,bb.w};
    float* xfp = xf_all + (size_t)t*SB*H_ + (size_t)r*H_ + c;
    *(float4*)xfp = a; *(float4*)(xfp+4) = bb;
    #pragma unroll
    for (int i=0;i<8;i++){ h[i]=f2b(v[i]); l[i]=f2b(v[i]-b2f(h[i])); }
  } else {
    #pragma unroll
    for (int i=0;i<8;i++){ h[i]=0; l[i]=0; }
  }
  *(us8*)(xa_hi+off) = h; *(us8*)(xa_lo+off) = l;
}

__device__ __forceinline__ void transpose_body(const float* __restrict__ src,
    float* __restrict__ dst, int rel, int tid, float (*tile)[33]){
  int b  = rel / 91;           // 7*13 tiles per b
  int rem = rel - b*91;
  int l0 = (rem % 7)*32, k0 = (rem / 7)*32;
  int tx = tid & 31, ty = tid >> 5;   // 32 x 8
  const float* s = src + (size_t)b*L_*H_;
  float*       d = dst + (size_t)b*H_*L_;
  #pragma unroll
  for (int i=ty; i<32; i+=8){
    int l = l0+i, k = k0+tx;
    tile[i][tx] = (l<L_ && k<H_) ? s[(size_t)l*H_ + k] : 0.f;
  }
  __syncthreads();
  #pragma unroll
  for (int i=ty; i<32; i+=8){
    int k = k0+i, l = l0+tx;
    if (k<H_ && l<L_) d[(size_t)k*L_ + l] = tile[tx][i];
  }
  __syncthreads();
}

__device__ __forceinline__ void init2_body(const float* __restrict__ slot_att,
    const float* __restrict__ slot_emb,
    float* __restrict__ xf_all, ushort_t* __restrict__ xa_hi, ushort_t* __restrict__ xa_lo,
    ushort_t* __restrict__ hbfA, ushort_t* __restrict__ hbf2A,
    ushort_t* __restrict__ hbfB, ushort_t* __restrict__ hbf2B,
    float* __restrict__ hfA, int idx){
  if (idx >= MP*KP) return;
  int r = idx/KP, c = idx - r*KP;
  ushort_t xh = 0, xl = 0;
  if (r < SB && c < H_){
    int s = r >> 4;
    float xv = slot_emb[s*H_ + c];
    xf_all[(size_t)r*H_ + c] = xv;
    xh = f2b(xv); xl = f2b(xv - b2f(xh));
    hfA[(size_t)r*H_ + c] = slot_att[s*H_ + c];
  }
  xa_hi[idx] = xh; xa_lo[idx] = xl;
  hbfA[idx] = 0; hbf2A[idx] = 0;
  hbfB[idx] = 0; hbf2B[idx] = 0;
}

__global__ __launch_bounds__(256) void setup1_kernel(
    const float* __restrict__ sys_H, const float* __restrict__ user_H,
    float* __restrict__ seqT_s, float* __restrict__ seqT_u,
    const float* __restrict__ slot_att, const float* __restrict__ slot_emb,
    float* __restrict__ xf_all, ushort_t* __restrict__ xa_hi, ushort_t* __restrict__ xa_lo,
    ushort_t* __restrict__ hbfA, ushort_t* __restrict__ hbf2A,
    ushort_t* __restrict__ hbfB, ushort_t* __restrict__ hbf2B,
    float* __restrict__ hfA,
    const int* __restrict__ targets, const float* __restrict__ emb,
    const float* __restrict__ W_ih, ushort_t* __restrict__ Wih_hi, ushort_t* __restrict__ Wih_lo,
    const float* __restrict__ W_hh, ushort_t* __restrict__ Whh_hi, ushort_t* __restrict__ Whh_lo,
    ushort_t* __restrict__ embp){
  __shared__ float tile[32][33];
  int bid = blockIdx.x, tid = threadIdx.x;
  int u = bid;
  if (u < TT_TILES){ transpose_body(sys_H, seqT_s, u, tid, tile); return; }
  u -= TT_TILES;
  if (u < TT_TILES){ transpose_body(user_H, seqT_u, u, tid, tile); return; }
  u -= TT_TILES;
  if (u < INIT_BLKS){
    init2_body(slot_att, slot_emb, xf_all, xa_hi, xa_lo, hbfA, hbf2A, hbfB, hbf2B, hfA,
               u*256 + tid);
    return;
  }
  u -= INIT_BLKS;
  if (u < XA8_BLKS){ xallcvt8_body(targets, emb, xf_all, xa_hi, xa_lo, u*256 + tid); return; }
  u -= XA8_BLKS;
  if (u < PS8_BLKS){ padsplit8_body(W_ih, Wih_hi, Wih_lo, u*256 + tid); return; }
  u -= PS8_BLKS;
  if (u < PS8_BLKS){ padsplit8_body(W_hh, Whh_hi, Whh_lo, u*256 + tid); return; }
  u -= PS8_BLKS;
  embcvt8_body(emb, embp, (long long)u*256 + tid);
}

// ================= attention v3 (R7-verified unroll-4) =================
__device__ void attend3_body(
    int u,
    const float* __restrict__ seqS, const float* __restrict__ seqTS, const float* __restrict__ muskS,
    const float* __restrict__ seqU, const float* __restrict__ seqTU, const float* __restrict__ muskU,
    const float* __restrict__ cond,
    float* __restrict__ ctxS, float* __restrict__ probS,
    float* __restrict__ ctxU, float* __restrict__ probU,
    float (*cond_l)[H_], float (*S_l)[208], float* smax, float* ssum){
  int which = (u >= B_*ATT_NRB) ? 1 : 0;
  int v = which ? u - B_*ATT_NRB : u;
  int b = v / ATT_NRB, rb = v - b*ATT_NRB;
  const float* seq  = which ? seqU  : seqS;
  const float* seqT = which ? seqTU : seqTS;
  const float* musk = which ? muskU : muskS;
  float* ctx  = which ? ctxU  : ctxS;
  float* prob = which ? probU : probS;
  int tid = threadIdx.x;
  int s0 = rb*ATT_ROWS;
  for (int idx=tid; idx<ATT_ROWS*H_; idx+=256){
    int i = idx/H_, k = idx - i*H_;
    cond_l[i][k] = cond[(size_t)((s0+i)*16 + b)*H_ + k];
  }
  __syncthreads();
  if (tid < L_){
    const float* sp = seqT + (size_t)b*H_*L_ + tid;
    float acc[ATT_ROWS];
    #pragma unroll
    for (int i=0;i<ATT_ROWS;i++) acc[i]=0.f;
    for (int k=0;k<H_;k+=4){
      float v0 = sp[(size_t)(k  )*L_];
      float v1 = sp[(size_t)(k+1)*L_];
      float v2 = sp[(size_t)(k+2)*L_];
      float v3 = sp[(size_t)(k+3)*L_];
      #pragma unroll
      for (int i=0;i<ATT_ROWS;i++){
        float4 c = *(const float4*)&cond_l[i][k];
        acc[i] += c.x*v0; acc[i] += c.y*v1; acc[i] += c.z*v2; acc[i] += c.w*v3;
      }
    }
    float mk = musk[b*L_ + tid];
    #pragma unroll
    for (int i=0;i<ATT_ROWS;i++) S_l[i][tid] = acc[i] + mk;
  }
  __syncthreads();
  if (tid < ATT_ROWS*16){
    int i = tid >> 4, sub = tid & 15;
    float m = -3.0e38f;
    for (int l=sub; l<L_; l+=16) m = fmaxf(m, S_l[i][l]);
    #pragma unroll
    for (int d=8; d>=1; d>>=1) m = fmaxf(m, __shfl_xor(m, d));
    float sm = 0.f;
    for (int l=sub; l<L_; l+=16) sm += __expf(S_l[i][l] - m);
    #pragma unroll
    for (int d=8; d>=1; d>>=1) sm += __shfl_xor(sm, d);
    if (sub==0){ smax[i] = m; ssum[i] = sm; }
  }
  __syncthreads();
  for (int idx=tid; idx<ATT_ROWS*L_; idx+=256){
    int i = idx/L_, l = idx - i*L_;
    float p = __expf(S_l[i][l] - smax[i]) / ssum[i];
    S_l[i][l] = p;
    prob[(size_t)((s0+i)*16 + b)*L_ + l] = p;
  }
  __syncthreads();
  for (int k=tid; k<H_; k+=256){
    const float* sp2 = seq + (size_t)b*L_*H_ + k;
    float acc[ATT_ROWS];
    #pragma unroll
    for (int i=0;i<ATT_ROWS;i++) acc[i]=0.f;
    for (int l=0;l<L_;l+=4){
      float v0 = sp2[(size_t)(l  )*H_];
      float v1 = sp2[(size_t)(l+1)*H_];
      float v2 = sp2[(size_t)(l+2)*H_];
      float v3 = sp2[(size_t)(l+3)*H_];
      #pragma unroll
      for (int i=0;i<ATT_ROWS;i++){
        float4 pp = *(const float4*)&S_l[i][l];
        acc[i] += pp.x*v0; acc[i] += pp.y*v1; acc[i] += pp.z*v2; acc[i] += pp.w*v3;
      }
    }
    #pragma unroll
    for (int i=0;i<ATT_ROWS;i++)
      ctx[(size_t)((s0+i)*16 + b)*H_ + k] = acc[i];
  }
}

// ================= hi/lo GEMM tile =================
__device__ __forceinline__ void hl_gemm_tile(
    const ushort_t* __restrict__ A_hi, const ushort_t* __restrict__ A_lo,
    const ushort_t* __restrict__ B_hi, const ushort_t* __restrict__ B_lo,
    float* __restrict__ outg, int nb, int mb, int tid){
  int wave = tid>>6, lane = tid&63;
  int q = lane>>4, ln = lane&15;
  int m_base = mb*64 + wave*16;
  int n_base = nb*64;
  const ushort_t* Ah  = A_hi + (size_t)(m_base + ln)*KP;
  const ushort_t* Ah2 = A_lo + (size_t)(m_base + ln)*KP;
  f32x4 ah[4];
  #pragma unroll
  for (int nt=0;nt<4;nt++) ah[nt]=(f32x4){0,0,0,0};
  for (int kk=0; kk<KP; kk+=32){
    int ko = kk + q*8;
    frag8 ahv = *(const frag8*)(Ah  + ko);
    frag8 ah2 = *(const frag8*)(Ah2 + ko);
    #pragma unroll
    for (int nt=0;nt<4;nt++){
      size_t nrow = (size_t)(n_base + nt*16 + ln)*KP + ko;
      frag8 bhh = *(const frag8*)(B_hi + nrow);
      frag8 bhl = *(const frag8*)(B_lo + nrow);
      ah[nt] = __builtin_amdgcn_mfma_f32_16x16x32_bf16(ahv,bhh, ah[nt],0,0,0);
      ah[nt] = __builtin_amdgcn_mfma_f32_16x16x32_bf16(ahv,bhl, ah[nt],0,0,0);
      ah[nt] = __builtin_amdgcn_mfma_f32_16x16x32_bf16(ah2,bhh, ah[nt],0,0,0);
    }
  }
  int mrow = m_base + q*4;
  #pragma unroll
  for (int nt=0; nt<4; nt++){
    int n = n_base + nt*16 + ln;
    if (n >= 3*H_) continue;
    #pragma unroll
    for (int i=0;i<4;i++){
      int m = mrow + i;
      if (m < SB) outg[(size_t)m*(3*H_) + n] = ah[nt][i];
    }
  }
}

// ---------- pre: h0 attend (160) + gi_all GEMM (1520 tiles) ----------
__global__ __launch_bounds__(256) void pre_kernel(
    const float* __restrict__ seqS, const float* __restrict__ seqTS, const float* __restrict__ muskS,
    const float* __restrict__ seqU, const float* __restrict__ seqTU, const float* __restrict__ muskU,
    const float* __restrict__ cond,
    float* __restrict__ ctxS, float* __restrict__ probS,
    float* __restrict__ ctxU, float* __restrict__ probU,
    const ushort_t* __restrict__ xa_hi, const ushort_t* __restrict__ xa_lo,
    const ushort_t* __restrict__ Wih_hi, const ushort_t* __restrict__ Wih_lo,
    float* __restrict__ gi_all){
  __shared__ float cond_l[ATT_ROWS][H_];
  __shared__ float S_l[ATT_ROWS][208];
  __shared__ float smax[ATT_ROWS], ssum[ATT_ROWS];
  int u = blockIdx.x, tid = threadIdx.x;
  if (u < ATT3_BLKS){
    attend3_body(u, seqS, seqTS, muskS, seqU, seqTU, muskU, cond,
                 ctxS, probS, ctxU, probU, cond_l, S_l, smax, ssum);
    return;
  }
  u -= ATT3_BLKS;
  int t = u / GG_T, rem = u - t*GG_T;
  hl_gemm_tile(xa_hi + (size_t)t*MP*KP, xa_lo + (size_t)t*MP*KP,
               Wih_hi, Wih_lo, gi_all + (size_t)t*SB*(3*H_),
               rem % 19, rem / 19, tid);
}

// ---------- gg0v2: hh GEMM for t'=0 with on-the-fly A = bf16(cs+cu); also writes hf0 ----------
__global__ __launch_bounds__(256) void gg0v2_kernel(
    const float* __restrict__ cs, const float* __restrict__ cu,
    const ushort_t* __restrict__ Whh_hi, const ushort_t* __restrict__ Whh_lo,
    float* __restrict__ gh, float* __restrict__ hf0){
  int u = blockIdx.x, tid = threadIdx.x;
  int nb = u % 19, mb = u / 19;
  int wave = tid>>6, lane = tid&63;
  int q = lane>>4, ln = lane&15;
  int m_base = mb*64 + wave*16;
  int n_base = nb*64;
  int row = m_base + ln;
  f32x4 ah[4];
  #pragma unroll
  for (int nt=0;nt<4;nt++) ah[nt]=(f32x4){0,0,0,0};
  for (int kk=0; kk<KP; kk+=32){
    int ko = kk + q*8;
    frag8 ahv, ah2;
    if (row < SB && ko < H_){
      const float* c1 = cs + (size_t)row*H_ + ko;
      const float* c2 = cu + (size_t)row*H_ + ko;
      float4 a = *(const float4*)c1, b = *(const float4*)(c1+4);
      float4 e = *(const float4*)c2, f = *(const float4*)(c2+4);
      float v[8] = {a.x+e.x, a.y+e.y, a.z+e.z, a.w+e.w,
                    b.x+f.x, b.y+f.y, b.z+f.z, b.w+f.w};
      #pragma unroll
      for (int i=0;i<8;i++){
        ushort_t hb = f2b(v[i]);
        ahv[i] = (short)hb;
        ah2[i] = (short)f2b(v[i] - b2f(hb));
      }
      if (nb == 0){
        float* hp = hf0 + (size_t)row*H_ + ko;
        *(float4*)hp     = (float4){v[0],v[1],v[2],v[3]};
        *(float4*)(hp+4) = (float4){v[4],v[5],v[6],v[7]};
      }
    } else {
      #pragma unroll
      for (int i=0;i<8;i++){ ahv[i]=0; ah2[i]=0; }
    }
    #pragma unroll
    for (int nt=0;nt<4;nt++){
      size_t nrow = (size_t)(n_base + nt*16 + ln)*KP + ko;
      frag8 bhh = *(const frag8*)(Whh_hi + nrow);
      frag8 bhl = *(const frag8*)(Whh_lo + nrow);
      ah[nt] = __builtin_amdgcn_mfma_f32_16x16x32_bf16(ahv,bhh, ah[nt],0,0,0);
      ah[nt] = __builtin_amdgcn_mfma_f32_16x16x32_bf16(ahv,bhl, ah[nt],0,0,0);
      ah[nt] = __builtin_amdgcn_mfma_f32_16x16x32_bf16(ah2,bhh, ah[nt],0,0,0);
    }
  }
  int mrow = m_base + q*4;
  #pragma unroll
  for (int nt=0; nt<4; nt++){
    int n = n_base + nt*16 + ln;
    if (n >= 3*H_) continue;
    #pragma unroll
    for (int i=0;i<4;i++){
      int m = mrow + i;
      if (m < SB) gh[(size_t)m*(3*H_) + n] = ah[nt][i];
    }
  }
}

// ---------- GRU row ----------
__device__ __forceinline__ void gru_row(int r,
    const float* __restrict__ gia_t, const float* __restrict__ gh,
    const float* __restrict__ b_ih, const float* __restrict__ b_hh,
    const float* __restrict__ hold, float* __restrict__ hfw,
    ushort_t* __restrict__ hbfw, ushort_t* __restrict__ hbf2w, int tid){
  const float* gir = gia_t + (size_t)r*(3*H_);
  const float* ghr = gh    + (size_t)r*(3*H_);
  for (int j=tid; j<H_; j+=256){
    float i_r = gir[j]      + b_ih[j];
    float i_z = gir[H_+j]   + b_ih[H_+j];
    float i_n = gir[2*H_+j] + b_ih[2*H_+j];
    float h_r = ghr[j]      + b_hh[j];
    float h_z = ghr[H_+j]   + b_hh[H_+j];
    float h_n = ghr[2*H_+j] + b_hh[2*H_+j];
    float rg = 1.f/(1.f+__expf(-(i_r+h_r)));
    float zg = 1.f/(1.f+__expf(-(i_z+h_z)));
    float ng = tanhf(i_n + rg*h_n);
    float hv = (1.f-zg)*ng + zg*hold[(size_t)r*H_ + j];
    hfw[(size_t)r*H_ + j] = hv;
    ushort_t hb = f2b(hv);
    hbfw [r*KP + j] = hb;
    hbf2w[r*KP + j] = f2b(hv - b2f(hb));
  }
}

__global__ __launch_bounds__(256) void gru0_kernel(
    const float* __restrict__ gia_t, const float* __restrict__ gh,
    const float* __restrict__ b_ih, const float* __restrict__ b_hh,
    const float* __restrict__ hold, float* __restrict__ hfw,
    ushort_t* __restrict__ hbfw, ushort_t* __restrict__ hbf2w){
  gru_row(blockIdx.x, gia_t, gh, b_ih, b_hh, hold, hfw, hbfw, hbf2w, threadIdx.x);
}

// ---------- vocab GEMM tile ----------
__device__ __forceinline__ void vocab_tile(
    const ushort_t* __restrict__ A, const ushort_t* __restrict__ Bm,
    float* __restrict__ outp, float* __restrict__ pmax, float* __restrict__ psum,
    int nb, int mb, int tid){
  int wave = tid>>6, lane = tid&63;
  int q = lane>>4, ln = lane&15;
  int m_base = mb*64 + wave*16;
  int n_base = nb*64;
  const ushort_t* Arow = A + (size_t)(m_base + ln)*KP;
  f32x4 acc[4];
  #pragma unroll
  for (int nt=0;nt<4;nt++) acc[nt]=(f32x4){0,0,0,0};
  for (int kk=0; kk<KP; kk+=32){
    int ko = kk + q*8;
    frag8 a  = *(const frag8*)(Arow + ko);
    #pragma unroll
    for (int nt=0;nt<4;nt++){
      frag8 b = *(const frag8*)(Bm + (size_t)(n_base + nt*16 + ln)*KP + ko);
      acc[nt] = __builtin_amdgcn_mfma_f32_16x16x32_bf16(a,b,acc[nt],0,0,0);
    }
  }
  int mrow = m_base + q*4;
  #pragma unroll
  for (int nt=0; nt<4; nt++){
    int n = n_base + nt*16 + ln;
    if (n >= V_) continue;
    #pragma unroll
    for (int i=0;i<4;i++){
      int m = mrow + i;
      if (m < SB) outp[(size_t)m*TV + n] = acc[nt][i];
    }
  }
  #pragma unroll
  for (int i=0;i<4;i++){
    float mx = -3.0e38f;
    #pragma unroll
    for (int nt=0;nt<4;nt++){
      int n = n_base + nt*16 + ln;
      if (n < V_) mx = fmaxf(mx, acc[nt][i]);
    }
    #pragma unroll
    for (int d=8; d>=1; d>>=1) mx = fmaxf(mx, __shfl_xor(mx, d));
    float sm = 0.f;
    #pragma unroll
    for (int nt=0;nt<4;nt++){
      int n = n_base + nt*16 + ln;
      if (n < V_) sm += __expf(acc[nt][i] - mx);
    }
    #pragma unroll
    for (int d=8; d>=1; d>>=1) sm += __shfl_xor(sm, d);
    int m = mrow + i;
    if (ln == 0 && m < SB){
      pmax[(size_t)m*NT_VOC + nb] = mx;
      psum[(size_t)m*NT_VOC + nb] = sm;
    }
  }
}

// ---------- finalize: one (row, part) — float4 scale pass + range-filtered scatter ----------
__device__ __forceinline__ void finalize_row_part(int r, int part,
    float* __restrict__ out_prev,
    const float* __restrict__ Marr, const float* __restrict__ scarr,
    const float* __restrict__ acarr, const float* __restrict__ bcarr,
    const float* __restrict__ ps, const float* __restrict__ pu,
    const int* __restrict__ story_sys, const int* __restrict__ story_user, int tid){
  int v0 = part*FZ_SEG, v1 = v0 + FZ_SEG;
  float M = Marr[r], sc = scarr[r];
  float* row = out_prev + (size_t)r*TV;
  // vectorized rmw: 16B/lane, same per-element math (FZ_SEG=10000 -> 2500 float4s;
  // base offsets are multiples of 16B)
  float4* row4 = (float4*)(row + v0);
  for (int i4=tid; i4<FZ_SEG/4; i4+=256){
    float4 x = row4[i4];
    x.x = __expf(x.x - M)*sc;
    x.y = __expf(x.y - M)*sc;
    x.z = __expf(x.z - M)*sc;
    x.w = __expf(x.w - M)*sc;
    row4[i4] = x;
  }
  __syncthreads();    // drain scale-writes before atomics (same block owns this v-range)
  int b = r & 15;
  float a_ = acarr[r], b_ = bcarr[r];
  for (int i=tid; i<2*L_; i+=256){
    int which = (i >= L_) ? 1 : 0;
    int l = which ? i - L_ : i;
    int v = which ? story_user[b*L_+l] : story_sys[b*L_+l];
    if (v < v0 || v >= v1) continue;
    float val = which ? b_*pu[(size_t)r*L_+l] : a_*ps[(size_t)r*L_+l];
    atomicAdd(row + v, val);
  }
}

// ================= megaC: finalize(t-1) first (long poles), then attend, gg, vocab =================
__global__ __launch_bounds__(256) void megaC_kernel(
    const float* __restrict__ seqS, const float* __restrict__ seqTS, const float* __restrict__ muskS,
    const float* __restrict__ seqU, const float* __restrict__ seqTU, const float* __restrict__ muskU,
    const float* __restrict__ hf_r,
    const ushort_t* __restrict__ hbf_r, const ushort_t* __restrict__ hbf2_r,
    float* __restrict__ ctxS, float* __restrict__ probS,
    float* __restrict__ ctxU, float* __restrict__ probU,
    const ushort_t* __restrict__ embp, float* __restrict__ outp,
    float* __restrict__ pmax, float* __restrict__ psum,
    const ushort_t* __restrict__ Whh_hi, const ushort_t* __restrict__ Whh_lo,
    float* __restrict__ gh, int ngg,
    float* __restrict__ out_prev,
    const float* __restrict__ Marr, const float* __restrict__ scarr,
    const float* __restrict__ acarr, const float* __restrict__ bcarr,
    const float* __restrict__ ps_prev, const float* __restrict__ pu_prev,
    const int* __restrict__ story_sys, const int* __restrict__ story_user,
    int base_off){
  __shared__ float cond_l[ATT_ROWS][H_];
  __shared__ float S_l[ATT_ROWS][208];
  __shared__ float smax[ATT_ROWS], ssum[ATT_ROWS];
  int u = blockIdx.x + base_off, tid = threadIdx.x;
  if (u < FZ_BLKS){
    finalize_row_part(u>>1, u&1, out_prev, Marr, scarr, acarr, bcarr,
                      ps_prev, pu_prev, story_sys, story_user, tid);
    return;
  }
  u -= FZ_BLKS;
  if (u < ATT3_BLKS){
    attend3_body(u, seqS, seqTS, muskS, seqU, seqTU, muskU, hf_r,
                 ctxS, probS, ctxU, probU, cond_l, S_l, smax, ssum);
    return;
  }
  u -= ATT3_BLKS;
  if (u < GG_PAD){
    if (u < GG_T && ngg)
      hl_gemm_tile(hbf_r, hbf2_r, Whh_hi, Whh_lo, gh, u % 19, u / 19, tid);
    return;
  }
  u -= GG_PAD;
  // vocab: XCD-chunked swizzle (role offset 1280 and base_off 0/960 are %8==0)
  int x = u & 7, j = u >> 3;
  int nb = x*40 + (j>>3), mb = j & 7;
  if (nb < NT_VOC)
    vocab_tile(hbf_r, embp, outp, pmax, psum, nb, mb, tid);
}

// ================= finalstats: gru(t+1) + per-row scalars + softmax stats =================
__device__ __forceinline__ float block_reduce(float v, float* red, int tid){
  red[tid]=v; __syncthreads();
  for (int s=128;s>0;s>>=1){ if(tid<s) red[tid]+=red[tid+s]; __syncthreads(); }
  float r = red[0]; __syncthreads();
  return r;
}

__global__ __launch_bounds__(256) void finalstats_kernel(
    const float* __restrict__ hf_r, const float* __restrict__ cs, const float* __restrict__ cu,
    const float* __restrict__ xf_t,
    const float* __restrict__ Wr_w, const float* __restrict__ Wr_b,
    const float* __restrict__ Wc_w, const float* __restrict__ Wc_b,
    const float* __restrict__ Wg_w, const float* __restrict__ Wg_b,
    const float* __restrict__ pmax, const float* __restrict__ psum,
    float* __restrict__ Marr, float* __restrict__ scarr,
    float* __restrict__ acarr, float* __restrict__ bcarr,
    float* __restrict__ gate_out, int do_gate,
    const float* __restrict__ gia_t1, const float* __restrict__ gh,
    const float* __restrict__ b_ih, const float* __restrict__ b_hh,
    float* __restrict__ hf_w, ushort_t* __restrict__ hbf_w, ushort_t* __restrict__ hbf2_w,
    int do_gru){
  __shared__ float red[256];
  int r = blockIdx.x, tid = threadIdx.x;
  if (do_gru)
    gru_row(r, gia_t1, gh, b_ih, b_hh, hf_r, hf_w, hbf_w, hbf2_w, tid);
  const float* h   = hf_r + (size_t)r*H_;
  const float* csr = cs + (size_t)r*H_;
  const float* cur = cu + (size_t)r*H_;
  const float* xr  = xf_t + (size_t)r*H_;
  float sr=0, ss=0, su=0, g0=0, g1=0, g2=0;
  for (int k=tid;k<4*H_;k+=256){
    float v = (k<H_)? h[k] : (k<2*H_)? csr[k-H_] : (k<3*H_)? cur[k-2*H_] : xr[k-3*H_];
    sr += Wr_w[k]*v;
  }
  for (int k=tid;k<3*H_;k+=256){
    float w = Wc_w[k];
    float vs = (k<H_)? h[k] : (k<2*H_)? csr[k-H_] : xr[k-2*H_];
    float vu = (k<H_)? h[k] : (k<2*H_)? cur[k-H_] : xr[k-2*H_];
    ss += w*vs; su += w*vu;
  }
  if (do_gate){
    for (int k=tid;k<2*H_;k+=256){
      float m = (k<H_)? csr[k] : cur[k-H_];
      g0 += Wg_w[k]*m;
      g1 += Wg_w[2*H_+k]*m;
      g2 += Wg_w[4*H_+k]*m;
    }
  }
  float SR = block_reduce(sr, red, tid);
  float SS = block_reduce(ss, red, tid);
  float SU = block_reduce(su, red, tid);
  if (do_gate){
    float G0=block_reduce(g0,red,tid);
    float G1=block_reduce(g1,red,tid);
    float G2=block_reduce(g2,red,tid);
    if (tid==0){
      gate_out[r*G_+0] = G0 + Wg_b[0];
      gate_out[r*G_+1] = G1 + Wg_b[1];
      gate_out[r*G_+2] = G2 + Wg_b[2];
    }
  }
  // softmax stats from online partials
  const float* pmr = pmax + (size_t)r*NT_VOC;
  const float* psr = psum + (size_t)r*NT_VOC;
  float lm = -3.0e38f;
  for (int nb=tid; nb<NT_VOC; nb+=256) lm = fmaxf(lm, pmr[nb]);
  red[tid]=lm; __syncthreads();
  for (int s=128;s>0;s>>=1){ if(tid<s) red[tid]=fmaxf(red[tid],red[tid+s]); __syncthreads(); }
  float M = red[0]; __syncthreads();
  float ls = 0.f;
  for (int nb=tid; nb<NT_VOC; nb+=256) ls += psr[nb]*__expf(pmr[nb]-M);
  float S = block_reduce(ls, red, tid);
  if (tid==0){
    float swv = 1.f/(1.f+__expf(-(SR + Wr_b[0])));
    float lcs = SS + Wc_b[0];
    float lcu = SU + Wc_b[0];
    float mx = fmaxf(lcs,lcu);
    float es = __expf(lcs-mx), eu = __expf(lcu-mx);
    float al = es/(es+eu);
    Marr[r]  = M;
    scarr[r] = swv / S;
    acarr[r] = (1.f-swv)*al;
    bcarr[r] = (1.f-swv)*(1.f-al);
  }
}

// ---------- tail finalize (t = T-1), 2-way split ----------
__global__ __launch_bounds__(256) void finalize_kernel(
    float* __restrict__ out_prev,
    const float* __restrict__ Marr, const float* __restrict__ scarr,
    const float* __restrict__ acarr, const float* __restrict__ bcarr,
    const float* __restrict__ ps, const float* __restrict__ pu,
    const int* __restrict__ story_sys, const int* __restrict__ story_user){
  int u = blockIdx.x;
  finalize_row_part(u>>1, u&1, out_prev, Marr, scarr, acarr, bcarr,
                    ps, pu, story_sys, story_user, threadIdx.x);
}

// ================= legacy basic-path kernels (small workspace fallback) =================

__global__ void padsplit_kernel(const float* __restrict__ src,
                                ushort_t* __restrict__ hi, ushort_t* __restrict__ lo){
  int idx = blockIdx.x*256 + threadIdx.x;
  if (idx >= NP_G*KP) return;
  int r = idx / KP, c = idx - r*KP;
  ushort_t h = 0, l = 0;
  if (r < 3*H_ && c < H_){
    float v = src[r*H_ + c];
    h = f2b(v);
    l = f2b(v - b2f(h));
  }
  hi[idx] = h; lo[idx] = l;
}

__global__ void initL_kernel(const float* __restrict__ slot_att, const float* __restrict__ slot_emb,
                            float* __restrict__ xf, ushort_t* __restrict__ xbf, ushort_t* __restrict__ xbf2,
                            ushort_t* __restrict__ hbf, ushort_t* __restrict__ hbf2,
                            float* __restrict__ hf){
  int idx = blockIdx.x*256 + threadIdx.x;
  if (idx >= MP*KP) return;
  int r = idx/KP, c = idx - r*KP;
  ushort_t xh = 0, xl = 0;
  if (r < SB && c < H_){
    int s = r >> 4;
    float xv = slot_emb[s*H_ + c];
    xf[r*H_ + c] = xv;
    xh = f2b(xv); xl = f2b(xv - b2f(xh));
    hf[r*H_ + c] = slot_att[s*H_ + c];
  }
  xbf[idx] = xh; xbf2[idx] = xl;
  hbf[idx] = 0;  hbf2[idx] = 0;
}

__global__ void addh_kernel(const float* __restrict__ cs, const float* __restrict__ cu,
                            float* __restrict__ hf, ushort_t* __restrict__ hbf, ushort_t* __restrict__ hbf2){
  int idx = blockIdx.x*256 + threadIdx.x;
  if (idx >= SB*H_) return;
  int r = idx/H_, c = idx - r*H_;
  float v = cs[idx] + cu[idx];
  hf[idx] = v;
  ushort_t hb = f2b(v);
  hbf [r*KP + c] = hb;
  hbf2[r*KP + c] = f2b(v - b2f(hb));
}

__global__ __launch_bounds__(256) void attendL_kernel(
    const float* __restrict__ seq, const float* __restrict__ musk,
    const float* __restrict__ cond, float* __restrict__ ctx, float* __restrict__ prob){
  __shared__ float hrow[H_];
  __shared__ float pl[L_];
  __shared__ float red[256];
  int r = blockIdx.x; int tid = threadIdx.x;
  int b = r & 15;
  for (int k=tid; k<H_; k+=256) hrow[k] = cond[(size_t)r*H_ + k];
  __syncthreads();
  float score = -3.0e38f;
  if (tid < L_){
    const float4* sp = (const float4*)(seq + ((size_t)b*L_ + tid)*H_);
    float acc = 0.f;
    for (int k=0; k<H_; k+=4){
      float4 v = sp[k>>2];
      acc += hrow[k]*v.x + hrow[k+1]*v.y + hrow[k+2]*v.z + hrow[k+3]*v.w;
    }
    score = acc + musk[b*L_ + tid];
  }
  red[tid] = score; __syncthreads();
  for (int s=128;s>0;s>>=1){ if(tid<s) red[tid]=fmaxf(red[tid],red[tid+s]); __syncthreads(); }
  float mv = red[0]; __syncthreads();
  float e = (tid<L_) ? __expf(score-mv) : 0.f;
  red[tid] = e; __syncthreads();
  for (int s=128;s>0;s>>=1){ if(tid<s) red[tid]+=red[tid+s]; __syncthreads(); }
  float sv = red[0]; __syncthreads();
  if (tid<L_){ float p = e/sv; pl[tid]=p; prob[(size_t)r*L_+tid]=p; }
  __syncthreads();
  for (int k=tid; k<H_; k+=256){
    float a = 0.f;
    const float* sp = seq + (size_t)b*L_*H_ + k;
    for (int l=0;l<L_;l++) a += pl[l]*sp[(size_t)l*H_];
    ctx[(size_t)r*H_ + k] = a;
  }
}

__global__ __launch_bounds__(256) void grugemmL_kernel(
    const ushort_t* __restrict__ xbf, const ushort_t* __restrict__ xbf2,
    const ushort_t* __restrict__ hbf, const ushort_t* __restrict__ hbf2,
    const ushort_t* __restrict__ Wih_hi, const ushort_t* __restrict__ Wih_lo,
    const ushort_t* __restrict__ Whh_hi, const ushort_t* __restrict__ Whh_lo,
    float* __restrict__ gi, float* __restrict__ gh){
  int tid = threadIdx.x;
  int wave = tid>>6, lane = tid&63;
  int q = lane>>4, ln = lane&15;
  int m_base = blockIdx.y*64 + wave*16;
  int n_base = blockIdx.x*64;
  const ushort_t* Ax  = xbf  + (size_t)(m_base + ln)*KP;
  const ushort_t* Ax2 = xbf2 + (size_t)(m_base + ln)*KP;
  const ushort_t* Ah  = hbf  + (size_t)(m_base + ln)*KP;
  const ushort_t* Ah2 = hbf2 + (size_t)(m_base + ln)*KP;
  f32x4 ai[4], ah[4];
  #pragma unroll
  for (int nt=0;nt<4;nt++){ ai[nt]=(f32x4){0,0,0,0}; ah[nt]=(f32x4){0,0,0,0}; }
  for (int kk=0; kk<KP; kk+=32){
    int ko = kk + q*8;
    frag8 ax  = *(const frag8*)(Ax  + ko);
    frag8 ax2 = *(const frag8*)(Ax2 + ko);
    frag8 ahv = *(const frag8*)(Ah  + ko);
    frag8 ah2 = *(const frag8*)(Ah2 + ko);
    #pragma unroll
    for (int nt=0;nt<4;nt++){
      size_t nrow = (size_t)(n_base + nt*16 + ln)*KP + ko;
      frag8 bih = *(const frag8*)(Wih_hi + nrow);
      frag8 bil = *(const frag8*)(Wih_lo + nrow);
      frag8 bhh = *(const frag8*)(Whh_hi + nrow);
      frag8 bhl = *(const frag8*)(Whh_lo + nrow);
      ai[nt] = __builtin_amdgcn_mfma_f32_16x16x32_bf16(ax, bih, ai[nt],0,0,0);
      ai[nt] = __builtin_amdgcn_mfma_f32_16x16x32_bf16(ax, bil, ai[nt],0,0,0);
      ai[nt] = __builtin_amdgcn_mfma_f32_16x16x32_bf16(ax2,bih, ai[nt],0,0,0);
      ah[nt] = __builtin_amdgcn_mfma_f32_16x16x32_bf16(ahv,bhh, ah[nt],0,0,0);
      ah[nt] = __builtin_amdgcn_mfma_f32_16x16x32_bf16(ahv,bhl, ah[nt],0,0,0);
      ah[nt] = __builtin_amdgcn_mfma_f32_16x16x32_bf16(ah2,bhh, ah[nt],0,0,0);
    }
  }
  int mrow = m_base + q*4;
  #pragma unroll
  for (int nt=0; nt<4; nt++){
    int n = n_base + nt*16 + ln;
    if (n >= 3*H_) continue;
    #pragma unroll
    for (int i=0;i<4;i++){
      int m = mrow + i;
      if (m < SB){
        gi[(size_t)m*(3*H_) + n] = ai[nt][i];
        gh[(size_t)m*(3*H_) + n] = ah[nt][i];
      }
    }
  }
}

__global__ void gruL_kernel(const float* __restrict__ gi, const float* __restrict__ gh,
    const float* __restrict__ b_ih, const float* __restrict__ b_hh,
    float* __restrict__ hf, ushort_t* __restrict__ hbf, ushort_t* __restrict__ hbf2){
  int idx = blockIdx.x*256 + threadIdx.x;
  if (idx >= SB*H_) return;
  int r = idx/H_, j = idx - r*H_;
  const float* gir = gi + (size_t)r*(3*H_);
  const float* ghr = gh + (size_t)r*(3*H_);
  float i_r = gir[j]      + b_ih[j];
  float i_z = gir[H_+j]   + b_ih[H_+j];
  float i_n = gir[2*H_+j] + b_ih[2*H_+j];
  float h_r = ghr[j]      + b_hh[j];
  float h_z = ghr[H_+j]   + b_hh[H_+j];
  float h_n = ghr[2*H_+j] + b_hh[2*H_+j];
  float rg = 1.f/(1.f+__expf(-(i_r+h_r)));
  float zg = 1.f/(1.f+__expf(-(i_z+h_z)));
  float ng = tanhf(i_n + rg*h_n);
  float hv = (1.f-zg)*ng + zg*hf[idx];
  hf[idx] = hv;
  ushort_t hb = f2b(hv);
  hbf [r*KP + j] = hb;
  hbf2[r*KP + j] = f2b(hv - b2f(hb));
}

__global__ __launch_bounds__(256) void smallL_kernel(
    const float* __restrict__ hf, const float* __restrict__ cs, const float* __restrict__ cu,
    const float* __restrict__ xf,
    const float* __restrict__ Wr_w, const float* __restrict__ Wr_b,
    const float* __restrict__ Wc_w, const float* __restrict__ Wc_b,
    const float* __restrict__ Wg_w, const float* __restrict__ Wg_b,
    float* __restrict__ sw_arr, float* __restrict__ ac_arr, float* __restrict__ bc_arr,
    float* __restrict__ gate_out, int do_gate){
  __shared__ float red[256];
  int r = blockIdx.x, tid = threadIdx.x;
  const float* h   = hf + (size_t)r*H_;
  const float* csr = cs + (size_t)r*H_;
  const float* cur = cu + (size_t)r*H_;
  const float* xr  = xf + (size_t)r*H_;
  float sr=0, ss=0, su=0, g0=0, g1=0, g2=0;
  for (int k=tid;k<4*H_;k+=256){
    float v = (k<H_)? h[k] : (k<2*H_)? csr[k-H_] : (k<3*H_)? cur[k-2*H_] : xr[k-3*H_];
    sr += Wr_w[k]*v;
  }
  for (int k=tid;k<3*H_;k+=256){
    float w = Wc_w[k];
    float vs = (k<H_)? h[k] : (k<2*H_)? csr[k-H_] : xr[k-2*H_];
    float vu = (k<H_)? h[k] : (k<2*H_)? cur[k-H_] : xr[k-2*H_];
    ss += w*vs; su += w*vu;
  }
  if (do_gate){
    for (int k=tid;k<2*H_;k+=256){
      float m = (k<H_)? csr[k] : cur[k-H_];
      g0 += Wg_w[k]*m;
      g1 += Wg_w[2*H_+k]*m;
      g2 += Wg_w[4*H_+k]*m;
    }
  }
  float SR = block_reduce(sr, red, tid);
  float SS = block_reduce(ss, red, tid);
  float SU = block_reduce(su, red, tid);
  float G0=0,G1=0,G2=0;
  if (do_gate){ G0=block_reduce(g0,red,tid); G1=block_reduce(g1,red,tid); G2=block_reduce(g2,red,tid); }
  if (tid==0){
    float swv = 1.f/(1.f+__expf(-(SR + Wr_b[0])));
    float lcs = SS + Wc_b[0];
    float lcu = SU + Wc_b[0];
    float mx = fmaxf(lcs,lcu);
    float es = __expf(lcs-mx), eu = __expf(lcu-mx);
    float al = es/(es+eu);
    sw_arr[r]=swv; ac_arr[r]=(1.f-swv)*al; bc_arr[r]=(1.f-swv)*(1.f-al);
    if (do_gate){
      gate_out[r*G_+0] = G0 + Wg_b[0];
      gate_out[r*G_+1] = G1 + Wg_b[1];
      gate_out[r*G_+2] = G2 + Wg_b[2];
    }
  }
}

__device__ __forceinline__ frag8 load_cvt8(const float* p){
  float4 a = *(const float4*)p;
  float4 b = *(const float4*)(p+4);
  frag8 r;
  r[0]=(short)f2b(a.x); r[1]=(short)f2b(a.y); r[2]=(short)f2b(a.z); r[3]=(short)f2b(a.w);
  r[4]=(short)f2b(b.x); r[5]=(short)f2b(b.y); r[6]=(short)f2b(b.z); r[7]=(short)f2b(b.w);
  return r;
}

__global__ __launch_bounds__(256) void vocabL_kernel(
    const ushort_t* __restrict__ A, const float* __restrict__ emb,
    float* __restrict__ outp){
  int tid = threadIdx.x;
  int wave = tid>>6, lane = tid&63;
  int q = lane>>4, ln = lane&15;
  int m_base = blockIdx.y*64 + wave*16;
  int n_base = blockIdx.x*64;
  const ushort_t* Arow = A + (size_t)(m_base + ln)*KP;
  int n0 = min(n_base +  0 + ln, V_-1);
  int n1 = min(n_base + 16 + ln, V_-1);
  int n2 = min(n_base + 32 + ln, V_-1);
  int n3 = min(n_base + 48 + ln, V_-1);
  const float* B0 = emb + (size_t)n0*H_;
  const float* B1 = emb + (size_t)n1*H_;
  const float* B2 = emb + (size_t)n2*H_;
  const float* B3 = emb + (size_t)n3*H_;
  f32x4 acc0={0,0,0,0}, acc1={0,0,0,0}, acc2={0,0,0,0}, acc3={0,0,0,0};
  for (int kk=0; kk<KP; kk+=32){
    int ko = kk + q*8;
    int safe = (ko < H_) ? ko : 0;
    frag8 a  = *(const frag8*)(Arow + ko);
    frag8 b0 = load_cvt8(B0 + safe);
    frag8 b1 = load_cvt8(B1 + safe);
    frag8 b2 = load_cvt8(B2 + safe);
    frag8 b3 = load_cvt8(B3 + safe);
    acc0 = __builtin_amdgcn_mfma_f32_16x16x32_bf16(a,b0,acc0,0,0,0);
    acc1 = __builtin_amdgcn_mfma_f32_16x16x32_bf16(a,b1,acc1,0,0,0);
    acc2 = __builtin_amdgcn_mfma_f32_16x16x32_bf16(a,b2,acc2,0,0,0);
    acc3 = __builtin_amdgcn_mfma_f32_16x16x32_bf16(a,b3,acc3,0,0,0);
  }
  int mrow = m_base + q*4;
  #pragma unroll
  for (int nt=0; nt<4; nt++){
    f32x4 acc = (nt==0)?acc0:(nt==1)?acc1:(nt==2)?acc2:acc3;
    int n = n_base + nt*16 + ln;
    if (n >= V_) continue;
    #pragma unroll
    for (int i=0;i<4;i++){
      int m = mrow + i;
      if (m < SB) outp[(size_t)m*TV + n] = acc[i];
    }
  }
}

__global__ __launch_bounds__(256) void softmax_scatterL_kernel(
    const float* __restrict__ sw_arr, const float* __restrict__ ac, const float* __restrict__ bc,
    const float* __restrict__ p_s, const float* __restrict__ p_u,
    const int* __restrict__ story_sys, const int* __restrict__ story_user,
    float* __restrict__ outp){
  __shared__ float red[256];
  int r = blockIdx.x, tid = threadIdx.x;
  float* row = outp + (size_t)r*TV;
  float m = -3.0e38f;
  for (int v=tid; v<V_; v+=256) m = fmaxf(m, row[v]);
  red[tid]=m; __syncthreads();
  for (int s=128;s>0;s>>=1){ if(tid<s) red[tid]=fmaxf(red[tid],red[tid+s]); __syncthreads(); }
  float M = red[0]; __syncthreads();
  float sum = 0.f;
  for (int v=tid; v<V_; v+=256) sum += __expf(row[v] - M);
  red[tid]=sum; __syncthreads();
  for (int s=128;s>0;s>>=1){ if(tid<s) red[tid]+=red[tid+s]; __syncthreads(); }
  float S = red[0]; __syncthreads();
  float scale = sw_arr[r]/S;
  for (int v=tid; v<V_; v+=256) row[v] = __expf(row[v] - M)*scale;
  __syncthreads();
  int b = r & 15;
  float a_ = ac[r], b_ = bc[r];
  for (int i=tid; i<2*L_; i+=256){
    int which = (i >= L_) ? 1 : 0;
    int l = which ? i - L_ : i;
    int v = which ? story_user[b*L_+l] : story_sys[b*L_+l];
    float val = which ? b_*p_u[(size_t)r*L_+l] : a_*p_s[(size_t)r*L_+l];
    atomicAdd(row + v, val);
  }
}

__global__ void nextxL_kernel(const int* __restrict__ targets, const float* __restrict__ emb,
    float* __restrict__ xf, ushort_t* __restrict__ xbf, ushort_t* __restrict__ xbf2, int t){
  int idx = blockIdx.x*256 + threadIdx.x;
  if (idx >= SB*H_) return;
  int r = idx/H_, k = idx - r*H_;
  int s = r>>4, b = r&15;
  int tg = targets[(b*S_ + s)*T_ + t];
  float v = emb[(size_t)tg*H_ + k];
  xf[(size_t)r*H_ + k] = v;
  ushort_t hb = f2b(v);
  xbf [r*KP + k] = hb;
  xbf2[r*KP + k] = f2b(v - b2f(hb));
}

// ================= host =================
extern "C" void kernel_launch(void* const* d_in, const int* in_sizes, int n_in,
                              void* d_out, int out_size, void* d_ws, size_t ws_size,
                              hipStream_t stream){
  const float* sys_H    = (const float*)d_in[0];
  const float* user_H   = (const float*)d_in[1];
  const float* sys_musk = (const float*)d_in[2];
  const float* user_musk= (const float*)d_in[3];
  const float* emb      = (const float*)d_in[4];
  const float* W_ih     = (const float*)d_in[5];
  const float* W_hh     = (const float*)d_in[6];
  const float* b_ih     = (const float*)d_in[7];
  const float* b_hh     = (const float*)d_in[8];
  const float* Wg_w     = (const float*)d_in[9];
  const float* Wg_b     = (const float*)d_in[10];
  const float* Wr_w     = (const float*)d_in[11];
  const float* Wr_b     = (const float*)d_in[12];
  const float* Wc_w     = (const float*)d_in[13];
  const float* Wc_b     = (const float*)d_in[14];
  const float* slot_att = (const float*)d_in[15];
  const float* slot_emb = (const float*)d_in[16];
  const int* story_sys  = (const int*)d_in[17];
  const int* story_user = (const int*)d_in[18];
  const int* targets    = (const int*)d_in[19];
  float* out = (float*)d_out;                      // OUTPUT IS FLOAT32
  float* gate_out = out + (size_t)SB*TV;

  char* base = (char*)d_ws;
  size_t off = 0;
  auto take = [&](size_t bytes)->char*{
    char* p = base + off; off += (bytes + 255) & ~(size_t)255; return p;
  };
  // --- shared (legacy + primary) ---
  ushort_t* Wih_hi = (ushort_t*)take((size_t)NP_G*KP*2);
  ushort_t* Wih_lo = (ushort_t*)take((size_t)NP_G*KP*2);
  ushort_t* Whh_hi = (ushort_t*)take((size_t)NP_G*KP*2);
  ushort_t* Whh_lo = (ushort_t*)take((size_t)NP_G*KP*2);
  ushort_t* hbf0  = (ushort_t*)take((size_t)MP*KP*2);
  ushort_t* hbf20 = (ushort_t*)take((size_t)MP*KP*2);
  float* hf0   = (float*)take((size_t)SB*H_*4);
  float* ctx_s = (float*)take((size_t)SB*H_*4);
  float* ctx_u = (float*)take((size_t)SB*H_*4);
  float* p_s   = (float*)take((size_t)SB*L_*4);
  float* p_u   = (float*)take((size_t)SB*L_*4);
  float* gh    = (float*)take((size_t)SB*3*H_*4);
  // --- legacy-only ---
  float* gi_l  = (float*)take((size_t)SB*3*H_*4);
  float* xf_l  = (float*)take((size_t)SB*H_*4);
  ushort_t* xbf_l  = (ushort_t*)take((size_t)MP*KP*2);
  ushort_t* xbf2_l = (ushort_t*)take((size_t)MP*KP*2);
  float* sw_arr = (float*)take(SB*4);
  float* ac_arr = (float*)take(SB*4);
  float* bc_arr = (float*)take(SB*4);
  size_t off_legacy = off;
  // --- primary-only ---
  ushort_t* hbf1  = (ushort_t*)take((size_t)MP*KP*2);
  ushort_t* hbf21 = (ushort_t*)take((size_t)MP*KP*2);
  float* hf1   = (float*)take((size_t)SB*H_*4);
  float* pmaxw = (float*)take((size_t)MP*NT_VOC*4);
  float* psumw = (float*)take((size_t)MP*NT_VOC*4);
  float* gi_all= (float*)take((size_t)T_*SB*3*H_*4);
  float* xf_all= (float*)take((size_t)T_*SB*H_*4);
  ushort_t* xa_hi = (ushort_t*)take((size_t)T_*MP*KP*2);
  ushort_t* xa_lo = (ushort_t*)take((size_t)T_*MP*KP*2);
  ushort_t* embp  = (ushort_t*)take((size_t)NP_EMB*KP*2);
  float* seqT_s = (float*)take((size_t)B_*H_*L_*4);
  float* seqT_u = (float*)take((size_t)B_*H_*L_*4);
  // double-buffered prob + per-row stat arrays (by t parity)
  float* psb[2] = { (float*)take((size_t)SB*L_*4), (float*)take((size_t)SB*L_*4) };
  float* pub[2] = { (float*)take((size_t)SB*L_*4), (float*)take((size_t)SB*L_*4) };
  float* Mar[2] = { (float*)take(SB*4), (float*)take(SB*4) };
  float* scar[2]= { (float*)take(SB*4), (float*)take(SB*4) };
  float* acar[2]= { (float*)take(SB*4), (float*)take(SB*4) };
  float* bcar[2]= { (float*)take(SB*4), (float*)take(SB*4) };
  size_t off_full = off;

  if (off_full <= ws_size){
    // ============ primary path: 25 dispatches ============
    setup1_kernel<<<SETUP1_UNITS,256,0,stream>>>(
        sys_H, user_H, seqT_s, seqT_u, slot_att, slot_emb,
        xf_all, xa_hi, xa_lo, hbf0, hbf20, hbf1, hbf21, hf0,
        targets, emb, W_ih, Wih_hi, Wih_lo, W_hh, Whh_hi, Whh_lo, embp);
    pre_kernel<<<PRE_UNITS,256,0,stream>>>(
        sys_H, seqT_s, sys_musk, user_H, seqT_u, user_musk,
        hf0, ctx_s, psb[1], ctx_u, pub[1],
        xa_hi, xa_lo, Wih_hi, Wih_lo, gi_all);
    // gg0v2: gh = bf16hl(ctx_s+ctx_u) @ Whh  (also writes hf0 = ctx_s+ctx_u)
    gg0v2_kernel<<<GG_T,256,0,stream>>>(ctx_s, ctx_u, Whh_hi, Whh_lo, gh, hf0);
    // gru(0): h(0) -> buf1
    gru0_kernel<<<SB,256,0,stream>>>(gi_all, gh, b_ih, b_hh, hf0, hf1, hbf1, hbf21);

    float* hfb[2]      = { hf0, hf1 };
    ushort_t* hbfb[2]  = { hbf0, hbf1 };
    ushort_t* hbf2b[2] = { hbf20, hbf21 };
    for (int t=0; t<T_; t++){
      int cur = (t+1)&1;     // h(t) lives here
      int nxt = t&1;         // gru(t+1) writes here
      int ngg = (t < T_-1) ? 1 : 0;
      int base_off = (t > 0) ? 0 : FZ_BLKS;   // skip finalize role entirely at t=0 (960 %8==0)
      int grid = MEGAC_BLKS - base_off;
      int pc = t&1;                   // attend(t) prob parity
      int pp = (t-1)&1;               // finalize(t-1) parity
      float* outp = out + (size_t)t*V_;
      float* outprev = out + (size_t)(t>0 ? t-1 : 0)*V_;
      megaC_kernel<<<grid,256,0,stream>>>(
          sys_H, seqT_s, sys_musk, user_H, seqT_u, user_musk,
          hfb[cur], hbfb[cur], hbf2b[cur],
          ctx_s, psb[pc], ctx_u, pub[pc],
          embp, outp, pmaxw, psumw,
          Whh_hi, Whh_lo, gh, ngg,
          outprev, Mar[pp], scar[pp], acar[pp], bcar[pp],
          psb[pp], pub[pp], story_sys, story_user, base_off);
      finalstats_kernel<<<SB,256,0,stream>>>(
          hfb[cur], ctx_s, ctx_u, xf_all + (size_t)t*SB*H_,
          Wr_w, Wr_b, Wc_w, Wc_b, Wg_w, Wg_b,
          pmaxw, psumw,
          Mar[t&1], scar[t&1], acar[t&1], bcar[t&1],
          gate_out, (t==0)?1:0,
          gi_all + (size_t)(t<T_-1 ? t+1 : 0)*SB*3*H_, gh, b_ih, b_hh,
          hfb[nxt], hbfb[nxt], hbf2b[nxt], (t<T_-1)?1:0);
    }
    // tail finalize for t = T-1 (parity (T-1)&1 = 1)
    finalize_kernel<<<FZ_BLKS,256,0,stream>>>(
        out + (size_t)(T_-1)*V_, Mar[1], scar[1], acar[1], bcar[1],
        psb[1], pub[1], story_sys, story_user);
    return;
  }

  if (off_legacy <= ws_size){
    // ============ legacy basic path ============
    padsplit_kernel<<<(NP_G*KP+255)/256,256,0,stream>>>(W_ih, Wih_hi, Wih_lo);
    padsplit_kernel<<<(NP_G*KP+255)/256,256,0,stream>>>(W_hh, Whh_hi, Whh_lo);
    initL_kernel<<<(MP*KP+255)/256,256,0,stream>>>(slot_att, slot_emb, xf_l, xbf_l, xbf2_l,
                                                   hbf0, hbf20, hf0);
    attendL_kernel<<<SB,256,0,stream>>>(sys_H, sys_musk, hf0, ctx_s, p_s);
    attendL_kernel<<<SB,256,0,stream>>>(user_H, user_musk, hf0, ctx_u, p_u);
    addh_kernel<<<(SB*H_+255)/256,256,0,stream>>>(ctx_s, ctx_u, hf0, hbf0, hbf20);
    for (int t=0; t<T_; t++){
      grugemmL_kernel<<<dim3(NP_G/64, MP/64),256,0,stream>>>(xbf_l, xbf2_l, hbf0, hbf20,
          Wih_hi, Wih_lo, Whh_hi, Whh_lo, gi_l, gh);
      gruL_kernel<<<(SB*H_+255)/256,256,0,stream>>>(gi_l, gh, b_ih, b_hh, hf0, hbf0, hbf20);
      attendL_kernel<<<SB,256,0,stream>>>(sys_H, sys_musk, hf0, ctx_s, p_s);
      attendL_kernel<<<SB,256,0,stream>>>(user_H, user_musk, hf0, ctx_u, p_u);
      smallL_kernel<<<SB,256,0,stream>>>(hf0, ctx_s, ctx_u, xf_l, Wr_w, Wr_b, Wc_w, Wc_b,
                                         Wg_w, Wg_b, sw_arr, ac_arr, bc_arr, gate_out, (t==0)?1:0);
      float* outp = out + (size_t)t*V_;
      vocabL_kernel<<<dim3(NT_VOC, MP/64),256,0,stream>>>(hbf0, emb, outp);
      softmax_scatterL_kernel<<<SB,256,0,stream>>>(sw_arr, ac_arr, bc_arr, p_s, p_u,
                                                   story_sys, story_user, outp);
      if (t < T_-1)
        nextxL_kernel<<<(SB*H_+255)/256,256,0,stream>>>(targets, emb, xf_l, xbf_l, xbf2_l, t);
    }
  }
}

// Round 11
// 1388.839 us; speedup vs baseline: 1.1064x; 1.0173x over previous
//
#include <hip/hip_runtime.h>
#include <stdint.h>

#define B_ 16
#define S_ 30
#define T_ 10
#define H_ 400
#define V_ 20000
#define L_ 200
#define G_ 3
#define SB 480          // S*B rows
#define KP 416          // padded K (13*32)
#define MP 512          // padded M rows (8*64)
#define NT_VOC 313      // ceil(20000/64)
#define NP_G 1216       // padded 3H rows (19*64)
#define NP_EMB 20096    // padded V rows (314*64)
#define TV (T_*V_)      // 200000

#define GG_T 152        // 19*8 hh tiles per t
#define GIA_UNITS (T_*GG_T)         // 1520

// attention v3: one block per (which,b,row-group)
#define ATT_ROWS 6
#define ATT_NRB 5                   // 30/6
#define ATT3_BLKS (2*B_*ATT_NRB)    // 160
// vocab with XCD-chunked swizzle: 8 chunks x 40 nb x 8 mb
#define VOC_PAD 2560
// finalize role: 2-way split rows (R7-verified config)
#define FZ_SPLIT 2
#define FZ_SEG (V_/FZ_SPLIT)        // 10000
#define FZ_BLKS (SB*FZ_SPLIT)       // 960 (%8==0)
#define GG_PAD 160                  // GG_T padded to keep vocab offset %8==0
#define MEGAC_BLKS (FZ_BLKS + ATT3_BLKS + GG_PAD + VOC_PAD)   // 3840

#define PRE_UNITS (ATT3_BLKS + GIA_UNITS)

// setup1 role counts
#define TT_TILES 1456   // 16 * 7 * 13 transpose tiles
#define INIT_BLKS 832   // MP*KP/256
#define XA8_BLKS 936    // 9*MP*KP/(256*8)
#define PS8_BLKS 247    // NP_G*KP/(256*8)
#define EC8_BLKS 4082   // NP_EMB*KP/(256*8)
#define SETUP1_UNITS (2*TT_TILES + INIT_BLKS + XA8_BLKS + 2*PS8_BLKS + EC8_BLKS)

typedef unsigned short ushort_t;
typedef __attribute__((ext_vector_type(8))) short frag8;       // 8 bf16
typedef __attribute__((ext_vector_type(8))) unsigned short us8;
typedef __attribute__((ext_vector_type(4))) unsigned short us4;
typedef __attribute__((ext_vector_type(4))) float f32x4;

__device__ __forceinline__ float b2f(ushort_t u){ return __uint_as_float(((unsigned)u)<<16); }
__device__ __forceinline__ ushort_t f2b(float f){
  unsigned u = __float_as_uint(f);
  unsigned r = u + 0x7fffu + ((u>>16)&1u);   // RNE
  return (ushort_t)(r>>16);
}

// ================= setup bodies =================

__device__ __forceinline__ void padsplit8_body(const float* __restrict__ src,
    ushort_t* __restrict__ hi, ushort_t* __restrict__ lo, int u8){
  int base = u8*8;
  if (base >= NP_G*KP) return;
  int r = base / KP, c = base - r*KP;
  us8 h, l;
  if (r < 3*H_ && c+8 <= H_){
    float4 a = *(const float4*)(src + (size_t)r*H_ + c);
    float4 b = *(const float4*)(src + (size_t)r*H_ + c + 4);
    float v[8] = {a.x,a.y,a.z,a.w,b.x,b.y,b.z,b.w};
    #pragma unroll
    for (int i=0;i<8;i++){ h[i]=f2b(v[i]); l[i]=f2b(v[i]-b2f(h[i])); }
  } else {
    #pragma unroll
    for (int i=0;i<8;i++){ h[i]=0; l[i]=0; }
  }
  *(us8*)(hi+base) = h; *(us8*)(lo+base) = l;
}

__device__ __forceinline__ void embcvt8_body(const float* __restrict__ emb,
    ushort_t* __restrict__ dst, long long u8){
  long long base = u8*8;
  if (base >= (long long)NP_EMB*KP) return;
  int r = (int)(base / KP), c = (int)(base - (long long)r*KP);
  us8 h;
  if (r < V_ && c+8 <= H_){
    float4 a = *(const float4*)(emb + (size_t)r*H_ + c);
    float4 b = *(const float4*)(emb + (size_t)r*H_ + c + 4);
    float v[8] = {a.x,a.y,a.z,a.w,b.x,b.y,b.z,b.w};
    #pragma unroll
    for (int i=0;i<8;i++) h[i]=f2b(v[i]);
  } else {
    #pragma unroll
    for (int i=0;i<8;i++) h[i]=0;
  }
  *(us8*)(dst+base) = h;
}

__device__ __forceinline__ void xallcvt8_body(const int* __restrict__ targets,
    const float* __restrict__ emb, float* __restrict__ xf_all,
    ushort_t* __restrict__ xa_hi, ushort_t* __restrict__ xa_lo, int u8){
  long long base = (long long)u8*8;
  if (base >= (long long)(T_-1)*MP*KP) return;
  int t = (int)(base / ((long long)MP*KP)) + 1;
  int rem = (int)(base - (long long)(t-1)*MP*KP);
  int r = rem / KP, c = rem - r*KP;
  size_t off = (size_t)t*MP*KP + rem;
  us8 h, l;
  if (r < SB && c+8 <= H_){
    int s = r>>4, b = r&15;
    int tg = targets[(b*S_ + s)*T_ + (t-1)];
    float4 a = *(const float4*)(emb + (size_t)tg*H_ + c);
    float4 bb= *(const float4*)(emb + (size_t)tg*H_ + c + 4);
    float v[8] = {a.x,a.y,a.z,a.w,bb.x,bb.y,bb.z,bb.w};
    float* xfp = xf_all + (size_t)t*SB*H_ + (size_t)r*H_ + c;
    *(float4*)xfp = a; *(float4*)(xfp+4) = bb;
    #pragma unroll
    for (int i=0;i<8;i++){ h[i]=f2b(v[i]); l[i]=f2b(v[i]-b2f(h[i])); }
  } else {
    #pragma unroll
    for (int i=0;i<8;i++){ h[i]=0; l[i]=0; }
  }
  *(us8*)(xa_hi+off) = h; *(us8*)(xa_lo+off) = l;
}

__device__ __forceinline__ void transpose_body(const float* __restrict__ src,
    float* __restrict__ dst, int rel, int tid, float (*tile)[33]){
  int b  = rel / 91;           // 7*13 tiles per b
  int rem = rel - b*91;
  int l0 = (rem % 7)*32, k0 = (rem / 7)*32;
  int tx = tid & 31, ty = tid >> 5;   // 32 x 8
  const float* s = src + (size_t)b*L_*H_;
  float*       d = dst + (size_t)b*H_*L_;
  #pragma unroll
  for (int i=ty; i<32; i+=8){
    int l = l0+i, k = k0+tx;
    tile[i][tx] = (l<L_ && k<H_) ? s[(size_t)l*H_ + k] : 0.f;
  }
  __syncthreads();
  #pragma unroll
  for (int i=ty; i<32; i+=8){
    int k = k0+i, l = l0+tx;
    if (k<H_ && l<L_) d[(size_t)k*L_ + l] = tile[tx][i];
  }
  __syncthreads();
}

__device__ __forceinline__ void init2_body(const float* __restrict__ slot_att,
    const float* __restrict__ slot_emb,
    float* __restrict__ xf_all, ushort_t* __restrict__ xa_hi, ushort_t* __restrict__ xa_lo,
    ushort_t* __restrict__ hbfA, ushort_t* __restrict__ hbf2A,
    ushort_t* __restrict__ hbfB, ushort_t* __restrict__ hbf2B,
    float* __restrict__ hfA, int idx){
  if (idx >= MP*KP) return;
  int r = idx/KP, c = idx - r*KP;
  ushort_t xh = 0, xl = 0;
  if (r < SB && c < H_){
    int s = r >> 4;
    float xv = slot_emb[s*H_ + c];
    xf_all[(size_t)r*H_ + c] = xv;
    xh = f2b(xv); xl = f2b(xv - b2f(xh));
    hfA[(size_t)r*H_ + c] = slot_att[s*H_ + c];
  }
  xa_hi[idx] = xh; xa_lo[idx] = xl;
  hbfA[idx] = 0; hbf2A[idx] = 0;
  hbfB[idx] = 0; hbf2B[idx] = 0;
}

__global__ __launch_bounds__(256) void setup1_kernel(
    const float* __restrict__ sys_H, const float* __restrict__ user_H,
    float* __restrict__ seqT_s, float* __restrict__ seqT_u,
    const float* __restrict__ slot_att, const float* __restrict__ slot_emb,
    float* __restrict__ xf_all, ushort_t* __restrict__ xa_hi, ushort_t* __restrict__ xa_lo,
    ushort_t* __restrict__ hbfA, ushort_t* __restrict__ hbf2A,
    ushort_t* __restrict__ hbfB, ushort_t* __restrict__ hbf2B,
    float* __restrict__ hfA,
    const int* __restrict__ targets, const float* __restrict__ emb,
    const float* __restrict__ W_ih, ushort_t* __restrict__ Wih_hi, ushort_t* __restrict__ Wih_lo,
    const float* __restrict__ W_hh, ushort_t* __restrict__ Whh_hi, ushort_t* __restrict__ Whh_lo,
    ushort_t* __restrict__ embp){
  __shared__ float tile[32][33];
  int bid = blockIdx.x, tid = threadIdx.x;
  int u = bid;
  if (u < TT_TILES){ transpose_body(sys_H, seqT_s, u, tid, tile); return; }
  u -= TT_TILES;
  if (u < TT_TILES){ transpose_body(user_H, seqT_u, u, tid, tile); return; }
  u -= TT_TILES;
  if (u < INIT_BLKS){
    init2_body(slot_att, slot_emb, xf_all, xa_hi, xa_lo, hbfA, hbf2A, hbfB, hbf2B, hfA,
               u*256 + tid);
    return;
  }
  u -= INIT_BLKS;
  if (u < XA8_BLKS){ xallcvt8_body(targets, emb, xf_all, xa_hi, xa_lo, u*256 + tid); return; }
  u -= XA8_BLKS;
  if (u < PS8_BLKS){ padsplit8_body(W_ih, Wih_hi, Wih_lo, u*256 + tid); return; }
  u -= PS8_BLKS;
  if (u < PS8_BLKS){ padsplit8_body(W_hh, Whh_hi, Whh_lo, u*256 + tid); return; }
  u -= PS8_BLKS;
  embcvt8_body(emb, embp, (long long)u*256 + tid);
}

// ================= attention v3 (R7-verified unroll-4) =================
__device__ void attend3_body(
    int u,
    const float* __restrict__ seqS, const float* __restrict__ seqTS, const float* __restrict__ muskS,
    const float* __restrict__ seqU, const float* __restrict__ seqTU, const float* __restrict__ muskU,
    const float* __restrict__ cond,
    float* __restrict__ ctxS, float* __restrict__ probS,
    float* __restrict__ ctxU, float* __restrict__ probU,
    float (*cond_l)[H_], float (*S_l)[208], float* smax, float* ssum){
  int which = (u >= B_*ATT_NRB) ? 1 : 0;
  int v = which ? u - B_*ATT_NRB : u;
  int b = v / ATT_NRB, rb = v - b*ATT_NRB;
  const float* seq  = which ? seqU  : seqS;
  const float* seqT = which ? seqTU : seqTS;
  const float* musk = which ? muskU : muskS;
  float* ctx  = which ? ctxU  : ctxS;
  float* prob = which ? probU : probS;
  int tid = threadIdx.x;
  int s0 = rb*ATT_ROWS;
  for (int idx=tid; idx<ATT_ROWS*H_; idx+=256){
    int i = idx/H_, k = idx - i*H_;
    cond_l[i][k] = cond[(size_t)((s0+i)*16 + b)*H_ + k];
  }
  __syncthreads();
  if (tid < L_){
    const float* sp = seqT + (size_t)b*H_*L_ + tid;
    float acc[ATT_ROWS];
    #pragma unroll
    for (int i=0;i<ATT_ROWS;i++) acc[i]=0.f;
    for (int k=0;k<H_;k+=4){
      float v0 = sp[(size_t)(k  )*L_];
      float v1 = sp[(size_t)(k+1)*L_];
      float v2 = sp[(size_t)(k+2)*L_];
      float v3 = sp[(size_t)(k+3)*L_];
      #pragma unroll
      for (int i=0;i<ATT_ROWS;i++){
        float4 c = *(const float4*)&cond_l[i][k];
        acc[i] += c.x*v0; acc[i] += c.y*v1; acc[i] += c.z*v2; acc[i] += c.w*v3;
      }
    }
    float mk = musk[b*L_ + tid];
    #pragma unroll
    for (int i=0;i<ATT_ROWS;i++) S_l[i][tid] = acc[i] + mk;
  }
  __syncthreads();
  if (tid < ATT_ROWS*16){
    int i = tid >> 4, sub = tid & 15;
    float m = -3.0e38f;
    for (int l=sub; l<L_; l+=16) m = fmaxf(m, S_l[i][l]);
    #pragma unroll
    for (int d=8; d>=1; d>>=1) m = fmaxf(m, __shfl_xor(m, d));
    float sm = 0.f;
    for (int l=sub; l<L_; l+=16) sm += __expf(S_l[i][l] - m);
    #pragma unroll
    for (int d=8; d>=1; d>>=1) sm += __shfl_xor(sm, d);
    if (sub==0){ smax[i] = m; ssum[i] = sm; }
  }
  __syncthreads();
  for (int idx=tid; idx<ATT_ROWS*L_; idx+=256){
    int i = idx/L_, l = idx - i*L_;
    float p = __expf(S_l[i][l] - smax[i]) / ssum[i];
    S_l[i][l] = p;
    prob[(size_t)((s0+i)*16 + b)*L_ + l] = p;
  }
  __syncthreads();
  for (int k=tid; k<H_; k+=256){
    const float* sp2 = seq + (size_t)b*L_*H_ + k;
    float acc[ATT_ROWS];
    #pragma unroll
    for (int i=0;i<ATT_ROWS;i++) acc[i]=0.f;
    for (int l=0;l<L_;l+=4){
      float v0 = sp2[(size_t)(l  )*H_];
      float v1 = sp2[(size_t)(l+1)*H_];
      float v2 = sp2[(size_t)(l+2)*H_];
      float v3 = sp2[(size_t)(l+3)*H_];
      #pragma unroll
      for (int i=0;i<ATT_ROWS;i++){
        float4 pp = *(const float4*)&S_l[i][l];
        acc[i] += pp.x*v0; acc[i] += pp.y*v1; acc[i] += pp.z*v2; acc[i] += pp.w*v3;
      }
    }
    #pragma unroll
    for (int i=0;i<ATT_ROWS;i++)
      ctx[(size_t)((s0+i)*16 + b)*H_ + k] = acc[i];
  }
}

// ================= hi/lo GEMM tile =================
__device__ __forceinline__ void hl_gemm_tile(
    const ushort_t* __restrict__ A_hi, const ushort_t* __restrict__ A_lo,
    const ushort_t* __restrict__ B_hi, const ushort_t* __restrict__ B_lo,
    float* __restrict__ outg, int nb, int mb, int tid){
  int wave = tid>>6, lane = tid&63;
  int q = lane>>4, ln = lane&15;
  int m_base = mb*64 + wave*16;
  int n_base = nb*64;
  const ushort_t* Ah  = A_hi + (size_t)(m_base + ln)*KP;
  const ushort_t* Ah2 = A_lo + (size_t)(m_base + ln)*KP;
  f32x4 ah[4];
  #pragma unroll
  for (int nt=0;nt<4;nt++) ah[nt]=(f32x4){0,0,0,0};
  for (int kk=0; kk<KP; kk+=32){
    int ko = kk + q*8;
    frag8 ahv = *(const frag8*)(Ah  + ko);
    frag8 ah2 = *(const frag8*)(Ah2 + ko);
    #pragma unroll
    for (int nt=0;nt<4;nt++){
      size_t nrow = (size_t)(n_base + nt*16 + ln)*KP + ko;
      frag8 bhh = *(const frag8*)(B_hi + nrow);
      frag8 bhl = *(const frag8*)(B_lo + nrow);
      ah[nt] = __builtin_amdgcn_mfma_f32_16x16x32_bf16(ahv,bhh, ah[nt],0,0,0);
      ah[nt] = __builtin_amdgcn_mfma_f32_16x16x32_bf16(ahv,bhl, ah[nt],0,0,0);
      ah[nt] = __builtin_amdgcn_mfma_f32_16x16x32_bf16(ah2,bhh, ah[nt],0,0,0);
    }
  }
  int mrow = m_base + q*4;
  #pragma unroll
  for (int nt=0; nt<4; nt++){
    int n = n_base + nt*16 + ln;
    if (n >= 3*H_) continue;
    #pragma unroll
    for (int i=0;i<4;i++){
      int m = mrow + i;
      if (m < SB) outg[(size_t)m*(3*H_) + n] = ah[nt][i];
    }
  }
}

// ---------- pre: h0 attend (160) + gi_all GEMM (1520 tiles) ----------
__global__ __launch_bounds__(256) void pre_kernel(
    const float* __restrict__ seqS, const float* __restrict__ seqTS, const float* __restrict__ muskS,
    const float* __restrict__ seqU, const float* __restrict__ seqTU, const float* __restrict__ muskU,
    const float* __restrict__ cond,
    float* __restrict__ ctxS, float* __restrict__ probS,
    float* __restrict__ ctxU, float* __restrict__ probU,
    const ushort_t* __restrict__ xa_hi, const ushort_t* __restrict__ xa_lo,
    const ushort_t* __restrict__ Wih_hi, const ushort_t* __restrict__ Wih_lo,
    float* __restrict__ gi_all){
  __shared__ float cond_l[ATT_ROWS][H_];
  __shared__ float S_l[ATT_ROWS][208];
  __shared__ float smax[ATT_ROWS], ssum[ATT_ROWS];
  int u = blockIdx.x, tid = threadIdx.x;
  if (u < ATT3_BLKS){
    attend3_body(u, seqS, seqTS, muskS, seqU, seqTU, muskU, cond,
                 ctxS, probS, ctxU, probU, cond_l, S_l, smax, ssum);
    return;
  }
  u -= ATT3_BLKS;
  int t = u / GG_T, rem = u - t*GG_T;
  hl_gemm_tile(xa_hi + (size_t)t*MP*KP, xa_lo + (size_t)t*MP*KP,
               Wih_hi, Wih_lo, gi_all + (size_t)t*SB*(3*H_),
               rem % 19, rem / 19, tid);
}

// ---------- gg0v2: hh GEMM for t'=0 with on-the-fly A = bf16(cs+cu); also writes hf0 ----------
__global__ __launch_bounds__(256) void gg0v2_kernel(
    const float* __restrict__ cs, const float* __restrict__ cu,
    const ushort_t* __restrict__ Whh_hi, const ushort_t* __restrict__ Whh_lo,
    float* __restrict__ gh, float* __restrict__ hf0){
  int u = blockIdx.x, tid = threadIdx.x;
  int nb = u % 19, mb = u / 19;
  int wave = tid>>6, lane = tid&63;
  int q = lane>>4, ln = lane&15;
  int m_base = mb*64 + wave*16;
  int n_base = nb*64;
  int row = m_base + ln;
  f32x4 ah[4];
  #pragma unroll
  for (int nt=0;nt<4;nt++) ah[nt]=(f32x4){0,0,0,0};
  for (int kk=0; kk<KP; kk+=32){
    int ko = kk + q*8;
    frag8 ahv, ah2;
    if (row < SB && ko < H_){
      const float* c1 = cs + (size_t)row*H_ + ko;
      const float* c2 = cu + (size_t)row*H_ + ko;
      float4 a = *(const float4*)c1, b = *(const float4*)(c1+4);
      float4 e = *(const float4*)c2, f = *(const float4*)(c2+4);
      float v[8] = {a.x+e.x, a.y+e.y, a.z+e.z, a.w+e.w,
                    b.x+f.x, b.y+f.y, b.z+f.z, b.w+f.w};
      #pragma unroll
      for (int i=0;i<8;i++){
        ushort_t hb = f2b(v[i]);
        ahv[i] = (short)hb;
        ah2[i] = (short)f2b(v[i] - b2f(hb));
      }
      if (nb == 0){
        float* hp = hf0 + (size_t)row*H_ + ko;
        *(float4*)hp     = (float4){v[0],v[1],v[2],v[3]};
        *(float4*)(hp+4) = (float4){v[4],v[5],v[6],v[7]};
      }
    } else {
      #pragma unroll
      for (int i=0;i<8;i++){ ahv[i]=0; ah2[i]=0; }
    }
    #pragma unroll
    for (int nt=0;nt<4;nt++){
      size_t nrow = (size_t)(n_base + nt*16 + ln)*KP + ko;
      frag8 bhh = *(const frag8*)(Whh_hi + nrow);
      frag8 bhl = *(const frag8*)(Whh_lo + nrow);
      ah[nt] = __builtin_amdgcn_mfma_f32_16x16x32_bf16(ahv,bhh, ah[nt],0,0,0);
      ah[nt] = __builtin_amdgcn_mfma_f32_16x16x32_bf16(ahv,bhl, ah[nt],0,0,0);
      ah[nt] = __builtin_amdgcn_mfma_f32_16x16x32_bf16(ah2,bhh, ah[nt],0,0,0);
    }
  }
  int mrow = m_base + q*4;
  #pragma unroll
  for (int nt=0; nt<4; nt++){
    int n = n_base + nt*16 + ln;
    if (n >= 3*H_) continue;
    #pragma unroll
    for (int i=0;i<4;i++){
      int m = mrow + i;
      if (m < SB) gh[(size_t)m*(3*H_) + n] = ah[nt][i];
    }
  }
}

// ---------- GRU row, float4-vectorized (elementwise -> bit-identical) ----------
__device__ __forceinline__ void gru_row4(int r,
    const float* __restrict__ gia_t, const float* __restrict__ gh,
    const float* __restrict__ b_ih, const float* __restrict__ b_hh,
    const float* __restrict__ hold, float* __restrict__ hfw,
    ushort_t* __restrict__ hbfw, ushort_t* __restrict__ hbf2w, int tid){
  const float* gir = gia_t + (size_t)r*(3*H_);
  const float* ghr = gh    + (size_t)r*(3*H_);
  for (int j4=tid; j4<H_/4; j4+=256){
    int j = j4*4;
    float4 ir4 = *(const float4*)(gir + j);
    float4 iz4 = *(const float4*)(gir + H_ + j);
    float4 in4 = *(const float4*)(gir + 2*H_ + j);
    float4 hr4 = *(const float4*)(ghr + j);
    float4 hz4 = *(const float4*)(ghr + H_ + j);
    float4 hn4 = *(const float4*)(ghr + 2*H_ + j);
    float4 bir4 = *(const float4*)(b_ih + j);
    float4 biz4 = *(const float4*)(b_ih + H_ + j);
    float4 bin4 = *(const float4*)(b_ih + 2*H_ + j);
    float4 bhr4 = *(const float4*)(b_hh + j);
    float4 bhz4 = *(const float4*)(b_hh + H_ + j);
    float4 bhn4 = *(const float4*)(b_hh + 2*H_ + j);
    float4 ho4 = *(const float4*)(hold + (size_t)r*H_ + j);
    float hv[4]; us4 hb4, hl4;
    float ir[4]={ir4.x,ir4.y,ir4.z,ir4.w}, iz[4]={iz4.x,iz4.y,iz4.z,iz4.w},
          in_[4]={in4.x,in4.y,in4.z,in4.w}, hr[4]={hr4.x,hr4.y,hr4.z,hr4.w},
          hz[4]={hz4.x,hz4.y,hz4.z,hz4.w}, hn[4]={hn4.x,hn4.y,hn4.z,hn4.w},
          bir[4]={bir4.x,bir4.y,bir4.z,bir4.w}, biz[4]={biz4.x,biz4.y,biz4.z,biz4.w},
          bin[4]={bin4.x,bin4.y,bin4.z,bin4.w}, bhr[4]={bhr4.x,bhr4.y,bhr4.z,bhr4.w},
          bhz[4]={bhz4.x,bhz4.y,bhz4.z,bhz4.w}, bhn[4]={bhn4.x,bhn4.y,bhn4.z,bhn4.w},
          ho[4]={ho4.x,ho4.y,ho4.z,ho4.w};
    #pragma unroll
    for (int i=0;i<4;i++){
      float i_r = ir[i] + bir[i];
      float i_z = iz[i] + biz[i];
      float i_n = in_[i] + bin[i];
      float h_r = hr[i] + bhr[i];
      float h_z = hz[i] + bhz[i];
      float h_n = hn[i] + bhn[i];
      float rg = 1.f/(1.f+__expf(-(i_r+h_r)));
      float zg = 1.f/(1.f+__expf(-(i_z+h_z)));
      float ng = tanhf(i_n + rg*h_n);
      hv[i] = (1.f-zg)*ng + zg*ho[i];
      ushort_t hb = f2b(hv[i]);
      hb4[i] = hb;
      hl4[i] = f2b(hv[i] - b2f(hb));
    }
    *(float4*)(hfw + (size_t)r*H_ + j) = (float4){hv[0],hv[1],hv[2],hv[3]};
    *(us4*)(hbfw + r*KP + j)  = hb4;   // KP=416, j%4==0 -> 8B aligned
    *(us4*)(hbf2w + r*KP + j) = hl4;
  }
}

__global__ __launch_bounds__(256) void gru0_kernel(
    const float* __restrict__ gia_t, const float* __restrict__ gh,
    const float* __restrict__ b_ih, const float* __restrict__ b_hh,
    const float* __restrict__ hold, float* __restrict__ hfw,
    ushort_t* __restrict__ hbfw, ushort_t* __restrict__ hbf2w){
  gru_row4(blockIdx.x, gia_t, gh, b_ih, b_hh, hold, hfw, hbfw, hbf2w, threadIdx.x);
}

// ---------- vocab GEMM tile ----------
__device__ __forceinline__ void vocab_tile(
    const ushort_t* __restrict__ A, const ushort_t* __restrict__ Bm,
    float* __restrict__ outp, float* __restrict__ pmax, float* __restrict__ psum,
    int nb, int mb, int tid){
  int wave = tid>>6, lane = tid&63;
  int q = lane>>4, ln = lane&15;
  int m_base = mb*64 + wave*16;
  int n_base = nb*64;
  const ushort_t* Arow = A + (size_t)(m_base + ln)*KP;
  f32x4 acc[4];
  #pragma unroll
  for (int nt=0;nt<4;nt++) acc[nt]=(f32x4){0,0,0,0};
  for (int kk=0; kk<KP; kk+=32){
    int ko = kk + q*8;
    frag8 a  = *(const frag8*)(Arow + ko);
    #pragma unroll
    for (int nt=0;nt<4;nt++){
      frag8 b = *(const frag8*)(Bm + (size_t)(n_base + nt*16 + ln)*KP + ko);
      acc[nt] = __builtin_amdgcn_mfma_f32_16x16x32_bf16(a,b,acc[nt],0,0,0);
    }
  }
  int mrow = m_base + q*4;
  #pragma unroll
  for (int nt=0; nt<4; nt++){
    int n = n_base + nt*16 + ln;
    if (n >= V_) continue;
    #pragma unroll
    for (int i=0;i<4;i++){
      int m = mrow + i;
      if (m < SB) outp[(size_t)m*TV + n] = acc[nt][i];
    }
  }
  #pragma unroll
  for (int i=0;i<4;i++){
    float mx = -3.0e38f;
    #pragma unroll
    for (int nt=0;nt<4;nt++){
      int n = n_base + nt*16 + ln;
      if (n < V_) mx = fmaxf(mx, acc[nt][i]);
    }
    #pragma unroll
    for (int d=8; d>=1; d>>=1) mx = fmaxf(mx, __shfl_xor(mx, d));
    float sm = 0.f;
    #pragma unroll
    for (int nt=0;nt<4;nt++){
      int n = n_base + nt*16 + ln;
      if (n < V_) sm += __expf(acc[nt][i] - mx);
    }
    #pragma unroll
    for (int d=8; d>=1; d>>=1) sm += __shfl_xor(sm, d);
    int m = mrow + i;
    if (ln == 0 && m < SB){
      pmax[(size_t)m*NT_VOC + nb] = mx;
      psum[(size_t)m*NT_VOC + nb] = sm;
    }
  }
}

// ---------- finalize: one (row, part) — float4 scale pass + range-filtered scatter ----------
__device__ __forceinline__ void finalize_row_part(int r, int part,
    float* __restrict__ out_prev,
    const float* __restrict__ Marr, const float* __restrict__ scarr,
    const float* __restrict__ acarr, const float* __restrict__ bcarr,
    const float* __restrict__ ps, const float* __restrict__ pu,
    const int* __restrict__ story_sys, const int* __restrict__ story_user, int tid){
  int v0 = part*FZ_SEG, v1 = v0 + FZ_SEG;
  float M = Marr[r], sc = scarr[r];
  float* row = out_prev + (size_t)r*TV;
  float4* row4 = (float4*)(row + v0);
  for (int i4=tid; i4<FZ_SEG/4; i4+=256){
    float4 x = row4[i4];
    x.x = __expf(x.x - M)*sc;
    x.y = __expf(x.y - M)*sc;
    x.z = __expf(x.z - M)*sc;
    x.w = __expf(x.w - M)*sc;
    row4[i4] = x;
  }
  __syncthreads();    // drain scale-writes before atomics (same block owns this v-range)
  int b = r & 15;
  float a_ = acarr[r], b_ = bcarr[r];
  for (int i=tid; i<2*L_; i+=256){
    int which = (i >= L_) ? 1 : 0;
    int l = which ? i - L_ : i;
    int v = which ? story_user[b*L_+l] : story_sys[b*L_+l];
    if (v < v0 || v >= v1) continue;
    float val = which ? b_*pu[(size_t)r*L_+l] : a_*ps[(size_t)r*L_+l];
    atomicAdd(row + v, val);
  }
}

// ================= megaC: finalize(t-1) first (long poles), then attend, gg, vocab =================
__global__ __launch_bounds__(256) void megaC_kernel(
    const float* __restrict__ seqS, const float* __restrict__ seqTS, const float* __restrict__ muskS,
    const float* __restrict__ seqU, const float* __restrict__ seqTU, const float* __restrict__ muskU,
    const float* __restrict__ hf_r,
    const ushort_t* __restrict__ hbf_r, const ushort_t* __restrict__ hbf2_r,
    float* __restrict__ ctxS, float* __restrict__ probS,
    float* __restrict__ ctxU, float* __restrict__ probU,
    const ushort_t* __restrict__ embp, float* __restrict__ outp,
    float* __restrict__ pmax, float* __restrict__ psum,
    const ushort_t* __restrict__ Whh_hi, const ushort_t* __restrict__ Whh_lo,
    float* __restrict__ gh, int ngg,
    float* __restrict__ out_prev,
    const float* __restrict__ Marr, const float* __restrict__ scarr,
    const float* __restrict__ acarr, const float* __restrict__ bcarr,
    const float* __restrict__ ps_prev, const float* __restrict__ pu_prev,
    const int* __restrict__ story_sys, const int* __restrict__ story_user,
    int base_off){
  __shared__ float cond_l[ATT_ROWS][H_];
  __shared__ float S_l[ATT_ROWS][208];
  __shared__ float smax[ATT_ROWS], ssum[ATT_ROWS];
  int u = blockIdx.x + base_off, tid = threadIdx.x;
  if (u < FZ_BLKS){
    finalize_row_part(u>>1, u&1, out_prev, Marr, scarr, acarr, bcarr,
                      ps_prev, pu_prev, story_sys, story_user, tid);
    return;
  }
  u -= FZ_BLKS;
  if (u < ATT3_BLKS){
    attend3_body(u, seqS, seqTS, muskS, seqU, seqTU, muskU, hf_r,
                 ctxS, probS, ctxU, probU, cond_l, S_l, smax, ssum);
    return;
  }
  u -= ATT3_BLKS;
  if (u < GG_PAD){
    if (u < GG_T && ngg)
      hl_gemm_tile(hbf_r, hbf2_r, Whh_hi, Whh_lo, gh, u % 19, u / 19, tid);
    return;
  }
  u -= GG_PAD;
  // vocab: XCD-chunked swizzle (role offset 1280 and base_off 0/960 are %8==0)
  int x = u & 7, j = u >> 3;
  int nb = x*40 + (j>>3), mb = j & 7;
  if (nb < NT_VOC)
    vocab_tile(hbf_r, embp, outp, pmax, psum, nb, mb, tid);
}

// ================= finalstats: gru(t+1) + per-row scalars + softmax stats (float4) =================
__device__ __forceinline__ float block_reduce(float v, float* red, int tid){
  red[tid]=v; __syncthreads();
  for (int s=128;s>0;s>>=1){ if(tid<s) red[tid]+=red[tid+s]; __syncthreads(); }
  float r = red[0]; __syncthreads();
  return r;
}

__global__ __launch_bounds__(256) void finalstats_kernel(
    const float* __restrict__ hf_r, const float* __restrict__ cs, const float* __restrict__ cu,
    const float* __restrict__ xf_t,
    const float* __restrict__ Wr_w, const float* __restrict__ Wr_b,
    const float* __restrict__ Wc_w, const float* __restrict__ Wc_b,
    const float* __restrict__ Wg_w, const float* __restrict__ Wg_b,
    const float* __restrict__ pmax, const float* __restrict__ psum,
    float* __restrict__ Marr, float* __restrict__ scarr,
    float* __restrict__ acarr, float* __restrict__ bcarr,
    float* __restrict__ gate_out, int do_gate,
    const float* __restrict__ gia_t1, const float* __restrict__ gh,
    const float* __restrict__ b_ih, const float* __restrict__ b_hh,
    float* __restrict__ hf_w, ushort_t* __restrict__ hbf_w, ushort_t* __restrict__ hbf2_w,
    int do_gru){
  __shared__ float red[256];
  int r = blockIdx.x, tid = threadIdx.x;
  if (do_gru)
    gru_row4(r, gia_t1, gh, b_ih, b_hh, hf_r, hf_w, hbf_w, hbf2_w, tid);
  const float* h   = hf_r + (size_t)r*H_;
  const float* csr = cs + (size_t)r*H_;
  const float* cur = cu + (size_t)r*H_;
  const float* xr  = xf_t + (size_t)r*H_;
  // float4 dot products (H_/4 = 100 float4s per segment; segments never straddle a float4)
  float sr=0, ss=0, su=0, g0=0, g1=0, g2=0;
  for (int k4=tid; k4<4*(H_/4); k4+=256){     // 400 float4s over [h|cs|cu|x]
    int seg = k4/(H_/4), o = (k4 - seg*(H_/4))*4;
    const float* src = (seg==0)? h : (seg==1)? csr : (seg==2)? cur : xr;
    float4 v = *(const float4*)(src + o);
    float4 w = *(const float4*)(Wr_w + k4*4);
    sr += w.x*v.x; sr += w.y*v.y; sr += w.z*v.z; sr += w.w*v.w;
  }
  for (int k4=tid; k4<3*(H_/4); k4+=256){     // 300 float4s
    int seg = k4/(H_/4), o = (k4 - seg*(H_/4))*4;
    const float* srcs = (seg==0)? h : (seg==1)? csr : xr;
    const float* srcu = (seg==0)? h : (seg==1)? cur : xr;
    float4 vs = *(const float4*)(srcs + o);
    float4 vu = *(const float4*)(srcu + o);
    float4 w = *(const float4*)(Wc_w + k4*4);
    ss += w.x*vs.x; ss += w.y*vs.y; ss += w.z*vs.z; ss += w.w*vs.w;
    su += w.x*vu.x; su += w.y*vu.y; su += w.z*vu.z; su += w.w*vu.w;
  }
  if (do_gate){
    for (int k4=tid; k4<2*(H_/4); k4+=256){   // 200 float4s over [cs|cu]
      int seg = k4/(H_/4), o = (k4 - seg*(H_/4))*4;
      const float* src = (seg==0)? csr : cur;
      float4 m = *(const float4*)(src + o);
      float4 w0 = *(const float4*)(Wg_w + k4*4);
      float4 w1 = *(const float4*)(Wg_w + 2*H_ + k4*4);
      float4 w2 = *(const float4*)(Wg_w + 4*H_ + k4*4);
      g0 += w0.x*m.x; g0 += w0.y*m.y; g0 += w0.z*m.z; g0 += w0.w*m.w;
      g1 += w1.x*m.x; g1 += w1.y*m.y; g1 += w1.z*m.z; g1 += w1.w*m.w;
      g2 += w2.x*m.x; g2 += w2.y*m.y; g2 += w2.z*m.z; g2 += w2.w*m.w;
    }
  }
  float SR = block_reduce(sr, red, tid);
  float SS = block_reduce(ss, red, tid);
  float SU = block_reduce(su, red, tid);
  if (do_gate){
    float G0=block_reduce(g0,red,tid);
    float G1=block_reduce(g1,red,tid);
    float G2=block_reduce(g2,red,tid);
    if (tid==0){
      gate_out[r*G_+0] = G0 + Wg_b[0];
      gate_out[r*G_+1] = G1 + Wg_b[1];
      gate_out[r*G_+2] = G2 + Wg_b[2];
    }
  }
  // softmax stats from online partials
  const float* pmr = pmax + (size_t)r*NT_VOC;
  const float* psr = psum + (size_t)r*NT_VOC;
  float lm = -3.0e38f;
  for (int nb=tid; nb<NT_VOC; nb+=256) lm = fmaxf(lm, pmr[nb]);
  red[tid]=lm; __syncthreads();
  for (int s=128;s>0;s>>=1){ if(tid<s) red[tid]=fmaxf(red[tid],red[tid+s]); __syncthreads(); }
  float M = red[0]; __syncthreads();
  float ls = 0.f;
  for (int nb=tid; nb<NT_VOC; nb+=256) ls += psr[nb]*__expf(pmr[nb]-M);
  float S = block_reduce(ls, red, tid);
  if (tid==0){
    float swv = 1.f/(1.f+__expf(-(SR + Wr_b[0])));
    float lcs = SS + Wc_b[0];
    float lcu = SU + Wc_b[0];
    float mx = fmaxf(lcs,lcu);
    float es = __expf(lcs-mx), eu = __expf(lcu-mx);
    float al = es/(es+eu);
    Marr[r]  = M;
    scarr[r] = swv / S;
    acarr[r] = (1.f-swv)*al;
    bcarr[r] = (1.f-swv)*(1.f-al);
  }
}

// ---------- tail finalize (t = T-1), 2-way split ----------
__global__ __launch_bounds__(256) void finalize_kernel(
    float* __restrict__ out_prev,
    const float* __restrict__ Marr, const float* __restrict__ scarr,
    const float* __restrict__ acarr, const float* __restrict__ bcarr,
    const float* __restrict__ ps, const float* __restrict__ pu,
    const int* __restrict__ story_sys, const int* __restrict__ story_user){
  int u = blockIdx.x;
  finalize_row_part(u>>1, u&1, out_prev, Marr, scarr, acarr, bcarr,
                    ps, pu, story_sys, story_user, threadIdx.x);
}

// ================= legacy basic-path kernels (small workspace fallback) =================

__global__ void padsplit_kernel(const float* __restrict__ src,
                                ushort_t* __restrict__ hi, ushort_t* __restrict__ lo){
  int idx = blockIdx.x*256 + threadIdx.x;
  if (idx >= NP_G*KP) return;
  int r = idx / KP, c = idx - r*KP;
  ushort_t h = 0, l = 0;
  if (r < 3*H_ && c < H_){
    float v = src[r*H_ + c];
    h = f2b(v);
    l = f2b(v - b2f(h));
  }
  hi[idx] = h; lo[idx] = l;
}

__global__ void initL_kernel(const float* __restrict__ slot_att, const float* __restrict__ slot_emb,
                            float* __restrict__ xf, ushort_t* __restrict__ xbf, ushort_t* __restrict__ xbf2,
                            ushort_t* __restrict__ hbf, ushort_t* __restrict__ hbf2,
                            float* __restrict__ hf){
  int idx = blockIdx.x*256 + threadIdx.x;
  if (idx >= MP*KP) return;
  int r = idx/KP, c = idx - r*KP;
  ushort_t xh = 0, xl = 0;
  if (r < SB && c < H_){
    int s = r >> 4;
    float xv = slot_emb[s*H_ + c];
    xf[r*H_ + c] = xv;
    xh = f2b(xv); xl = f2b(xv - b2f(xh));
    hf[r*H_ + c] = slot_att[s*H_ + c];
  }
  xbf[idx] = xh; xbf2[idx] = xl;
  hbf[idx] = 0;  hbf2[idx] = 0;
}

__global__ void addh_kernel(const float* __restrict__ cs, const float* __restrict__ cu,
                            float* __restrict__ hf, ushort_t* __restrict__ hbf, ushort_t* __restrict__ hbf2){
  int idx = blockIdx.x*256 + threadIdx.x;
  if (idx >= SB*H_) return;
  int r = idx/H_, c = idx - r*H_;
  float v = cs[idx] + cu[idx];
  hf[idx] = v;
  ushort_t hb = f2b(v);
  hbf [r*KP + c] = hb;
  hbf2[r*KP + c] = f2b(v - b2f(hb));
}

__global__ __launch_bounds__(256) void attendL_kernel(
    const float* __restrict__ seq, const float* __restrict__ musk,
    const float* __restrict__ cond, float* __restrict__ ctx, float* __restrict__ prob){
  __shared__ float hrow[H_];
  __shared__ float pl[L_];
  __shared__ float red[256];
  int r = blockIdx.x; int tid = threadIdx.x;
  int b = r & 15;
  for (int k=tid; k<H_; k+=256) hrow[k] = cond[(size_t)r*H_ + k];
  __syncthreads();
  float score = -3.0e38f;
  if (tid < L_){
    const float4* sp = (const float4*)(seq + ((size_t)b*L_ + tid)*H_);
    float acc = 0.f;
    for (int k=0; k<H_; k+=4){
      float4 v = sp[k>>2];
      acc += hrow[k]*v.x + hrow[k+1]*v.y + hrow[k+2]*v.z + hrow[k+3]*v.w;
    }
    score = acc + musk[b*L_ + tid];
  }
  red[tid] = score; __syncthreads();
  for (int s=128;s>0;s>>=1){ if(tid<s) red[tid]=fmaxf(red[tid],red[tid+s]); __syncthreads(); }
  float mv = red[0]; __syncthreads();
  float e = (tid<L_) ? __expf(score-mv) : 0.f;
  red[tid] = e; __syncthreads();
  for (int s=128;s>0;s>>=1){ if(tid<s) red[tid]+=red[tid+s]; __syncthreads(); }
  float sv = red[0]; __syncthreads();
  if (tid<L_){ float p = e/sv; pl[tid]=p; prob[(size_t)r*L_+tid]=p; }
  __syncthreads();
  for (int k=tid; k<H_; k+=256){
    float a = 0.f;
    const float* sp = seq + (size_t)b*L_*H_ + k;
    for (int l=0;l<L_;l++) a += pl[l]*sp[(size_t)l*H_];
    ctx[(size_t)r*H_ + k] = a;
  }
}

__global__ __launch_bounds__(256) void grugemmL_kernel(
    const ushort_t* __restrict__ xbf, const ushort_t* __restrict__ xbf2,
    const ushort_t* __restrict__ hbf, const ushort_t* __restrict__ hbf2,
    const ushort_t* __restrict__ Wih_hi, const ushort_t* __restrict__ Wih_lo,
    const ushort_t* __restrict__ Whh_hi, const ushort_t* __restrict__ Whh_lo,
    float* __restrict__ gi, float* __restrict__ gh){
  int tid = threadIdx.x;
  int wave = tid>>6, lane = tid&63;
  int q = lane>>4, ln = lane&15;
  int m_base = blockIdx.y*64 + wave*16;
  int n_base = blockIdx.x*64;
  const ushort_t* Ax  = xbf  + (size_t)(m_base + ln)*KP;
  const ushort_t* Ax2 = xbf2 + (size_t)(m_base + ln)*KP;
  const ushort_t* Ah  = hbf  + (size_t)(m_base + ln)*KP;
  const ushort_t* Ah2 = hbf2 + (size_t)(m_base + ln)*KP;
  f32x4 ai[4], ah[4];
  #pragma unroll
  for (int nt=0;nt<4;nt++){ ai[nt]=(f32x4){0,0,0,0}; ah[nt]=(f32x4){0,0,0,0}; }
  for (int kk=0; kk<KP; kk+=32){
    int ko = kk + q*8;
    frag8 ax  = *(const frag8*)(Ax  + ko);
    frag8 ax2 = *(const frag8*)(Ax2 + ko);
    frag8 ahv = *(const frag8*)(Ah  + ko);
    frag8 ah2 = *(const frag8*)(Ah2 + ko);
    #pragma unroll
    for (int nt=0;nt<4;nt++){
      size_t nrow = (size_t)(n_base + nt*16 + ln)*KP + ko;
      frag8 bih = *(const frag8*)(Wih_hi + nrow);
      frag8 bil = *(const frag8*)(Wih_lo + nrow);
      frag8 bhh = *(const frag8*)(Whh_hi + nrow);
      frag8 bhl = *(const frag8*)(Whh_lo + nrow);
      ai[nt] = __builtin_amdgcn_mfma_f32_16x16x32_bf16(ax, bih, ai[nt],0,0,0);
      ai[nt] = __builtin_amdgcn_mfma_f32_16x16x32_bf16(ax, bil, ai[nt],0,0,0);
      ai[nt] = __builtin_amdgcn_mfma_f32_16x16x32_bf16(ax2,bih, ai[nt],0,0,0);
      ah[nt] = __builtin_amdgcn_mfma_f32_16x16x32_bf16(ahv,bhh, ah[nt],0,0,0);
      ah[nt] = __builtin_amdgcn_mfma_f32_16x16x32_bf16(ahv,bhl, ah[nt],0,0,0);
      ah[nt] = __builtin_amdgcn_mfma_f32_16x16x32_bf16(ah2,bhh, ah[nt],0,0,0);
    }
  }
  int mrow = m_base + q*4;
  #pragma unroll
  for (int nt=0; nt<4; nt++){
    int n = n_base + nt*16 + ln;
    if (n >= 3*H_) continue;
    #pragma unroll
    for (int i=0;i<4;i++){
      int m = mrow + i;
      if (m < SB){
        gi[(size_t)m*(3*H_) + n] = ai[nt][i];
        gh[(size_t)m*(3*H_) + n] = ah[nt][i];
      }
    }
  }
}

__global__ void gruL_kernel(const float* __restrict__ gi, const float* __restrict__ gh,
    const float* __restrict__ b_ih, const float* __restrict__ b_hh,
    float* __restrict__ hf, ushort_t* __restrict__ hbf, ushort_t* __restrict__ hbf2){
  int idx = blockIdx.x*256 + threadIdx.x;
  if (idx >= SB*H_) return;
  int r = idx/H_, j = idx - r*H_;
  const float* gir = gi + (size_t)r*(3*H_);
  const float* ghr = gh + (size_t)r*(3*H_);
  float i_r = gir[j]      + b_ih[j];
  float i_z = gir[H_+j]   + b_ih[H_+j];
  float i_n = gir[2*H_+j] + b_ih[2*H_+j];
  float h_r = ghr[j]      + b_hh[j];
  float h_z = ghr[H_+j]   + b_hh[H_+j];
  float h_n = ghr[2*H_+j] + b_hh[2*H_+j];
  float rg = 1.f/(1.f+__expf(-(i_r+h_r)));
  float zg = 1.f/(1.f+__expf(-(i_z+h_z)));
  float ng = tanhf(i_n + rg*h_n);
  float hv = (1.f-zg)*ng + zg*hf[idx];
  hf[idx] = hv;
  ushort_t hb = f2b(hv);
  hbf [r*KP + j] = hb;
  hbf2[r*KP + j] = f2b(hv - b2f(hb));
}

__global__ __launch_bounds__(256) void smallL_kernel(
    const float* __restrict__ hf, const float* __restrict__ cs, const float* __restrict__ cu,
    const float* __restrict__ xf,
    const float* __restrict__ Wr_w, const float* __restrict__ Wr_b,
    const float* __restrict__ Wc_w, const float* __restrict__ Wc_b,
    const float* __restrict__ Wg_w, const float* __restrict__ Wg_b,
    float* __restrict__ sw_arr, float* __restrict__ ac_arr, float* __restrict__ bc_arr,
    float* __restrict__ gate_out, int do_gate){
  __shared__ float red[256];
  int r = blockIdx.x, tid = threadIdx.x;
  const float* h   = hf + (size_t)r*H_;
  const float* csr = cs + (size_t)r*H_;
  const float* cur = cu + (size_t)r*H_;
  const float* xr  = xf + (size_t)r*H_;
  float sr=0, ss=0, su=0, g0=0, g1=0, g2=0;
  for (int k=tid;k<4*H_;k+=256){
    float v = (k<H_)? h[k] : (k<2*H_)? csr[k-H_] : (k<3*H_)? cur[k-2*H_] : xr[k-3*H_];
    sr += Wr_w[k]*v;
  }
  for (int k=tid;k<3*H_;k+=256){
    float w = Wc_w[k];
    float vs = (k<H_)? h[k] : (k<2*H_)? csr[k-H_] : xr[k-2*H_];
    float vu = (k<H_)? h[k] : (k<2*H_)? cur[k-H_] : xr[k-2*H_];
    ss += w*vs; su += w*vu;
  }
  if (do_gate){
    for (int k=tid;k<2*H_;k+=256){
      float m = (k<H_)? csr[k] : cur[k-H_];
      g0 += Wg_w[k]*m;
      g1 += Wg_w[2*H_+k]*m;
      g2 += Wg_w[4*H_+k]*m;
    }
  }
  float SR = block_reduce(sr, red, tid);
  float SS = block_reduce(ss, red, tid);
  float SU = block_reduce(su, red, tid);
  float G0=0,G1=0,G2=0;
  if (do_gate){ G0=block_reduce(g0,red,tid); G1=block_reduce(g1,red,tid); G2=block_reduce(g2,red,tid); }
  if (tid==0){
    float swv = 1.f/(1.f+__expf(-(SR + Wr_b[0])));
    float lcs = SS + Wc_b[0];
    float lcu = SU + Wc_b[0];
    float mx = fmaxf(lcs,lcu);
    float es = __expf(lcs-mx), eu = __expf(lcu-mx);
    float al = es/(es+eu);
    sw_arr[r]=swv; ac_arr[r]=(1.f-swv)*al; bc_arr[r]=(1.f-swv)*(1.f-al);
    if (do_gate){
      gate_out[r*G_+0] = G0 + Wg_b[0];
      gate_out[r*G_+1] = G1 + Wg_b[1];
      gate_out[r*G_+2] = G2 + Wg_b[2];
    }
  }
}

__device__ __forceinline__ frag8 load_cvt8(const float* p){
  float4 a = *(const float4*)p;
  float4 b = *(const float4*)(p+4);
  frag8 r;
  r[0]=(short)f2b(a.x); r[1]=(short)f2b(a.y); r[2]=(short)f2b(a.z); r[3]=(short)f2b(a.w);
  r[4]=(short)f2b(b.x); r[5]=(short)f2b(b.y); r[6]=(short)f2b(b.z); r[7]=(short)f2b(b.w);
  return r;
}

__global__ __launch_bounds__(256) void vocabL_kernel(
    const ushort_t* __restrict__ A, const float* __restrict__ emb,
    float* __restrict__ outp){
  int tid = threadIdx.x;
  int wave = tid>>6, lane = tid&63;
  int q = lane>>4, ln = lane&15;
  int m_base = blockIdx.y*64 + wave*16;
  int n_base = blockIdx.x*64;
  const ushort_t* Arow = A + (size_t)(m_base + ln)*KP;
  int n0 = min(n_base +  0 + ln, V_-1);
  int n1 = min(n_base + 16 + ln, V_-1);
  int n2 = min(n_base + 32 + ln, V_-1);
  int n3 = min(n_base + 48 + ln, V_-1);
  const float* B0 = emb + (size_t)n0*H_;
  const float* B1 = emb + (size_t)n1*H_;
  const float* B2 = emb + (size_t)n2*H_;
  const float* B3 = emb + (size_t)n3*H_;
  f32x4 acc0={0,0,0,0}, acc1={0,0,0,0}, acc2={0,0,0,0}, acc3={0,0,0,0};
  for (int kk=0; kk<KP; kk+=32){
    int ko = kk + q*8;
    int safe = (ko < H_) ? ko : 0;
    frag8 a  = *(const frag8*)(Arow + ko);
    frag8 b0 = load_cvt8(B0 + safe);
    frag8 b1 = load_cvt8(B1 + safe);
    frag8 b2 = load_cvt8(B2 + safe);
    frag8 b3 = load_cvt8(B3 + safe);
    acc0 = __builtin_amdgcn_mfma_f32_16x16x32_bf16(a,b0,acc0,0,0,0);
    acc1 = __builtin_amdgcn_mfma_f32_16x16x32_bf16(a,b1,acc1,0,0,0);
    acc2 = __builtin_amdgcn_mfma_f32_16x16x32_bf16(a,b2,acc2,0,0,0);
    acc3 = __builtin_amdgcn_mfma_f32_16x16x32_bf16(a,b3,acc3,0,0,0);
  }
  int mrow = m_base + q*4;
  #pragma unroll
  for (int nt=0; nt<4; nt++){
    f32x4 acc = (nt==0)?acc0:(nt==1)?acc1:(nt==2)?acc2:acc3;
    int n = n_base + nt*16 + ln;
    if (n >= V_) continue;
    #pragma unroll
    for (int i=0;i<4;i++){
      int m = mrow + i;
      if (m < SB) outp[(size_t)m*TV + n] = acc[i];
    }
  }
}

__global__ __launch_bounds__(256) void softmax_scatterL_kernel(
    const float* __restrict__ sw_arr, const float* __restrict__ ac, const float* __restrict__ bc,
    const float* __restrict__ p_s, const float* __restrict__ p_u,
    const int* __restrict__ story_sys, const int* __restrict__ story_user,
    float* __restrict__ outp){
  __shared__ float red[256];
  int r = blockIdx.x, tid = threadIdx.x;
  float* row = outp + (size_t)r*TV;
  float m = -3.0e38f;
  for (int v=tid; v<V_; v+=256) m = fmaxf(m, row[v]);
  red[tid]=m; __syncthreads();
  for (int s=128;s>0;s>>=1){ if(tid<s) red[tid]=fmaxf(red[tid],red[tid+s]); __syncthreads(); }
  float M = red[0]; __syncthreads();
  float sum = 0.f;
  for (int v=tid; v<V_; v+=256) sum += __expf(row[v] - M);
  red[tid]=sum; __syncthreads();
  for (int s=128;s>0;s>>=1){ if(tid<s) red[tid]+=red[tid+s]; __syncthreads(); }
  float S = red[0]; __syncthreads();
  float scale = sw_arr[r]/S;
  for (int v=tid; v<V_; v+=256) row[v] = __expf(row[v] - M)*scale;
  __syncthreads();
  int b = r & 15;
  float a_ = ac[r], b_ = bc[r];
  for (int i=tid; i<2*L_; i+=256){
    int which = (i >= L_) ? 1 : 0;
    int l = which ? i - L_ : i;
    int v = which ? story_user[b*L_+l] : story_sys[b*L_+l];
    float val = which ? b_*p_u[(size_t)r*L_+l] : a_*p_s[(size_t)r*L_+l];
    atomicAdd(row + v, val);
  }
}

__global__ void nextxL_kernel(const int* __restrict__ targets, const float* __restrict__ emb,
    float* __restrict__ xf, ushort_t* __restrict__ xbf, ushort_t* __restrict__ xbf2, int t){
  int idx = blockIdx.x*256 + threadIdx.x;
  if (idx >= SB*H_) return;
  int r = idx/H_, k = idx - r*H_;
  int s = r>>4, b = r&15;
  int tg = targets[(b*S_ + s)*T_ + t];
  float v = emb[(size_t)tg*H_ + k];
  xf[(size_t)r*H_ + k] = v;
  ushort_t hb = f2b(v);
  xbf [r*KP + k] = hb;
  xbf2[r*KP + k] = f2b(v - b2f(hb));
}

// ================= host =================
extern "C" void kernel_launch(void* const* d_in, const int* in_sizes, int n_in,
                              void* d_out, int out_size, void* d_ws, size_t ws_size,
                              hipStream_t stream){
  const float* sys_H    = (const float*)d_in[0];
  const float* user_H   = (const float*)d_in[1];
  const float* sys_musk = (const float*)d_in[2];
  const float* user_musk= (const float*)d_in[3];
  const float* emb      = (const float*)d_in[4];
  const float* W_ih     = (const float*)d_in[5];
  const float* W_hh     = (const float*)d_in[6];
  const float* b_ih     = (const float*)d_in[7];
  const float* b_hh     = (const float*)d_in[8];
  const float* Wg_w     = (const float*)d_in[9];
  const float* Wg_b     = (const float*)d_in[10];
  const float* Wr_w     = (const float*)d_in[11];
  const float* Wr_b     = (const float*)d_in[12];
  const float* Wc_w     = (const float*)d_in[13];
  const float* Wc_b     = (const float*)d_in[14];
  const float* slot_att = (const float*)d_in[15];
  const float* slot_emb = (const float*)d_in[16];
  const int* story_sys  = (const int*)d_in[17];
  const int* story_user = (const int*)d_in[18];
  const int* targets    = (const int*)d_in[19];
  float* out = (float*)d_out;                      // OUTPUT IS FLOAT32
  float* gate_out = out + (size_t)SB*TV;

  char* base = (char*)d_ws;
  size_t off = 0;
  auto take = [&](size_t bytes)->char*{
    char* p = base + off; off += (bytes + 255) & ~(size_t)255; return p;
  };
  // --- shared (legacy + primary) ---
  ushort_t* Wih_hi = (ushort_t*)take((size_t)NP_G*KP*2);
  ushort_t* Wih_lo = (ushort_t*)take((size_t)NP_G*KP*2);
  ushort_t* Whh_hi = (ushort_t*)take((size_t)NP_G*KP*2);
  ushort_t* Whh_lo = (ushort_t*)take((size_t)NP_G*KP*2);
  ushort_t* hbf0  = (ushort_t*)take((size_t)MP*KP*2);
  ushort_t* hbf20 = (ushort_t*)take((size_t)MP*KP*2);
  float* hf0   = (float*)take((size_t)SB*H_*4);
  float* ctx_s = (float*)take((size_t)SB*H_*4);
  float* ctx_u = (float*)take((size_t)SB*H_*4);
  float* p_s   = (float*)take((size_t)SB*L_*4);
  float* p_u   = (float*)take((size_t)SB*L_*4);
  float* gh    = (float*)take((size_t)SB*3*H_*4);
  // --- legacy-only ---
  float* gi_l  = (float*)take((size_t)SB*3*H_*4);
  float* xf_l  = (float*)take((size_t)SB*H_*4);
  ushort_t* xbf_l  = (ushort_t*)take((size_t)MP*KP*2);
  ushort_t* xbf2_l = (ushort_t*)take((size_t)MP*KP*2);
  float* sw_arr = (float*)take(SB*4);
  float* ac_arr = (float*)take(SB*4);
  float* bc_arr = (float*)take(SB*4);
  size_t off_legacy = off;
  // --- primary-only ---
  ushort_t* hbf1  = (ushort_t*)take((size_t)MP*KP*2);
  ushort_t* hbf21 = (ushort_t*)take((size_t)MP*KP*2);
  float* hf1   = (float*)take((size_t)SB*H_*4);
  float* pmaxw = (float*)take((size_t)MP*NT_VOC*4);
  float* psumw = (float*)take((size_t)MP*NT_VOC*4);
  float* gi_all= (float*)take((size_t)T_*SB*3*H_*4);
  float* xf_all= (float*)take((size_t)T_*SB*H_*4);
  ushort_t* xa_hi = (ushort_t*)take((size_t)T_*MP*KP*2);
  ushort_t* xa_lo = (ushort_t*)take((size_t)T_*MP*KP*2);
  ushort_t* embp  = (ushort_t*)take((size_t)NP_EMB*KP*2);
  float* seqT_s = (float*)take((size_t)B_*H_*L_*4);
  float* seqT_u = (float*)take((size_t)B_*H_*L_*4);
  // double-buffered prob + per-row stat arrays (by t parity)
  float* psb[2] = { (float*)take((size_t)SB*L_*4), (float*)take((size_t)SB*L_*4) };
  float* pub[2] = { (float*)take((size_t)SB*L_*4), (float*)take((size_t)SB*L_*4) };
  float* Mar[2] = { (float*)take(SB*4), (float*)take(SB*4) };
  float* scar[2]= { (float*)take(SB*4), (float*)take(SB*4) };
  float* acar[2]= { (float*)take(SB*4), (float*)take(SB*4) };
  float* bcar[2]= { (float*)take(SB*4), (float*)take(SB*4) };
  size_t off_full = off;

  if (off_full <= ws_size){
    // ============ primary path: 25 dispatches ============
    setup1_kernel<<<SETUP1_UNITS,256,0,stream>>>(
        sys_H, user_H, seqT_s, seqT_u, slot_att, slot_emb,
        xf_all, xa_hi, xa_lo, hbf0, hbf20, hbf1, hbf21, hf0,
        targets, emb, W_ih, Wih_hi, Wih_lo, W_hh, Whh_hi, Whh_lo, embp);
    pre_kernel<<<PRE_UNITS,256,0,stream>>>(
        sys_H, seqT_s, sys_musk, user_H, seqT_u, user_musk,
        hf0, ctx_s, psb[1], ctx_u, pub[1],
        xa_hi, xa_lo, Wih_hi, Wih_lo, gi_all);
    // gg0v2: gh = bf16hl(ctx_s+ctx_u) @ Whh  (also writes hf0 = ctx_s+ctx_u)
    gg0v2_kernel<<<GG_T,256,0,stream>>>(ctx_s, ctx_u, Whh_hi, Whh_lo, gh, hf0);
    // gru(0): h(0) -> buf1
    gru0_kernel<<<SB,256,0,stream>>>(gi_all, gh, b_ih, b_hh, hf0, hf1, hbf1, hbf21);

    float* hfb[2]      = { hf0, hf1 };
    ushort_t* hbfb[2]  = { hbf0, hbf1 };
    ushort_t* hbf2b[2] = { hbf20, hbf21 };
    for (int t=0; t<T_; t++){
      int cur = (t+1)&1;     // h(t) lives here
      int nxt = t&1;         // gru(t+1) writes here
      int ngg = (t < T_-1) ? 1 : 0;
      int base_off = (t > 0) ? 0 : FZ_BLKS;   // skip finalize role entirely at t=0 (960 %8==0)
      int grid = MEGAC_BLKS - base_off;
      int pc = t&1;                   // attend(t) prob parity
      int pp = (t-1)&1;               // finalize(t-1) parity
      float* outp = out + (size_t)t*V_;
      float* outprev = out + (size_t)(t>0 ? t-1 : 0)*V_;
      megaC_kernel<<<grid,256,0,stream>>>(
          sys_H, seqT_s, sys_musk, user_H, seqT_u, user_musk,
          hfb[cur], hbfb[cur], hbf2b[cur],
          ctx_s, psb[pc], ctx_u, pub[pc],
          embp, outp, pmaxw, psumw,
          Whh_hi, Whh_lo, gh, ngg,
          outprev, Mar[pp], scar[pp], acar[pp], bcar[pp],
          psb[pp], pub[pp], story_sys, story_user, base_off);
      finalstats_kernel<<<SB,256,0,stream>>>(
          hfb[cur], ctx_s, ctx_u, xf_all + (size_t)t*SB*H_,
          Wr_w, Wr_b, Wc_w, Wc_b, Wg_w, Wg_b,
          pmaxw, psumw,
          Mar[t&1], scar[t&1], acar[t&1], bcar[t&1],
          gate_out, (t==0)?1:0,
          gi_all + (size_t)(t<T_-1 ? t+1 : 0)*SB*3*H_, gh, b_ih, b_hh,
          hfb[nxt], hbfb[nxt], hbf2b[nxt], (t<T_-1)?1:0);
    }
    // tail finalize for t = T-1 (parity (T-1)&1 = 1)
    finalize_kernel<<<FZ_BLKS,256,0,stream>>>(
        out + (size_t)(T_-1)*V_, Mar[1], scar[1], acar[1], bcar[1],
        psb[1], pub[1], story_sys, story_user);
    return;
  }

  if (off_legacy <= ws_size){
    // ============ legacy basic path ============
    padsplit_kernel<<<(NP_G*KP+255)/256,256,0,stream>>>(W_ih, Wih_hi, Wih_lo);
    padsplit_kernel<<<(NP_G*KP+255)/256,256,0,stream>>>(W_hh, Whh_hi, Whh_lo);
    initL_kernel<<<(MP*KP+255)/256,256,0,stream>>>(slot_att, slot_emb, xf_l, xbf_l, xbf2_l,
                                                   hbf0, hbf20, hf0);
    attendL_kernel<<<SB,256,0,stream>>>(sys_H, sys_musk, hf0, ctx_s, p_s);
    attendL_kernel<<<SB,256,0,stream>>>(user_H, user_musk, hf0, ctx_u, p_u);
    addh_kernel<<<(SB*H_+255)/256,256,0,stream>>>(ctx_s, ctx_u, hf0, hbf0, hbf20);
    for (int t=0; t<T_; t++){
      grugemmL_kernel<<<dim3(NP_G/64, MP/64),256,0,stream>>>(xbf_l, xbf2_l, hbf0, hbf20,
          Wih_hi, Wih_lo, Whh_hi, Whh_lo, gi_l, gh);
      gruL_kernel<<<(SB*H_+255)/256,256,0,stream>>>(gi_l, gh, b_ih, b_hh, hf0, hbf0, hbf20);
      attendL_kernel<<<SB,256,0,stream>>>(sys_H, sys_musk, hf0, ctx_s, p_s);
      attendL_kernel<<<SB,256,0,stream>>>(user_H, user_musk, hf0, ctx_u, p_u);
      smallL_kernel<<<SB,256,0,stream>>>(hf0, ctx_s, ctx_u, xf_l, Wr_w, Wr_b, Wc_w, Wc_b,
                                         Wg_w, Wg_b, sw_arr, ac_arr, bc_arr, gate_out, (t==0)?1:0);
      float* outp = out + (size_t)t*V_;
      vocabL_kernel<<<dim3(NT_VOC, MP/64),256,0,stream>>>(hbf0, emb, outp);
      softmax_scatterL_kernel<<<SB,256,0,stream>>>(sw_arr, ac_arr, bc_arr, p_s, p_u,
                                                   story_sys, story_user, outp);
      if (t < T_-1)
        nextxL_kernel<<<(SB*H_+255)/256,256,0,stream>>>(targets, emb, xf_l, xbf_l, xbf2_l, t);
    }
  }
}